// Round 5
// baseline (652.933 us; speedup 1.0000x reference)
//
#include <hip/hip_runtime.h>
#include <hip/hip_bf16.h>
#include <cmath>

typedef __hip_bfloat16 bf16;
typedef __attribute__((ext_vector_type(8))) short short8;   // 8 bf16 (4 VGPRs)
typedef __attribute__((ext_vector_type(4))) float f32x4;

#define SEQ   2048
#define DIMX  512
#define DIM2X 1024
#define NHEADS 8
#define HDIM  128
#define EPSF  1e-5f
#define PADROWS 2051   // 3 zero rows + 2048 per batch

__device__ __forceinline__ float b2f(bf16 v) { return __bfloat162float(v); }
__device__ __forceinline__ bf16 f2b(float f) { return __float2bfloat16(f); }
__device__ __forceinline__ unsigned short f2bu(float f) { bf16 t = __float2bfloat16(f); return *(unsigned short*)&t; }

// async global->LDS, 16B per lane. LDS dest must be linear in lane order (wave base + lane*16).
__device__ __forceinline__ void gl16(const bf16* g, bf16* l) {
  __builtin_amdgcn_global_load_lds((const __attribute__((address_space(1))) void*)g,
                                   (__attribute__((address_space(3))) void*)l, 16, 0, 0);
}

// ---------------- LayerNorm: one wave per row of 512 (fp32 in, bf16 out) ----------------
__global__ void __launch_bounds__(256) k_layernorm(const float* __restrict__ x,
                                                   const float* __restrict__ w,
                                                   const float* __restrict__ b,
                                                   bf16* __restrict__ out) {
  int row  = blockIdx.x * 4 + (threadIdx.x >> 6);
  int lane = threadIdx.x & 63;
  const float* xr = x + (size_t)row * DIMX;
  float v[8]; float s = 0.f, sq = 0.f;
#pragma unroll
  for (int i = 0; i < 8; i++) {
    float f = xr[lane + i * 64];
    v[i] = f; s += f; sq += f * f;
  }
#pragma unroll
  for (int off = 32; off; off >>= 1) { s += __shfl_xor(s, off); sq += __shfl_xor(sq, off); }
  float mu  = s * (1.f / DIMX);
  float var = sq * (1.f / DIMX) - mu * mu;
  float rs  = rsqrtf(var + EPSF);
  bf16* o = out + (size_t)row * DIMX;
#pragma unroll
  for (int i = 0; i < 8; i++) {
    int c = lane + i * 64;
    o[c] = f2b((v[i] - mu) * rs * w[c] + b[c]);
  }
}

// ---------------- weight cast+transpose: WT[n][k] = bf16(W[k][n]), LDS-tiled ----------------
__global__ void __launch_bounds__(256) k_castT(const float* __restrict__ W, bf16* __restrict__ WT,
                                               int K, int N, int gW, int gT) {
  __shared__ float t[32][33];
  W  += (size_t)blockIdx.z * gW;
  WT += (size_t)blockIdx.z * gT;
  const int k0 = blockIdx.y * 32, n0 = blockIdx.x * 32;
  const int r = threadIdx.x >> 5, c = threadIdx.x & 31;
#pragma unroll
  for (int i = 0; i < 4; i++)
    t[r + i * 8][c] = W[(size_t)(k0 + r + i * 8) * N + n0 + c];
  __syncthreads();
#pragma unroll
  for (int i = 0; i < 4; i++)
    WT[(size_t)(n0 + r + i * 8) * K + k0 + c] = f2b(t[c][r + i * 8]);
}

// ---------------- conv weight reshape: WT2[o][kk*1024+i] = bf16(conv_w[o][i][kk]) ----------------
__global__ void __launch_bounds__(256) k_convwT(const float* __restrict__ cw, bf16* __restrict__ wc) {
  int idx = blockIdx.x * 256 + threadIdx.x;     // out-ordered: (o, kk, i)
  int o = idx >> 12, z = idx & 4095, kk = z >> 10, i = z & 1023;
  wc[idx] = f2b(cw[(size_t)o * 4096 + i * 4 + kk]);
}

// ---------------- zero the 3 pad rows before each batch of padded A ----------------
__global__ void __launch_bounds__(256) k_zeropad(bf16* __restrict__ p) {
  int idx = blockIdx.x * 256 + threadIdx.x;     // 6144 total
  int b = idx / 3072, off = idx % 3072;
  p[(size_t)b * PADROWS * DIM2X + off] = f2b(0.f);
}

// ---------------- MFMA GEMM, m97 structure: 128x128 block, 4 waves (2x2), 64x64/wave ----------------
template <int ACT, int STORE, int APAD>
__global__ void __launch_bounds__(256) k_mgemm(const bf16* __restrict__ A, int lda,
                                               const bf16* __restrict__ WT,
                                               const float* __restrict__ bias,
                                               void* __restrict__ Cv,
                                               const float* __restrict__ xres,
                                               int ldc, int K,
                                               int gA, int gW, int gC) {
  const int g = blockIdx.z;
  A  += (size_t)g * gA;
  WT += (size_t)g * gW;
  __shared__ __align__(16) bf16 smA[128 * 32];
  __shared__ __align__(16) bf16 smB[128 * 32];
  const int tid  = threadIdx.x;
  const int lane = tid & 63;
  const int w = tid >> 6, wy = w >> 1, wx = w & 1;
  const int col = lane & 15, quad = lane >> 4;
  const int bm = blockIdx.y * 128, bn = blockIdx.x * 128;

  const int r4 = tid >> 2, c8 = (tid & 3) * 8;
  int ra0 = bm + r4, ra1 = bm + 64 + r4;
  if (APAD) { ra0 += (ra0 >> 11) * 3 + 3; ra1 += (ra1 >> 11) * 3 + 3; }
  const bf16* gA0 = A + (size_t)ra0 * lda + c8;
  const bf16* gA1 = A + (size_t)ra1 * lda + c8;
  const bf16* gB0 = WT + (size_t)(bn + r4) * K + c8;
  const bf16* gB1 = WT + (size_t)(bn + 64 + r4) * K + c8;
  bf16* lA = &smA[r4 * 32 + c8];
  bf16* lB = &smB[r4 * 32 + c8];

  f32x4 acc[4][4];
#pragma unroll
  for (int a = 0; a < 4; a++)
#pragma unroll
    for (int b = 0; b < 4; b++) acc[a][b] = (f32x4){0.f, 0.f, 0.f, 0.f};

  const int laoff = (wy * 64) * 32, lboff = (wx * 64) * 32;
  for (int k0 = 0; k0 < K; k0 += 32) {
    gl16(gA0 + k0, lA);
    gl16(gA1 + k0, lA + 64 * 32);
    gl16(gB0 + k0, lB);
    gl16(gB1 + k0, lB + 64 * 32);
    asm volatile("s_waitcnt vmcnt(0)" ::: "memory");
    __syncthreads();
    short8 af[4], bfr[4];
#pragma unroll
    for (int mt = 0; mt < 4; mt++)
      af[mt] = *(const short8*)&smA[laoff + (mt * 16 + col) * 32 + quad * 8];
#pragma unroll
    for (int nt = 0; nt < 4; nt++)
      bfr[nt] = *(const short8*)&smB[lboff + (nt * 16 + col) * 32 + quad * 8];
#pragma unroll
    for (int mt = 0; mt < 4; mt++)
#pragma unroll
      for (int nt = 0; nt < 4; nt++)
        acc[mt][nt] = __builtin_amdgcn_mfma_f32_16x16x32_bf16(af[mt], bfr[nt], acc[mt][nt], 0, 0, 0);
    __syncthreads();
  }

#pragma unroll
  for (int mt = 0; mt < 4; mt++) {
#pragma unroll
    for (int nt = 0; nt < 4; nt++) {
      const int n = bn + wx * 64 + nt * 16 + col;
      const int mrow0 = bm + wy * 64 + mt * 16 + quad * 4;
      float bs = bias ? bias[n] : 0.f;
      if (STORE == 1) {
        bf16* C = (bf16*)Cv + (size_t)g * gC;
        ushort4 pk;
        pk.x = f2bu(acc[mt][nt][0] + bs); pk.y = f2bu(acc[mt][nt][1] + bs);
        pk.z = f2bu(acc[mt][nt][2] + bs); pk.w = f2bu(acc[mt][nt][3] + bs);
        *(ushort4*)(C + (size_t)n * 4096 + mrow0) = pk;
      } else if (STORE == 2) {
        float* O = (float*)Cv + (size_t)g * gC;
#pragma unroll
        for (int r = 0; r < 4; r++) {
          size_t gi = (size_t)(mrow0 + r) * ldc + n;
          O[gi] = acc[mt][nt][r] + bs + xres[gi];
        }
      } else if (STORE == 3) {
        bf16* C = (bf16*)Cv;
        const int pr = (mrow0 >> 11) * 3 + 3;   // all 4 rows in same batch (128-blocks)
#pragma unroll
        for (int r = 0; r < 4; r++)
          C[(size_t)(mrow0 + pr + r) * ldc + n] = f2b(acc[mt][nt][r] + bs);
      } else {
        bf16* C = (bf16*)Cv + (size_t)g * gC;
#pragma unroll
        for (int r = 0; r < 4; r++) {
          float v = acc[mt][nt][r] + bs;
          if (ACT == 1) v = v / (1.f + expf(-v));  // silu
          C[(size_t)(mrow0 + r) * ldc + n] = f2b(v);
        }
      }
    }
  }
}

// ---------------- gate GEMV ----------------
__global__ void __launch_bounds__(256) k_gates(const bf16* __restrict__ q, const bf16* __restrict__ kk,
                                               const float* __restrict__ wi, const float* __restrict__ wib,
                                               const float* __restrict__ wf, const float* __restrict__ wfb,
                                               float* __restrict__ it, float* __restrict__ ft) {
  int gid  = blockIdx.x * 4 + (threadIdx.x >> 6);
  int lane = threadIdx.x & 63;
  int which = gid >> 12;
  int m = gid & 4095;
  const bf16* row = (which ? kk : q) + (size_t)m * DIM2X;
  const float* w = which ? wf : wi;
  float s[8] = {0, 0, 0, 0, 0, 0, 0, 0};
  for (int d = lane; d < DIM2X; d += 64) {
    float xv = b2f(row[d]);
    const float4* wp = (const float4*)(w + d * 8);
    float4 w0 = wp[0], w1 = wp[1];
    s[0] += xv * w0.x; s[1] += xv * w0.y; s[2] += xv * w0.z; s[3] += xv * w0.w;
    s[4] += xv * w1.x; s[5] += xv * w1.y; s[6] += xv * w1.z; s[7] += xv * w1.w;
  }
#pragma unroll
  for (int off = 32; off; off >>= 1) {
#pragma unroll
    for (int h = 0; h < 8; h++) s[h] += __shfl_xor(s[h], off);
  }
  if (lane == 0) {
    int b_ = m >> 11, tt = m & 2047;
    const float* wb = which ? wfb : wib;
    float* dst = which ? ft : it;
#pragma unroll
    for (int h = 0; h < 8; h++)
      dst[((size_t)(b_ * NHEADS + h)) * SEQ + tt] = s[h] + wb[h];
  }
}

// ---------------- per-(b,h) scan ----------------
__global__ void __launch_bounds__(256) k_scan(const float* __restrict__ it, const float* __restrict__ ft,
                                              float* __restrict__ cs, float* __restrict__ md) {
  const int bh = blockIdx.x;
  const int t  = threadIdx.x;
  const float* fr = ft + (size_t)bh * SEQ;
  const float* ir = it + (size_t)bh * SEQ;
  float* csr = cs + (size_t)bh * SEQ;
  float* mdr = md + (size_t)bh * SEQ;
  __shared__ float tmp[256];
  float loc[8]; float run = 0.f;
#pragma unroll
  for (int j = 0; j < 8; j++) {
    float xv = fr[t * 8 + j];
    float ls = fminf(xv, 0.f) - log1pf(expf(-fabsf(xv)));
    run += ls; loc[j] = run;
  }
  tmp[t] = run;
  __syncthreads();
  for (int off = 1; off < 256; off <<= 1) {
    float add = (t >= off) ? tmp[t - off] : 0.f;
    __syncthreads();
    tmp[t] += add;
    __syncthreads();
  }
  float exc = (t == 0) ? 0.f : tmp[t - 1];
  float csv[8];
#pragma unroll
  for (int j = 0; j < 8; j++) { csv[j] = loc[j] + exc; csr[t * 8 + j] = csv[j]; }
  __syncthreads();
  float rmax = -INFINITY; float gm[8];
#pragma unroll
  for (int j = 0; j < 8; j++) {
    float gv = ir[t * 8 + j] - csv[j];
    rmax = fmaxf(rmax, gv); gm[j] = rmax;
  }
  tmp[t] = rmax;
  __syncthreads();
  for (int off = 1; off < 256; off <<= 1) {
    float other = (t >= off) ? tmp[t - off] : -INFINITY;
    __syncthreads();
    tmp[t] = fmaxf(tmp[t], other);
    __syncthreads();
  }
  float emax = (t == 0) ? -INFINITY : tmp[t - 1];
#pragma unroll
  for (int j = 0; j < 8; j++) mdr[t * 8 + j] = csv[j] + fmaxf(gm[j], emax);
}

// ---------------- MFMA causal attention: LDS-staged K, register V, exp2 softmax ----------------
// Block = 4 waves, QBLK=64 i-rows; wave w owns rows [i0+16w, i0+16w+16) completely.
// K tiles (32 x 128) staged to LDS via global_load_lds, double-buffered, source
// pre-swizzled chunk^(row&7) (m214 pattern -> conflict-free ds_read_b128).
// V^T read straight from global into regs at trip top (L2-resident; full-trip slack).
// Softmax in log2 domain: cs/md/it pre-scaled by log2(e); 1/tau=2^-5 folded into exponent.
__global__ void __launch_bounds__(256) k_attn_mfma(const bf16* __restrict__ qh,
                                                   const bf16* __restrict__ kh,
                                                   const bf16* __restrict__ vt,
                                                   const float* __restrict__ cs,
                                                   const float* __restrict__ md,
                                                   const float* __restrict__ itl,
                                                   bf16* __restrict__ Hout) {
  const int bh = blockIdx.y, b_ = bh >> 3, h = bh & 7;
  const int tile = 31 - blockIdx.x;           // heavy tiles dispatched first
  const int i0 = tile * 64;
  const int tid = threadIdx.x;
  const int w = tid >> 6;                     // wave 0..3 -> i-rows i0+16w..
  const int lane = tid & 63;
  const int col = lane & 15, quad = lane >> 4;
  const int i0w = i0 + w * 16;
  const int iwmax = i0w + 15;
  const float L2E = 1.44269504f;

  __shared__ __align__(16) bf16 smK[2 * 4096]; // [buf][j 32][d 128], chunk^(j&7) swizzle
  __shared__ __align__(16) bf16 Sc[4][16][40];

  const size_t baseQK = ((size_t)b_ * SEQ) * DIM2X + (size_t)h * HDIM;
  const size_t vtb = (size_t)(h * HDIM) * 4096 + (size_t)b_ * SEQ;
  const float* csp = cs + (size_t)bh * SEQ;
  const float* mdp = md + (size_t)bh * SEQ;
  const float* itp = itl + (size_t)bh * SEQ;

  short8 qf[4];
#pragma unroll
  for (int kc = 0; kc < 4; kc++)
    qf[kc] = *(const short8*)(qh + baseQK + (size_t)(i0w + col) * DIM2X + kc * 32 + quad * 8);

  float cs_i[4], md_i[4];                     // log2 domain
#pragma unroll
  for (int r = 0; r < 4; r++) {
    int i = i0w + quad * 4 + r;
    cs_i[r] = csp[i] * L2E; md_i[r] = mdp[i] * L2E;
  }

  f32x4 accpv[8];
#pragma unroll
  for (int nb = 0; nb < 8; nb++) accpv[nb] = (f32x4){0.f, 0.f, 0.f, 0.f};
  float rs[4] = {0.f, 0.f, 0.f, 0.f};

  // K staging source (thread t covers LDS 16B-chunk t; source pre-swizzled)
  const int kj = tid >> 4, kq = tid & 15;     // K: row kj (+16), chunk kq
  const bf16* gKs = kh + baseQK + (size_t)kj * DIM2X + ((kq ^ (kj & 7)) * 8);

  const int trips = 2 * tile + 2;

#define KSTAGE(buf, j0s)                                                       \
  do {                                                                         \
    bf16* dK = &smK[(buf) * 4096 + tid * 8];                                   \
    gl16(gKs + (size_t)(j0s) * DIM2X, dK);                                     \
    gl16(gKs + (size_t)((j0s) + 16) * DIM2X, dK + 2048);                       \
  } while (0)

  KSTAGE(0, 0);
  asm volatile("s_waitcnt vmcnt(0)" ::: "memory");
  __syncthreads();

  for (int t = 0; t < trips; ++t) {
    const int cur = t & 1;
    const int j0p = t * 32;
    if (t + 1 < trips) KSTAGE(cur ^ 1, j0p + 32);
    if (j0p <= iwmax) {
      // V prefetch for this trip (consumed after QK+softmax+Sc, ~full trip of slack)
      short8 vv[8];
#pragma unroll
      for (int nb = 0; nb < 8; nb++)
        vv[nb] = *(const short8*)(vt + vtb + (size_t)(nb * 16 + col) * 4096 + j0p + quad * 8);
      // hoisted gate loads, log2 domain
      float g0 = (itp[j0p + col] - csp[j0p + col]) * L2E;
      float g1 = (itp[j0p + 16 + col] - csp[j0p + 16 + col]) * L2E;
      const bool jt1 = (j0p + 16 <= iwmax);
#pragma unroll
      for (int jt = 0; jt < 2; jt++) {
        const int j0 = j0p + jt * 16;
        float sv[4] = {0.f, 0.f, 0.f, 0.f};
        if (jt == 0 || jt1) {
          const int jj = jt * 16 + col;
          f32x4 aq = (f32x4){0.f, 0.f, 0.f, 0.f};
#pragma unroll
          for (int kc = 0; kc < 4; kc++) {
            short8 bk = *(const short8*)&smK[cur * 4096 + jj * 128 + ((((kc << 2) | quad) ^ (jj & 7)) << 3)];
            aq = __builtin_amdgcn_mfma_f32_16x16x32_bf16(qf[kc], bk, aq, 0, 0, 0);
          }
          const int j = j0 + col;
          const float gj = jt ? g1 : g0;
#pragma unroll
          for (int r = 0; r < 4; r++) {
            const int i = i0w + quad * 4 + r;
            // arg <= -5 by construction (md = exact row max); 2^-5 = 1/tau
            float s = (j <= i) ? exp2f(cs_i[r] + gj - md_i[r] - 5.f) * aq[r] : 0.f;
            sv[r] = s; rs[r] += s;
          }
        }
#pragma unroll
        for (int r = 0; r < 4; r++) Sc[w][quad * 4 + r][jt * 16 + col] = f2b(sv[r]);
      }
      // own-wave cross-lane LDS round-trip: force write completion before read (rule #18)
      asm volatile("s_waitcnt lgkmcnt(0)" ::: "memory");
      __builtin_amdgcn_sched_barrier(0);
      short8 af = *(const short8*)(&Sc[w][col][quad * 8]);
#pragma unroll
      for (int nb = 0; nb < 8; nb++)
        accpv[nb] = __builtin_amdgcn_mfma_f32_16x16x32_bf16(af, vv[nb], accpv[nb], 0, 0, 0);
    }
    asm volatile("s_waitcnt vmcnt(0)" ::: "memory");  // next-tile K staging done (overlapped)
    __syncthreads();
  }
#undef KSTAGE

  // wave-local epilogue (each wave owns full rows)
#pragma unroll
  for (int r = 0; r < 4; r++) {
    float v = rs[r];
    v += __shfl_xor(v, 1); v += __shfl_xor(v, 2);
    v += __shfl_xor(v, 4); v += __shfl_xor(v, 8);
    rs[r] = v;
  }
  float inv[4];
#pragma unroll
  for (int r = 0; r < 4; r++) {
    float maxit = fmaxf(fabsf(rs[r]), exp2f(fminf(-md_i[r], 43.f)));
    inv[r] = 1.f / (maxit + 1e-8f);
  }
#pragma unroll
  for (int nb = 0; nb < 8; nb++)
#pragma unroll
    for (int r = 0; r < 4; r++)
      Hout[baseQK + (size_t)(i0w + quad * 4 + r) * DIM2X + nb * 16 + col] = f2b(accpv[nb][r] * inv[r]);
}

// ---------------- GroupNorm(per-head over 128) + skip*qk then *bgate ----------------
__global__ void __launch_bounds__(256) k_gnorm(const bf16* __restrict__ H, const bf16* __restrict__ qk,
                                               const bf16* __restrict__ bg,
                                               const float* __restrict__ gw, const float* __restrict__ gb,
                                               const float* __restrict__ skip, bf16* __restrict__ pre) {
  int gid  = blockIdx.x * 4 + (threadIdx.x >> 6);
  int lane = threadIdx.x & 63;
  int m = gid >> 3, h = gid & 7;
  const bf16* Hr = H + (size_t)m * DIM2X + (size_t)h * HDIM;
  float v0 = b2f(Hr[lane]), v1 = b2f(Hr[lane + 64]);
  float s = v0 + v1, sq = v0 * v0 + v1 * v1;
#pragma unroll
  for (int off = 32; off; off >>= 1) { s += __shfl_xor(s, off); sq += __shfl_xor(sq, off); }
  float mu  = s * (1.f / 128.f);
  float var = sq * (1.f / 128.f) - mu * mu;
  float rs  = rsqrtf(var + EPSF);
#pragma unroll
  for (int e = 0; e < 2; e++) {
    int c = lane + e * 64;
    int col = h * HDIM + c;
    float v = e ? v1 : v0;
    float hn = (v - mu) * rs * gw[col] + gb[col];
    size_t gidx = (size_t)m * DIM2X + col;
    pre[gidx] = f2b((hn + skip[col] * b2f(qk[gidx])) * b2f(bg[gidx]));
  }
}

extern "C" void kernel_launch(void* const* d_in, const int* in_sizes, int n_in,
                              void* d_out, int out_size, void* d_ws, size_t ws_size,
                              hipStream_t stream) {
  const float* x     = (const float*)d_in[0];
  const float* ln_w  = (const float*)d_in[1];
  const float* ln_b  = (const float*)d_in[2];
  const float* mlp1w = (const float*)d_in[3];
  const float* mlp1b = (const float*)d_in[4];
  const float* mlp2w = (const float*)d_in[5];
  const float* mlp2b = (const float*)d_in[6];
  const float* convw = (const float*)d_in[7];
  const float* convb = (const float*)d_in[8];
  const float* bqw   = (const float*)d_in[9];
  const float* bkw   = (const float*)d_in[10];
  const float* bvw   = (const float*)d_in[11];
  const float* wqw   = (const float*)d_in[12];
  const float* wqb   = (const float*)d_in[13];
  const float* wkw   = (const float*)d_in[14];
  const float* wkb   = (const float*)d_in[15];
  const float* wvw   = (const float*)d_in[16];
  const float* wvb   = (const float*)d_in[17];
  const float* wiw   = (const float*)d_in[18];
  const float* wib   = (const float*)d_in[19];
  const float* wfw   = (const float*)d_in[20];
  const float* wfb   = (const float*)d_in[21];
  const float* gnw   = (const float*)d_in[22];
  const float* gnb   = (const float*)d_in[23];
  const float* skip  = (const float*)d_in[24];
  const float* finw  = (const float*)d_in[25];
  const float* finb  = (const float*)d_in[26];
  float* out = (float*)d_out;

  float* GA  = (float*)d_ws;
  float* ITb = GA;
  float* FTb = GA + 32768;
  float* CSb = GA + 65536;
  float* MDb = GA + 98304;
  const size_t SLOT = 4u * 1024u * 1024u;
  bf16* S0 = (bf16*)((char*)d_ws + (1 << 20));
  bf16* S1 = S0 + SLOT;
  bf16* S2 = S1 + SLOT;
  bf16* S3 = S2 + SLOT;
  bf16* S4 = S3 + SLOT;
  bf16* S5 = S4 + SLOT;
  bf16* S6 = S5 + SLOT;
  bf16 *LN = S0, *BG = S2, *QKb = S3, *Qb = S4, *Kb = S5, *Vb = S6;
  bf16 *QH = S0, *KH = S1, *VT = S4, *Hb = S5, *PRE = S6;
  bf16* WTb   = S6 + SLOT;
  bf16* mlp1T = WTb;
  bf16* mlp2T = WTb + 524288;
  bf16* convT = WTb + 1048576;                 // [1024][4096] flat-K layout
  bf16* bqT   = WTb + 5242880;
  bf16* bkT   = bqT + 262144;
  bf16* bvT   = bkT + 262144;
  bf16* wqT   = bvT + 262144;
  bf16* wkT   = wqT + 1048576;
  bf16* wvT   = wkT + 1048576;
  bf16* finT  = wvT + 1048576;
  bf16* APD   = finT + 524288;                 // padded A: [2][2051][1024]

  k_castT<<<dim3(32, 16), 256, 0, stream>>>(mlp1w, mlp1T, DIMX, DIM2X, 0, 0);
  k_castT<<<dim3(32, 16), 256, 0, stream>>>(mlp2w, mlp2T, DIMX, DIM2X, 0, 0);
  k_convwT<<<16384, 256, 0, stream>>>(convw, convT);
  k_zeropad<<<24, 256, 0, stream>>>(APD);
  k_castT<<<dim3(8, 8, 4), 256, 0, stream>>>(bqw, bqT, 256, 256, 65536, 65536);
  k_castT<<<dim3(8, 8, 4), 256, 0, stream>>>(bkw, bkT, 256, 256, 65536, 65536);
  k_castT<<<dim3(8, 8, 4), 256, 0, stream>>>(bvw, bvT, 256, 256, 65536, 65536);
  k_castT<<<dim3(32, 32), 256, 0, stream>>>(wqw, wqT, DIM2X, DIM2X, 0, 0);
  k_castT<<<dim3(32, 32), 256, 0, stream>>>(wkw, wkT, DIM2X, DIM2X, 0, 0);
  k_castT<<<dim3(32, 32), 256, 0, stream>>>(wvw, wvT, DIM2X, DIM2X, 0, 0);
  k_castT<<<dim3(16, 32), 256, 0, stream>>>(finw, finT, DIM2X, DIMX, 0, 0);

  k_layernorm<<<1024, 256, 0, stream>>>(x, ln_w, ln_b, LN);
  // a = LN @ mlp1 + b  -> padded layout (3 zero rows per batch) for flat-K conv
  k_mgemm<0, 3, 0><<<dim3(8, 32), 256, 0, stream>>>(LN, DIMX, mlp1T, mlp1b, APD, nullptr, DIM2X, DIMX, 0, 0, 0);
  k_mgemm<1, 0, 0><<<dim3(8, 32), 256, 0, stream>>>(LN, DIMX, mlp2T, mlp2b, BG, nullptr, DIM2X, DIMX, 0, 0, 0);
  // causal conv1d == single GEMM: K=4096 contiguous window over padded rows t..t+3
  k_mgemm<1, 0, 0><<<dim3(8, 16, 2), 256, 0, stream>>>(APD, DIM2X, convT, convb, QKb, nullptr,
                                                       DIM2X, 4096, PADROWS * DIM2X, 0, SEQ * DIM2X);
  k_mgemm<0, 0, 0><<<dim3(2, 32, 4), 256, 0, stream>>>(QKb, DIM2X, bqT, nullptr, Qb, nullptr, DIM2X, 256, 256, 65536, 256);
  k_mgemm<0, 0, 0><<<dim3(2, 32, 4), 256, 0, stream>>>(QKb, DIM2X, bkT, nullptr, Kb, nullptr, DIM2X, 256, 256, 65536, 256);
  k_mgemm<0, 0, 1><<<dim3(2, 32, 4), 256, 0, stream>>>(APD, DIM2X, bvT, nullptr, Vb, nullptr, DIM2X, 256, 256, 65536, 256);
  k_gates<<<2048, 256, 0, stream>>>(Qb, Kb, wiw, wib, wfw, wfb, ITb, FTb);
  k_scan<<<16, 256, 0, stream>>>(ITb, FTb, CSb, MDb);
  k_mgemm<0, 0, 0><<<dim3(8, 32), 256, 0, stream>>>(Qb, DIM2X, wqT, wqb, QH, nullptr, DIM2X, DIM2X, 0, 0, 0);
  k_mgemm<0, 0, 0><<<dim3(8, 32), 256, 0, stream>>>(Kb, DIM2X, wkT, wkb, KH, nullptr, DIM2X, DIM2X, 0, 0, 0);
  k_mgemm<0, 1, 0><<<dim3(8, 32), 256, 0, stream>>>(Vb, DIM2X, wvT, wvb, VT, nullptr, 0, DIM2X, 0, 0, 0);  // V^T
  k_attn_mfma<<<dim3(32, 16), 256, 0, stream>>>(QH, KH, VT, CSb, MDb, ITb, Hb);
  k_gnorm<<<8192, 256, 0, stream>>>(Hb, QKb, BG, gnw, gnb, skip, PRE);
  k_mgemm<0, 2, 0><<<dim3(4, 32), 256, 0, stream>>>(PRE, DIM2X, finT, finb, out, x, DIMX, DIM2X, 0, 0, 0);
}

// Round 6
// 509.595 us; speedup vs baseline: 1.2813x; 1.2813x over previous
//
#include <hip/hip_runtime.h>
#include <hip/hip_bf16.h>
#include <cmath>

typedef __hip_bfloat16 bf16;
typedef __attribute__((ext_vector_type(8))) short short8;   // 8 bf16 (4 VGPRs)
typedef __attribute__((ext_vector_type(4))) float f32x4;

#define SEQ   2048
#define DIMX  512
#define DIM2X 1024
#define NHEADS 8
#define HDIM  128
#define EPSF  1e-5f
#define PADROWS 2051   // 3 zero rows + 2048 per batch

__device__ __forceinline__ float b2f(bf16 v) { return __bfloat162float(v); }
__device__ __forceinline__ bf16 f2b(float f) { return __float2bfloat16(f); }
__device__ __forceinline__ unsigned short f2bu(float f) { bf16 t = __float2bfloat16(f); return *(unsigned short*)&t; }

// async global->LDS, 16B per lane. LDS dest must be linear in lane order (wave base + lane*16).
__device__ __forceinline__ void gl16(const bf16* g, bf16* l) {
  __builtin_amdgcn_global_load_lds((const __attribute__((address_space(1))) void*)g,
                                   (__attribute__((address_space(3))) void*)l, 16, 0, 0);
}

// ---------------- LayerNorm: one wave per row of 512 (fp32 in, bf16 out) ----------------
__global__ void __launch_bounds__(256) k_layernorm(const float* __restrict__ x,
                                                   const float* __restrict__ w,
                                                   const float* __restrict__ b,
                                                   bf16* __restrict__ out) {
  int row  = blockIdx.x * 4 + (threadIdx.x >> 6);
  int lane = threadIdx.x & 63;
  const float* xr = x + (size_t)row * DIMX;
  float v[8]; float s = 0.f, sq = 0.f;
#pragma unroll
  for (int i = 0; i < 8; i++) {
    float f = xr[lane + i * 64];
    v[i] = f; s += f; sq += f * f;
  }
#pragma unroll
  for (int off = 32; off; off >>= 1) { s += __shfl_xor(s, off); sq += __shfl_xor(sq, off); }
  float mu  = s * (1.f / DIMX);
  float var = sq * (1.f / DIMX) - mu * mu;
  float rs  = rsqrtf(var + EPSF);
  bf16* o = out + (size_t)row * DIMX;
#pragma unroll
  for (int i = 0; i < 8; i++) {
    int c = lane + i * 64;
    o[c] = f2b((v[i] - mu) * rs * w[c] + b[c]);
  }
}

// ---------------- fused weight cast+transpose: dst = sel-th of {W0,W1,W2} ----------------
// WT[sel*innerZ*gT + zz*gT + n*K + k] = bf16(Wsel[zz*gW + k*N + n])
__global__ void __launch_bounds__(256) k_castT3(const float* __restrict__ W0,
                                                const float* __restrict__ W1,
                                                const float* __restrict__ W2,
                                                bf16* __restrict__ WT,
                                                int K, int N, int innerZ, int gW, int gT) {
  __shared__ float t[32][33];
  const int z = blockIdx.z;
  const int sel = z / innerZ, zz = z % innerZ;
  const float* W = (sel == 0 ? W0 : sel == 1 ? W1 : W2) + (size_t)zz * gW;
  bf16* T = WT + (size_t)(sel * innerZ + zz) * gT;
  const int k0 = blockIdx.y * 32, n0 = blockIdx.x * 32;
  const int r = threadIdx.x >> 5, c = threadIdx.x & 31;
#pragma unroll
  for (int i = 0; i < 4; i++)
    t[r + i * 8][c] = W[(size_t)(k0 + r + i * 8) * N + n0 + c];
  __syncthreads();
#pragma unroll
  for (int i = 0; i < 4; i++)
    T[(size_t)(n0 + r + i * 8) * K + k0 + c] = f2b(t[c][r + i * 8]);
}

// ---------------- conv weight reshape: WT2[o][kk*1024+i] = bf16(conv_w[o][i][kk]) ----------------
__global__ void __launch_bounds__(256) k_convwT(const float* __restrict__ cw, bf16* __restrict__ wc) {
  int idx = blockIdx.x * 256 + threadIdx.x;     // out-ordered: (o, kk, i)
  int o = idx >> 12, z = idx & 4095, kk = z >> 10, i = z & 1023;
  wc[idx] = f2b(cw[(size_t)o * 4096 + i * 4 + kk]);
}

// ---------------- zero the 3 pad rows before each batch of padded A ----------------
__global__ void __launch_bounds__(256) k_zeropad(bf16* __restrict__ p) {
  int idx = blockIdx.x * 256 + threadIdx.x;     // 6144 total
  int b = idx / 3072, off = idx % 3072;
  p[(size_t)b * PADROWS * DIM2X + off] = f2b(0.f);
}

// ---------------- MFMA GEMM: 128x64 block, 4 waves (2Mx2N), 64x32/wave ----------------
// Grid doubled vs 128x128 (2 blocks/CU) for cross-block latency overlap. LDS 12KB.
template <int ACT, int STORE, int APAD>
__global__ void __launch_bounds__(256) k_mgemm(const bf16* __restrict__ A, int lda,
                                               const bf16* __restrict__ WT,
                                               const float* __restrict__ bias,
                                               void* __restrict__ Cv,
                                               const float* __restrict__ xres,
                                               int ldc, int K,
                                               int gA, int gW, int gC) {
  const int g = blockIdx.z;
  A  += (size_t)g * gA;
  WT += (size_t)g * gW;
  __shared__ __align__(16) bf16 smA[128 * 32];
  __shared__ __align__(16) bf16 smB[64 * 32];
  const int tid  = threadIdx.x;
  const int lane = tid & 63;
  const int w = tid >> 6, wy = w >> 1, wx = w & 1;
  const int col = lane & 15, quad = lane >> 4;
  const int bm = blockIdx.y * 128, bn = blockIdx.x * 64;

  const int r4 = tid >> 2, c8 = (tid & 3) * 8;
  int ra0 = bm + r4, ra1 = bm + 64 + r4;
  if (APAD) { ra0 += (ra0 >> 11) * 3 + 3; ra1 += (ra1 >> 11) * 3 + 3; }
  const bf16* gA0 = A + (size_t)ra0 * lda + c8;
  const bf16* gA1 = A + (size_t)ra1 * lda + c8;
  const bf16* gB0 = WT + (size_t)(bn + r4) * K + c8;
  bf16* lA = &smA[r4 * 32 + c8];
  bf16* lB = &smB[r4 * 32 + c8];

  f32x4 acc[4][2];
#pragma unroll
  for (int a = 0; a < 4; a++)
#pragma unroll
    for (int b = 0; b < 2; b++) acc[a][b] = (f32x4){0.f, 0.f, 0.f, 0.f};

  const int laoff = (wy * 64) * 32, lboff = (wx * 32) * 32;
  for (int k0 = 0; k0 < K; k0 += 32) {
    gl16(gA0 + k0, lA);
    gl16(gA1 + k0, lA + 64 * 32);
    gl16(gB0 + k0, lB);
    asm volatile("s_waitcnt vmcnt(0)" ::: "memory");
    __syncthreads();
    short8 af[4], bfr[2];
#pragma unroll
    for (int mt = 0; mt < 4; mt++)
      af[mt] = *(const short8*)&smA[laoff + (mt * 16 + col) * 32 + quad * 8];
#pragma unroll
    for (int nt = 0; nt < 2; nt++)
      bfr[nt] = *(const short8*)&smB[lboff + (nt * 16 + col) * 32 + quad * 8];
#pragma unroll
    for (int mt = 0; mt < 4; mt++)
#pragma unroll
      for (int nt = 0; nt < 2; nt++)
        acc[mt][nt] = __builtin_amdgcn_mfma_f32_16x16x32_bf16(af[mt], bfr[nt], acc[mt][nt], 0, 0, 0);
    __syncthreads();
  }

#pragma unroll
  for (int mt = 0; mt < 4; mt++) {
#pragma unroll
    for (int nt = 0; nt < 2; nt++) {
      const int n = bn + wx * 32 + nt * 16 + col;
      const int mrow0 = bm + wy * 64 + mt * 16 + quad * 4;
      float bs = bias ? bias[n] : 0.f;
      if (STORE == 1) {
        bf16* C = (bf16*)Cv + (size_t)g * gC;
        ushort4 pk;
        pk.x = f2bu(acc[mt][nt][0] + bs); pk.y = f2bu(acc[mt][nt][1] + bs);
        pk.z = f2bu(acc[mt][nt][2] + bs); pk.w = f2bu(acc[mt][nt][3] + bs);
        *(ushort4*)(C + (size_t)n * 4096 + mrow0) = pk;
      } else if (STORE == 2) {
        float* O = (float*)Cv + (size_t)g * gC;
#pragma unroll
        for (int r = 0; r < 4; r++) {
          size_t gi = (size_t)(mrow0 + r) * ldc + n;
          O[gi] = acc[mt][nt][r] + bs + xres[gi];
        }
      } else if (STORE == 3) {
        bf16* C = (bf16*)Cv;
        const int pr = (mrow0 >> 11) * 3 + 3;   // all 4 rows in same batch (128-blocks)
#pragma unroll
        for (int r = 0; r < 4; r++)
          C[(size_t)(mrow0 + pr + r) * ldc + n] = f2b(acc[mt][nt][r] + bs);
      } else {
        bf16* C = (bf16*)Cv + (size_t)g * gC;
#pragma unroll
        for (int r = 0; r < 4; r++) {
          float v = acc[mt][nt][r] + bs;
          if (ACT == 1) v = v / (1.f + expf(-v));  // silu
          C[(size_t)(mrow0 + r) * ldc + n] = f2b(v);
        }
      }
    }
  }
}

// ---------------- gate GEMV ----------------
__global__ void __launch_bounds__(256) k_gates(const bf16* __restrict__ q, const bf16* __restrict__ kk,
                                               const float* __restrict__ wi, const float* __restrict__ wib,
                                               const float* __restrict__ wf, const float* __restrict__ wfb,
                                               float* __restrict__ it, float* __restrict__ ft) {
  int gid  = blockIdx.x * 4 + (threadIdx.x >> 6);
  int lane = threadIdx.x & 63;
  int which = gid >> 12;
  int m = gid & 4095;
  const bf16* row = (which ? kk : q) + (size_t)m * DIM2X;
  const float* w = which ? wf : wi;
  float s[8] = {0, 0, 0, 0, 0, 0, 0, 0};
  for (int d = lane; d < DIM2X; d += 64) {
    float xv = b2f(row[d]);
    const float4* wp = (const float4*)(w + d * 8);
    float4 w0 = wp[0], w1 = wp[1];
    s[0] += xv * w0.x; s[1] += xv * w0.y; s[2] += xv * w0.z; s[3] += xv * w0.w;
    s[4] += xv * w1.x; s[5] += xv * w1.y; s[6] += xv * w1.z; s[7] += xv * w1.w;
  }
#pragma unroll
  for (int off = 32; off; off >>= 1) {
#pragma unroll
    for (int h = 0; h < 8; h++) s[h] += __shfl_xor(s[h], off);
  }
  if (lane == 0) {
    int b_ = m >> 11, tt = m & 2047;
    const float* wb = which ? wfb : wib;
    float* dst = which ? ft : it;
#pragma unroll
    for (int h = 0; h < 8; h++)
      dst[((size_t)(b_ * NHEADS + h)) * SEQ + tt] = s[h] + wb[h];
  }
}

// ---------------- per-(b,h) scan ----------------
__global__ void __launch_bounds__(256) k_scan(const float* __restrict__ it, const float* __restrict__ ft,
                                              float* __restrict__ cs, float* __restrict__ md) {
  const int bh = blockIdx.x;
  const int t  = threadIdx.x;
  const float* fr = ft + (size_t)bh * SEQ;
  const float* ir = it + (size_t)bh * SEQ;
  float* csr = cs + (size_t)bh * SEQ;
  float* mdr = md + (size_t)bh * SEQ;
  __shared__ float tmp[256];
  float loc[8]; float run = 0.f;
#pragma unroll
  for (int j = 0; j < 8; j++) {
    float xv = fr[t * 8 + j];
    float ls = fminf(xv, 0.f) - log1pf(expf(-fabsf(xv)));
    run += ls; loc[j] = run;
  }
  tmp[t] = run;
  __syncthreads();
  for (int off = 1; off < 256; off <<= 1) {
    float add = (t >= off) ? tmp[t - off] : 0.f;
    __syncthreads();
    tmp[t] += add;
    __syncthreads();
  }
  float exc = (t == 0) ? 0.f : tmp[t - 1];
  float csv[8];
#pragma unroll
  for (int j = 0; j < 8; j++) { csv[j] = loc[j] + exc; csr[t * 8 + j] = csv[j]; }
  __syncthreads();
  float rmax = -INFINITY; float gm[8];
#pragma unroll
  for (int j = 0; j < 8; j++) {
    float gv = ir[t * 8 + j] - csv[j];
    rmax = fmaxf(rmax, gv); gm[j] = rmax;
  }
  tmp[t] = rmax;
  __syncthreads();
  for (int off = 1; off < 256; off <<= 1) {
    float other = (t >= off) ? tmp[t - off] : -INFINITY;
    __syncthreads();
    tmp[t] = fmaxf(tmp[t], other);
    __syncthreads();
  }
  float emax = (t == 0) ? -INFINITY : tmp[t - 1];
#pragma unroll
  for (int j = 0; j < 8; j++) mdr[t * 8 + j] = csv[j] + fmaxf(gm[j], emax);
}

// ---------------- MFMA causal attention, LDS-staged K+V (round-4 structure, exp2 softmax) ----------------
// Block = 4 waves, QBLK=64 i-rows; wave w owns rows [i0+16w, i0+16w+16) completely.
// K and V tiles staged once per block via global_load_lds, double-buffered; one barrier +
// one overlapped vmcnt(0) per step (queue holds ONLY staging loads — keeps dbuf overlap).
// Softmax in log2 domain (exp2f; 1/tau = 2^-5 folded into exponent).
__global__ void __launch_bounds__(256) k_attn_mfma(const bf16* __restrict__ qh,
                                                   const bf16* __restrict__ kh,
                                                   const bf16* __restrict__ vt,
                                                   const float* __restrict__ cs,
                                                   const float* __restrict__ md,
                                                   const float* __restrict__ itl,
                                                   bf16* __restrict__ Hout) {
  const int bh = blockIdx.y, b_ = bh >> 3, h = bh & 7;
  const int tile = 31 - blockIdx.x;           // heavy tiles dispatched first
  const int i0 = tile * 64;
  const int tid = threadIdx.x;
  const int w = tid >> 6;                     // wave 0..3 -> i-rows i0+16w..
  const int lane = tid & 63;
  const int col = lane & 15, quad = lane >> 4;
  const int i0w = i0 + w * 16;
  const int iwmax = i0w + 15;
  const float L2E = 1.44269504f;

  __shared__ __align__(16) bf16 smK[2 * 4096]; // [buf][j 32][d 128], chunk^(j&7) swizzle
  __shared__ __align__(16) bf16 smV[2 * 4096]; // [buf][n 128][j 32], chunk^(n&3) swizzle
  __shared__ __align__(16) bf16 Sc[4][16][40];

  const size_t baseQK = ((size_t)b_ * SEQ) * DIM2X + (size_t)h * HDIM;
  const size_t vtb = (size_t)(h * HDIM) * 4096 + (size_t)b_ * SEQ;
  const float* csp = cs + (size_t)bh * SEQ;
  const float* mdp = md + (size_t)bh * SEQ;
  const float* itp = itl + (size_t)bh * SEQ;

  short8 qf[4];
#pragma unroll
  for (int kc = 0; kc < 4; kc++)
    qf[kc] = *(const short8*)(qh + baseQK + (size_t)(i0w + col) * DIM2X + kc * 32 + quad * 8);

  float cs_i[4], md_i[4];                     // log2 domain
#pragma unroll
  for (int r = 0; r < 4; r++) {
    int i = i0w + quad * 4 + r;
    cs_i[r] = csp[i] * L2E; md_i[r] = mdp[i] * L2E;
  }

  f32x4 accpv[8];
#pragma unroll
  for (int nb = 0; nb < 8; nb++) accpv[nb] = (f32x4){0.f, 0.f, 0.f, 0.f};
  float rs[4] = {0.f, 0.f, 0.f, 0.f};

  // staging sources (thread t covers LDS chunk t of each 4KB half; source pre-swizzled)
  const int kj = tid >> 4, kq = tid & 15;     // K: row kj (+16), chunk kq
  const bf16* gKs = kh + baseQK + (size_t)kj * DIM2X + ((kq ^ (kj & 7)) * 8);
  const int vn = tid >> 2, vq = tid & 3;      // V: row vn (+64), chunk vq
  const bf16* gVs = vt + vtb + (size_t)vn * 4096 + ((vq ^ (vn & 3)) * 8);

  const int trips = 2 * tile + 2;

#define STAGE(buf, j0s)                                                        \
  do {                                                                         \
    bf16* dK = &smK[(buf) * 4096 + tid * 8];                                   \
    gl16(gKs + (size_t)(j0s) * DIM2X, dK);                                     \
    gl16(gKs + (size_t)((j0s) + 16) * DIM2X, dK + 2048);                       \
    bf16* dV = &smV[(buf) * 4096 + tid * 8];                                   \
    gl16(gVs + (j0s), dV);                                                     \
    gl16(gVs + (j0s) + (size_t)64 * 4096, dV + 2048);                          \
  } while (0)

  STAGE(0, 0);
  asm volatile("s_waitcnt vmcnt(0)" ::: "memory");
  __syncthreads();

  for (int t = 0; t < trips; ++t) {
    const int cur = t & 1;
    const int j0p = t * 32;
    if (t + 1 < trips) STAGE(cur ^ 1, j0p + 32);
    if (j0p <= iwmax) {
      // hoisted gate loads, log2 domain
      float g0 = (itp[j0p + col] - csp[j0p + col]) * L2E;
      float g1 = (itp[j0p + 16 + col] - csp[j0p + 16 + col]) * L2E;
      const bool jt1 = (j0p + 16 <= iwmax);
#pragma unroll
      for (int jt = 0; jt < 2; jt++) {
        const int j0 = j0p + jt * 16;
        float sv[4] = {0.f, 0.f, 0.f, 0.f};
        if (jt == 0 || jt1) {
          const int jj = jt * 16 + col;
          f32x4 aq = (f32x4){0.f, 0.f, 0.f, 0.f};
#pragma unroll
          for (int kc = 0; kc < 4; kc++) {
            short8 bk = *(const short8*)&smK[cur * 4096 + jj * 128 + ((((kc << 2) | quad) ^ (jj & 7)) << 3)];
            aq = __builtin_amdgcn_mfma_f32_16x16x32_bf16(qf[kc], bk, aq, 0, 0, 0);
          }
          const int j = j0 + col;
          const float gj = jt ? g1 : g0;
#pragma unroll
          for (int r = 0; r < 4; r++) {
            const int i = i0w + quad * 4 + r;
            // arg <= -5 by construction (md = exact row max); 2^-5 = 1/tau
            float s = (j <= i) ? exp2f(cs_i[r] + gj - md_i[r] - 5.f) * aq[r] : 0.f;
            sv[r] = s; rs[r] += s;
          }
        }
#pragma unroll
        for (int r = 0; r < 4; r++) Sc[w][quad * 4 + r][jt * 16 + col] = f2b(sv[r]);
      }
      // own-wave cross-lane LDS round-trip: force write completion before read (rule #18)
      asm volatile("s_waitcnt lgkmcnt(0)" ::: "memory");
      __builtin_amdgcn_sched_barrier(0);
      short8 af = *(const short8*)(&Sc[w][col][quad * 8]);
#pragma unroll
      for (int nb = 0; nb < 8; nb++) {
        const int rn = nb * 16 + col;
        short8 bv = *(const short8*)&smV[cur * 4096 + rn * 32 + (((quad ^ (col & 3))) << 3)];
        accpv[nb] = __builtin_amdgcn_mfma_f32_16x16x32_bf16(af, bv, accpv[nb], 0, 0, 0);
      }
    }
    asm volatile("s_waitcnt vmcnt(0)" ::: "memory");  // next-tile staging done (overlapped)
    __syncthreads();
  }
#undef STAGE

  // wave-local epilogue (each wave owns full rows)
#pragma unroll
  for (int r = 0; r < 4; r++) {
    float v = rs[r];
    v += __shfl_xor(v, 1); v += __shfl_xor(v, 2);
    v += __shfl_xor(v, 4); v += __shfl_xor(v, 8);
    rs[r] = v;
  }
  float inv[4];
#pragma unroll
  for (int r = 0; r < 4; r++) {
    float maxit = fmaxf(fabsf(rs[r]), exp2f(fminf(-md_i[r], 43.f)));
    inv[r] = 1.f / (maxit + 1e-8f);
  }
#pragma unroll
  for (int nb = 0; nb < 8; nb++)
#pragma unroll
    for (int r = 0; r < 4; r++)
      Hout[baseQK + (size_t)(i0w + quad * 4 + r) * DIM2X + nb * 16 + col] = f2b(accpv[nb][r] * inv[r]);
}

// ---------------- GroupNorm(per-head over 128) + skip*qk then *bgate ----------------
__global__ void __launch_bounds__(256) k_gnorm(const bf16* __restrict__ H, const bf16* __restrict__ qk,
                                               const bf16* __restrict__ bg,
                                               const float* __restrict__ gw, const float* __restrict__ gb,
                                               const float* __restrict__ skip, bf16* __restrict__ pre) {
  int gid  = blockIdx.x * 4 + (threadIdx.x >> 6);
  int lane = threadIdx.x & 63;
  int m = gid >> 3, h = gid & 7;
  const bf16* Hr = H + (size_t)m * DIM2X + (size_t)h * HDIM;
  float v0 = b2f(Hr[lane]), v1 = b2f(Hr[lane + 64]);
  float s = v0 + v1, sq = v0 * v0 + v1 * v1;
#pragma unroll
  for (int off = 32; off; off >>= 1) { s += __shfl_xor(s, off); sq += __shfl_xor(sq, off); }
  float mu  = s * (1.f / 128.f);
  float var = sq * (1.f / 128.f) - mu * mu;
  float rs  = rsqrtf(var + EPSF);
#pragma unroll
  for (int e = 0; e < 2; e++) {
    int c = lane + e * 64;
    int col = h * HDIM + c;
    float v = e ? v1 : v0;
    float hn = (v - mu) * rs * gw[col] + gb[col];
    size_t gidx = (size_t)m * DIM2X + col;
    pre[gidx] = f2b((hn + skip[col] * b2f(qk[gidx])) * b2f(bg[gidx]));
  }
}

extern "C" void kernel_launch(void* const* d_in, const int* in_sizes, int n_in,
                              void* d_out, int out_size, void* d_ws, size_t ws_size,
                              hipStream_t stream) {
  const float* x     = (const float*)d_in[0];
  const float* ln_w  = (const float*)d_in[1];
  const float* ln_b  = (const float*)d_in[2];
  const float* mlp1w = (const float*)d_in[3];
  const float* mlp1b = (const float*)d_in[4];
  const float* mlp2w = (const float*)d_in[5];
  const float* mlp2b = (const float*)d_in[6];
  const float* convw = (const float*)d_in[7];
  const float* convb = (const float*)d_in[8];
  const float* bqw   = (const float*)d_in[9];
  const float* bkw   = (const float*)d_in[10];
  const float* bvw   = (const float*)d_in[11];
  const float* wqw   = (const float*)d_in[12];
  const float* wqb   = (const float*)d_in[13];
  const float* wkw   = (const float*)d_in[14];
  const float* wkb   = (const float*)d_in[15];
  const float* wvw   = (const float*)d_in[16];
  const float* wvb   = (const float*)d_in[17];
  const float* wiw   = (const float*)d_in[18];
  const float* wib   = (const float*)d_in[19];
  const float* wfw   = (const float*)d_in[20];
  const float* wfb   = (const float*)d_in[21];
  const float* gnw   = (const float*)d_in[22];
  const float* gnb   = (const float*)d_in[23];
  const float* skip  = (const float*)d_in[24];
  const float* finw  = (const float*)d_in[25];
  const float* finb  = (const float*)d_in[26];
  float* out = (float*)d_out;

  float* GA  = (float*)d_ws;
  float* ITb = GA;
  float* FTb = GA + 32768;
  float* CSb = GA + 65536;
  float* MDb = GA + 98304;
  const size_t SLOT = 4u * 1024u * 1024u;
  bf16* S0 = (bf16*)((char*)d_ws + (1 << 20));
  bf16* S1 = S0 + SLOT;
  bf16* S2 = S1 + SLOT;
  bf16* S3 = S2 + SLOT;
  bf16* S4 = S3 + SLOT;
  bf16* S5 = S4 + SLOT;
  bf16* S6 = S5 + SLOT;
  bf16 *LN = S0, *BG = S2, *QKb = S3, *Qb = S4, *Kb = S5, *Vb = S6;
  bf16 *QH = S0, *KH = S1, *VT = S4, *Hb = S5, *PRE = S6;
  bf16* WTb   = S6 + SLOT;
  bf16* mlp1T = WTb;
  bf16* mlp2T = WTb + 524288;
  bf16* convT = WTb + 1048576;                 // [1024][4096] flat-K layout
  bf16* bqT   = WTb + 5242880;
  bf16* bkT   = bqT + 262144;
  bf16* bvT   = bkT + 262144;
  bf16* wqT   = bvT + 262144;
  bf16* wkT   = wqT + 1048576;
  bf16* wvT   = wkT + 1048576;
  bf16* finT  = wvT + 1048576;
  bf16* APD   = finT + 524288;                 // padded A: [2][2051][1024]

  // fused weight prep: 4 castT3 launches (mlp pair / wq-wk-wv / bq-bk-bv / fin)
  k_castT3<<<dim3(32, 16, 2), 256, 0, stream>>>(mlp1w, mlp2w, mlp2w, mlp1T, DIMX, DIM2X, 1, 0, 524288);
  k_castT3<<<dim3(32, 32, 3), 256, 0, stream>>>(wqw, wkw, wvw, wqT, DIM2X, DIM2X, 1, 0, 1048576);
  k_castT3<<<dim3(8, 8, 12), 256, 0, stream>>>(bqw, bkw, bvw, bqT, 256, 256, 4, 65536, 65536);
  k_castT3<<<dim3(16, 32, 1), 256, 0, stream>>>(finw, finw, finw, finT, DIM2X, DIMX, 1, 0, 524288);
  k_convwT<<<16384, 256, 0, stream>>>(convw, convT);
  k_zeropad<<<24, 256, 0, stream>>>(APD);

  k_layernorm<<<1024, 256, 0, stream>>>(x, ln_w, ln_b, LN);
  // a = LN @ mlp1 + b  -> padded layout (3 zero rows per batch) for flat-K conv
  k_mgemm<0, 3, 0><<<dim3(16, 32), 256, 0, stream>>>(LN, DIMX, mlp1T, mlp1b, APD, nullptr, DIM2X, DIMX, 0, 0, 0);
  k_mgemm<1, 0, 0><<<dim3(16, 32), 256, 0, stream>>>(LN, DIMX, mlp2T, mlp2b, BG, nullptr, DIM2X, DIMX, 0, 0, 0);
  // causal conv1d == single GEMM: K=4096 contiguous window over padded rows t..t+3
  k_mgemm<1, 0, 0><<<dim3(16, 16, 2), 256, 0, stream>>>(APD, DIM2X, convT, convb, QKb, nullptr,
                                                        DIM2X, 4096, PADROWS * DIM2X, 0, SEQ * DIM2X);
  k_mgemm<0, 0, 0><<<dim3(4, 32, 4), 256, 0, stream>>>(QKb, DIM2X, bqT, nullptr, Qb, nullptr, DIM2X, 256, 256, 65536, 256);
  k_mgemm<0, 0, 0><<<dim3(4, 32, 4), 256, 0, stream>>>(QKb, DIM2X, bkT, nullptr, Kb, nullptr, DIM2X, 256, 256, 65536, 256);
  k_mgemm<0, 0, 1><<<dim3(4, 32, 4), 256, 0, stream>>>(APD, DIM2X, bvT, nullptr, Vb, nullptr, DIM2X, 256, 256, 65536, 256);
  k_gates<<<2048, 256, 0, stream>>>(Qb, Kb, wiw, wib, wfw, wfb, ITb, FTb);
  k_scan<<<16, 256, 0, stream>>>(ITb, FTb, CSb, MDb);
  k_mgemm<0, 0, 0><<<dim3(16, 32), 256, 0, stream>>>(Qb, DIM2X, wqT, wqb, QH, nullptr, DIM2X, DIM2X, 0, 0, 0);
  k_mgemm<0, 0, 0><<<dim3(16, 32), 256, 0, stream>>>(Kb, DIM2X, wkT, wkb, KH, nullptr, DIM2X, DIM2X, 0, 0, 0);
  k_mgemm<0, 1, 0><<<dim3(16, 32), 256, 0, stream>>>(Vb, DIM2X, wvT, wvb, VT, nullptr, 0, DIM2X, 0, 0, 0);  // V^T
  k_attn_mfma<<<dim3(32, 16), 256, 0, stream>>>(QH, KH, VT, CSb, MDb, ITb, Hb);
  k_gnorm<<<8192, 256, 0, stream>>>(Hb, QKb, BG, gnw, gnb, skip, PRE);
  k_mgemm<0, 2, 0><<<dim3(8, 32), 256, 0, stream>>>(PRE, DIM2X, finT, finb, out, x, DIMX, DIM2X, 0, 0, 0);
}

// Round 7
// 475.819 us; speedup vs baseline: 1.3722x; 1.0710x over previous
//
#include <hip/hip_runtime.h>
#include <hip/hip_bf16.h>
#include <cmath>

typedef __hip_bfloat16 bf16;
typedef __attribute__((ext_vector_type(8))) short short8;   // 8 bf16 (4 VGPRs)
typedef __attribute__((ext_vector_type(4))) float f32x4;

#define SEQ   2048
#define DIMX  512
#define DIM2X 1024
#define NHEADS 8
#define HDIM  128
#define EPSF  1e-5f
#define PADROWS 2051   // 3 zero rows + 2048 per batch

__device__ __forceinline__ float b2f(bf16 v) { return __bfloat162float(v); }
__device__ __forceinline__ bf16 f2b(float f) { return __float2bfloat16(f); }
__device__ __forceinline__ unsigned short f2bu(float f) { bf16 t = __float2bfloat16(f); return *(unsigned short*)&t; }

// async global->LDS, 16B per lane. LDS dest must be linear in lane order (wave base + lane*16).
__device__ __forceinline__ void gl16(const bf16* g, bf16* l) {
  __builtin_amdgcn_global_load_lds((const __attribute__((address_space(1))) void*)g,
                                   (__attribute__((address_space(3))) void*)l, 16, 0, 0);
}

// ---------------- LayerNorm: one wave per row of 512 (fp32 in, bf16 out) ----------------
__global__ void __launch_bounds__(256) k_layernorm(const float* __restrict__ x,
                                                   const float* __restrict__ w,
                                                   const float* __restrict__ b,
                                                   bf16* __restrict__ out) {
  int row  = blockIdx.x * 4 + (threadIdx.x >> 6);
  int lane = threadIdx.x & 63;
  const float* xr = x + (size_t)row * DIMX;
  float v[8]; float s = 0.f, sq = 0.f;
#pragma unroll
  for (int i = 0; i < 8; i++) {
    float f = xr[lane + i * 64];
    v[i] = f; s += f; sq += f * f;
  }
#pragma unroll
  for (int off = 32; off; off >>= 1) { s += __shfl_xor(s, off); sq += __shfl_xor(sq, off); }
  float mu  = s * (1.f / DIMX);
  float var = sq * (1.f / DIMX) - mu * mu;
  float rs  = rsqrtf(var + EPSF);
  bf16* o = out + (size_t)row * DIMX;
#pragma unroll
  for (int i = 0; i < 8; i++) {
    int c = lane + i * 64;
    o[c] = f2b((v[i] - mu) * rs * w[c] + b[c]);
  }
}

// ---------------- fused weight cast+transpose: dst = sel-th of {W0,W1,W2} ----------------
__global__ void __launch_bounds__(256) k_castT3(const float* __restrict__ W0,
                                                const float* __restrict__ W1,
                                                const float* __restrict__ W2,
                                                bf16* __restrict__ WT,
                                                int K, int N, int innerZ, int gW, int gT) {
  __shared__ float t[32][33];
  const int z = blockIdx.z;
  const int sel = z / innerZ, zz = z % innerZ;
  const float* W = (sel == 0 ? W0 : sel == 1 ? W1 : W2) + (size_t)zz * gW;
  bf16* T = WT + (size_t)(sel * innerZ + zz) * gT;
  const int k0 = blockIdx.y * 32, n0 = blockIdx.x * 32;
  const int r = threadIdx.x >> 5, c = threadIdx.x & 31;
#pragma unroll
  for (int i = 0; i < 4; i++)
    t[r + i * 8][c] = W[(size_t)(k0 + r + i * 8) * N + n0 + c];
  __syncthreads();
#pragma unroll
  for (int i = 0; i < 4; i++)
    T[(size_t)(n0 + r + i * 8) * K + k0 + c] = f2b(t[c][r + i * 8]);
}

// ---------------- conv weight reshape: WT2[o][kk*1024+i] = bf16(conv_w[o][i][kk]) ----------------
__global__ void __launch_bounds__(256) k_convwT(const float* __restrict__ cw, bf16* __restrict__ wc) {
  int idx = blockIdx.x * 256 + threadIdx.x;     // out-ordered: (o, kk, i)
  int o = idx >> 12, z = idx & 4095, kk = z >> 10, i = z & 1023;
  wc[idx] = f2b(cw[(size_t)o * 4096 + i * 4 + kk]);
}

// ---------------- zero the 3 pad rows before each batch of padded A ----------------
__global__ void __launch_bounds__(256) k_zeropad(bf16* __restrict__ p) {
  int idx = blockIdx.x * 256 + threadIdx.x;     // 6144 total
  int b = idx / 3072, off = idx % 3072;
  p[(size_t)b * PADROWS * DIM2X + off] = f2b(0.f);
}

// ---------------- GEMM epilogue + body shared by template and batched variants ----------------
// 128x64 block, 4 waves (2Mx2N), 64x32/wave, LDS 12KB, gl16 staging.
__device__ __forceinline__ void mgemm_body(const bf16* A, int lda, const bf16* WT,
                                           const float* bias, void* Cv, const float* xres,
                                           int ldc, int K, int ACT, int STORE, int APAD,
                                           size_t coff) {
  __shared__ __align__(16) bf16 smA[128 * 32];
  __shared__ __align__(16) bf16 smB[64 * 32];
  const int tid  = threadIdx.x;
  const int lane = tid & 63;
  const int w = tid >> 6, wy = w >> 1, wx = w & 1;
  const int col = lane & 15, quad = lane >> 4;
  const int bm = blockIdx.y * 128, bn = blockIdx.x * 64;

  const int r4 = tid >> 2, c8 = (tid & 3) * 8;
  int ra0 = bm + r4, ra1 = bm + 64 + r4;
  if (APAD) { ra0 += (ra0 >> 11) * 3 + 3; ra1 += (ra1 >> 11) * 3 + 3; }
  const bf16* gA0 = A + (size_t)ra0 * lda + c8;
  const bf16* gA1 = A + (size_t)ra1 * lda + c8;
  const bf16* gB0 = WT + (size_t)(bn + r4) * K + c8;
  bf16* lA = &smA[r4 * 32 + c8];
  bf16* lB = &smB[r4 * 32 + c8];

  f32x4 acc[4][2];
#pragma unroll
  for (int a = 0; a < 4; a++)
#pragma unroll
    for (int b = 0; b < 2; b++) acc[a][b] = (f32x4){0.f, 0.f, 0.f, 0.f};

  const int laoff = (wy * 64) * 32, lboff = (wx * 32) * 32;
  for (int k0 = 0; k0 < K; k0 += 32) {
    gl16(gA0 + k0, lA);
    gl16(gA1 + k0, lA + 64 * 32);
    gl16(gB0 + k0, lB);
    asm volatile("s_waitcnt vmcnt(0)" ::: "memory");
    __syncthreads();
    short8 af[4], bfr[2];
#pragma unroll
    for (int mt = 0; mt < 4; mt++)
      af[mt] = *(const short8*)&smA[laoff + (mt * 16 + col) * 32 + quad * 8];
#pragma unroll
    for (int nt = 0; nt < 2; nt++)
      bfr[nt] = *(const short8*)&smB[lboff + (nt * 16 + col) * 32 + quad * 8];
#pragma unroll
    for (int mt = 0; mt < 4; mt++)
#pragma unroll
      for (int nt = 0; nt < 2; nt++)
        acc[mt][nt] = __builtin_amdgcn_mfma_f32_16x16x32_bf16(af[mt], bfr[nt], acc[mt][nt], 0, 0, 0);
    __syncthreads();
  }

#pragma unroll
  for (int mt = 0; mt < 4; mt++) {
#pragma unroll
    for (int nt = 0; nt < 2; nt++) {
      const int n = bn + wx * 32 + nt * 16 + col;
      const int mrow0 = bm + wy * 64 + mt * 16 + quad * 4;
      float bs = bias ? bias[n] : 0.f;
      if (STORE == 1) {
        bf16* C = (bf16*)Cv + coff;
        ushort4 pk;
        pk.x = f2bu(acc[mt][nt][0] + bs); pk.y = f2bu(acc[mt][nt][1] + bs);
        pk.z = f2bu(acc[mt][nt][2] + bs); pk.w = f2bu(acc[mt][nt][3] + bs);
        *(ushort4*)(C + (size_t)n * 4096 + mrow0) = pk;
      } else if (STORE == 2) {
        float* O = (float*)Cv + coff;
#pragma unroll
        for (int r = 0; r < 4; r++) {
          size_t gi = (size_t)(mrow0 + r) * ldc + n;
          O[gi] = acc[mt][nt][r] + bs + xres[gi];
        }
      } else if (STORE == 3) {
        bf16* C = (bf16*)Cv;
        const int pr = (mrow0 >> 11) * 3 + 3;   // all 4 rows in same batch (128-blocks)
#pragma unroll
        for (int r = 0; r < 4; r++)
          C[(size_t)(mrow0 + pr + r) * ldc + n] = f2b(acc[mt][nt][r] + bs);
      } else {
        bf16* C = (bf16*)Cv + coff;
#pragma unroll
        for (int r = 0; r < 4; r++) {
          float v = acc[mt][nt][r] + bs;
          if (ACT == 1) v = v / (1.f + expf(-v));  // silu
          C[(size_t)(mrow0 + r) * ldc + n] = f2b(v);
        }
      }
    }
  }
}

// template variant (conv, fin)
template <int ACT, int STORE, int APAD>
__global__ void __launch_bounds__(256) k_mgemm(const bf16* __restrict__ A, int lda,
                                               const bf16* __restrict__ WT,
                                               const float* __restrict__ bias,
                                               void* __restrict__ Cv,
                                               const float* __restrict__ xres,
                                               int ldc, int K,
                                               int gA, int gW, int gC) {
  const int g = blockIdx.z;
  mgemm_body(A + (size_t)g * gA, lda, WT + (size_t)g * gW, bias, Cv, xres,
             ldc, K, ACT, STORE, APAD, (size_t)g * gC);
}

// batched variant: z-slice selects one of 3 jobs (uniform scalar branches)
__global__ void __launch_bounds__(256) k_mgemmB(const bf16* A0, const bf16* A1, const bf16* A2,
                                                const bf16* W0, const bf16* W1, const bf16* W2,
                                                const float* b0, const float* b1, const float* b2,
                                                void* C0, void* C1, void* C2,
                                                int lda, int ldc, int K, int zPer,
                                                int gA, int gW, int gC,
                                                int actm, int storem, int apadm) {
  const int z = blockIdx.z;
  const int sel = z / zPer, zz = z % zPer;
  const bf16* A = (sel == 0 ? A0 : sel == 1 ? A1 : A2) + (size_t)zz * gA;
  const bf16* W = (sel == 0 ? W0 : sel == 1 ? W1 : W2) + (size_t)zz * gW;
  const float* bias = sel == 0 ? b0 : sel == 1 ? b1 : b2;
  void* Cv = sel == 0 ? C0 : sel == 1 ? C1 : C2;
  mgemm_body(A, lda, W, bias, Cv, nullptr, ldc, K,
             (actm >> sel) & 1, (storem >> (4 * sel)) & 15, (apadm >> sel) & 1,
             (size_t)zz * gC);
}

// ---------------- gate GEMV ----------------
__global__ void __launch_bounds__(256) k_gates(const bf16* __restrict__ q, const bf16* __restrict__ kk,
                                               const float* __restrict__ wi, const float* __restrict__ wib,
                                               const float* __restrict__ wf, const float* __restrict__ wfb,
                                               float* __restrict__ it, float* __restrict__ ft) {
  int gid  = blockIdx.x * 4 + (threadIdx.x >> 6);
  int lane = threadIdx.x & 63;
  int which = gid >> 12;
  int m = gid & 4095;
  const bf16* row = (which ? kk : q) + (size_t)m * DIM2X;
  const float* w = which ? wf : wi;
  float s[8] = {0, 0, 0, 0, 0, 0, 0, 0};
  for (int d = lane; d < DIM2X; d += 64) {
    float xv = b2f(row[d]);
    const float4* wp = (const float4*)(w + d * 8);
    float4 w0 = wp[0], w1 = wp[1];
    s[0] += xv * w0.x; s[1] += xv * w0.y; s[2] += xv * w0.z; s[3] += xv * w0.w;
    s[4] += xv * w1.x; s[5] += xv * w1.y; s[6] += xv * w1.z; s[7] += xv * w1.w;
  }
#pragma unroll
  for (int off = 32; off; off >>= 1) {
#pragma unroll
    for (int h = 0; h < 8; h++) s[h] += __shfl_xor(s[h], off);
  }
  if (lane == 0) {
    int b_ = m >> 11, tt = m & 2047;
    const float* wb = which ? wfb : wib;
    float* dst = which ? ft : it;
#pragma unroll
    for (int h = 0; h < 8; h++)
      dst[((size_t)(b_ * NHEADS + h)) * SEQ + tt] = s[h] + wb[h];
  }
}

// ---------------- per-(b,h) scan ----------------
__global__ void __launch_bounds__(256) k_scan(const float* __restrict__ it, const float* __restrict__ ft,
                                              float* __restrict__ cs, float* __restrict__ md) {
  const int bh = blockIdx.x;
  const int t  = threadIdx.x;
  const float* fr = ft + (size_t)bh * SEQ;
  const float* ir = it + (size_t)bh * SEQ;
  float* csr = cs + (size_t)bh * SEQ;
  float* mdr = md + (size_t)bh * SEQ;
  __shared__ float tmp[256];
  float loc[8]; float run = 0.f;
#pragma unroll
  for (int j = 0; j < 8; j++) {
    float xv = fr[t * 8 + j];
    float ls = fminf(xv, 0.f) - log1pf(expf(-fabsf(xv)));
    run += ls; loc[j] = run;
  }
  tmp[t] = run;
  __syncthreads();
  for (int off = 1; off < 256; off <<= 1) {
    float add = (t >= off) ? tmp[t - off] : 0.f;
    __syncthreads();
    tmp[t] += add;
    __syncthreads();
  }
  float exc = (t == 0) ? 0.f : tmp[t - 1];
  float csv[8];
#pragma unroll
  for (int j = 0; j < 8; j++) { csv[j] = loc[j] + exc; csr[t * 8 + j] = csv[j]; }
  __syncthreads();
  float rmax = -INFINITY; float gm[8];
#pragma unroll
  for (int j = 0; j < 8; j++) {
    float gv = ir[t * 8 + j] - csv[j];
    rmax = fmaxf(rmax, gv); gm[j] = rmax;
  }
  tmp[t] = rmax;
  __syncthreads();
  for (int off = 1; off < 256; off <<= 1) {
    float other = (t >= off) ? tmp[t - off] : -INFINITY;
    __syncthreads();
    tmp[t] = fmaxf(tmp[t], other);
    __syncthreads();
  }
  float emax = (t == 0) ? -INFINITY : tmp[t - 1];
#pragma unroll
  for (int j = 0; j < 8; j++) mdr[t * 8 + j] = csv[j] + fmaxf(gm[j], emax);
}

// ---------------- MFMA causal attention, LDS-staged K+V, exp2 softmax ----------------
// Block = 4 waves, QBLK=64 i-rows; wave w owns rows [i0+16w, i0+16w+16) completely.
// K swizzle chunk^(j&7) (2-way, free). V swizzle chunk^((n>>1)&3): smV row stride is
// 64B so rows alternate bank halves by n&1; (n>>1)&3 spreads the 8 same-parity rows
// of a PV read across all 4 chunk slots -> 2 lanes/bank = free (was rn&3: 4-way).
__global__ void __launch_bounds__(256) k_attn_mfma(const bf16* __restrict__ qh,
                                                   const bf16* __restrict__ kh,
                                                   const bf16* __restrict__ vt,
                                                   const float* __restrict__ cs,
                                                   const float* __restrict__ md,
                                                   const float* __restrict__ itl,
                                                   bf16* __restrict__ Hout) {
  const int bh = blockIdx.y, b_ = bh >> 3, h = bh & 7;
  const int tile = 31 - blockIdx.x;           // heavy tiles dispatched first
  const int i0 = tile * 64;
  const int tid = threadIdx.x;
  const int w = tid >> 6;                     // wave 0..3 -> i-rows i0+16w..
  const int lane = tid & 63;
  const int col = lane & 15, quad = lane >> 4;
  const int i0w = i0 + w * 16;
  const int iwmax = i0w + 15;
  const float L2E = 1.44269504f;

  __shared__ __align__(16) bf16 smK[2 * 4096]; // [buf][j 32][d 128], chunk^(j&7) swizzle
  __shared__ __align__(16) bf16 smV[2 * 4096]; // [buf][n 128][j 32], chunk^((n>>1)&3) swizzle
  __shared__ __align__(16) bf16 Sc[4][16][40];

  const size_t baseQK = ((size_t)b_ * SEQ) * DIM2X + (size_t)h * HDIM;
  const size_t vtb = (size_t)(h * HDIM) * 4096 + (size_t)b_ * SEQ;
  const float* csp = cs + (size_t)bh * SEQ;
  const float* mdp = md + (size_t)bh * SEQ;
  const float* itp = itl + (size_t)bh * SEQ;

  short8 qf[4];
#pragma unroll
  for (int kc = 0; kc < 4; kc++)
    qf[kc] = *(const short8*)(qh + baseQK + (size_t)(i0w + col) * DIM2X + kc * 32 + quad * 8);

  float cs_i[4], md_i[4];                     // log2 domain
#pragma unroll
  for (int r = 0; r < 4; r++) {
    int i = i0w + quad * 4 + r;
    cs_i[r] = csp[i] * L2E; md_i[r] = mdp[i] * L2E;
  }

  f32x4 accpv[8];
#pragma unroll
  for (int nb = 0; nb < 8; nb++) accpv[nb] = (f32x4){0.f, 0.f, 0.f, 0.f};
  float rs[4] = {0.f, 0.f, 0.f, 0.f};

  // staging sources (thread t covers LDS chunk t of each 4KB half; source pre-swizzled)
  const int kj = tid >> 4, kq = tid & 15;     // K: row kj (+16), chunk kq
  const bf16* gKs = kh + baseQK + (size_t)kj * DIM2X + ((kq ^ (kj & 7)) * 8);
  const int vn = tid >> 2, vq = tid & 3;      // V: row vn (+64), chunk vq
  const bf16* gVs = vt + vtb + (size_t)vn * 4096 + ((vq ^ ((vn >> 1) & 3)) * 8);

  const int trips = 2 * tile + 2;

#define STAGE(buf, j0s)                                                        \
  do {                                                                         \
    bf16* dK = &smK[(buf) * 4096 + tid * 8];                                   \
    gl16(gKs + (size_t)(j0s) * DIM2X, dK);                                     \
    gl16(gKs + (size_t)((j0s) + 16) * DIM2X, dK + 2048);                       \
    bf16* dV = &smV[(buf) * 4096 + tid * 8];                                   \
    gl16(gVs + (j0s), dV);                                                     \
    gl16(gVs + (j0s) + (size_t)64 * 4096, dV + 2048);                          \
  } while (0)

  STAGE(0, 0);
  asm volatile("s_waitcnt vmcnt(0)" ::: "memory");
  __syncthreads();

  for (int t = 0; t < trips; ++t) {
    const int cur = t & 1;
    const int j0p = t * 32;
    if (t + 1 < trips) STAGE(cur ^ 1, j0p + 32);
    if (j0p <= iwmax) {
      // hoisted gate loads, log2 domain
      float g0 = (itp[j0p + col] - csp[j0p + col]) * L2E;
      float g1 = (itp[j0p + 16 + col] - csp[j0p + 16 + col]) * L2E;
      const bool jt1 = (j0p + 16 <= iwmax);
#pragma unroll
      for (int jt = 0; jt < 2; jt++) {
        const int j0 = j0p + jt * 16;
        float sv[4] = {0.f, 0.f, 0.f, 0.f};
        if (jt == 0 || jt1) {
          const int jj = jt * 16 + col;
          f32x4 aq = (f32x4){0.f, 0.f, 0.f, 0.f};
#pragma unroll
          for (int kc = 0; kc < 4; kc++) {
            short8 bk = *(const short8*)&smK[cur * 4096 + jj * 128 + ((((kc << 2) | quad) ^ (jj & 7)) << 3)];
            aq = __builtin_amdgcn_mfma_f32_16x16x32_bf16(qf[kc], bk, aq, 0, 0, 0);
          }
          const int j = j0 + col;
          const float gj = jt ? g1 : g0;
#pragma unroll
          for (int r = 0; r < 4; r++) {
            const int i = i0w + quad * 4 + r;
            // arg <= -5 by construction (md = exact row max); 2^-5 = 1/tau
            float s = (j <= i) ? exp2f(cs_i[r] + gj - md_i[r] - 5.f) * aq[r] : 0.f;
            sv[r] = s; rs[r] += s;
          }
        }
#pragma unroll
        for (int r = 0; r < 4; r++) Sc[w][quad * 4 + r][jt * 16 + col] = f2b(sv[r]);
      }
      // own-wave cross-lane LDS round-trip: force write completion before read (rule #18)
      asm volatile("s_waitcnt lgkmcnt(0)" ::: "memory");
      __builtin_amdgcn_sched_barrier(0);
      short8 af = *(const short8*)(&Sc[w][col][quad * 8]);
#pragma unroll
      for (int nb = 0; nb < 8; nb++) {
        const int rn = nb * 16 + col;
        short8 bv = *(const short8*)&smV[cur * 4096 + rn * 32 + ((quad ^ ((rn >> 1) & 3)) << 3)];
        accpv[nb] = __builtin_amdgcn_mfma_f32_16x16x32_bf16(af, bv, accpv[nb], 0, 0, 0);
      }
    }
    asm volatile("s_waitcnt vmcnt(0)" ::: "memory");  // next-tile staging done (overlapped)
    __syncthreads();
  }
#undef STAGE

  // wave-local epilogue (each wave owns full rows)
#pragma unroll
  for (int r = 0; r < 4; r++) {
    float v = rs[r];
    v += __shfl_xor(v, 1); v += __shfl_xor(v, 2);
    v += __shfl_xor(v, 4); v += __shfl_xor(v, 8);
    rs[r] = v;
  }
  float inv[4];
#pragma unroll
  for (int r = 0; r < 4; r++) {
    float maxit = fmaxf(fabsf(rs[r]), exp2f(fminf(-md_i[r], 43.f)));
    inv[r] = 1.f / (maxit + 1e-8f);
  }
#pragma unroll
  for (int nb = 0; nb < 8; nb++)
#pragma unroll
    for (int r = 0; r < 4; r++)
      Hout[baseQK + (size_t)(i0w + quad * 4 + r) * DIM2X + nb * 16 + col] = f2b(accpv[nb][r] * inv[r]);
}

// ---------------- GroupNorm(per-head over 128) + skip*qk then *bgate ----------------
__global__ void __launch_bounds__(256) k_gnorm(const bf16* __restrict__ H, const bf16* __restrict__ qk,
                                               const bf16* __restrict__ bg,
                                               const float* __restrict__ gw, const float* __restrict__ gb,
                                               const float* __restrict__ skip, bf16* __restrict__ pre) {
  int gid  = blockIdx.x * 4 + (threadIdx.x >> 6);
  int lane = threadIdx.x & 63;
  int m = gid >> 3, h = gid & 7;
  const bf16* Hr = H + (size_t)m * DIM2X + (size_t)h * HDIM;
  float v0 = b2f(Hr[lane]), v1 = b2f(Hr[lane + 64]);
  float s = v0 + v1, sq = v0 * v0 + v1 * v1;
#pragma unroll
  for (int off = 32; off; off >>= 1) { s += __shfl_xor(s, off); sq += __shfl_xor(sq, off); }
  float mu  = s * (1.f / 128.f);
  float var = sq * (1.f / 128.f) - mu * mu;
  float rs  = rsqrtf(var + EPSF);
#pragma unroll
  for (int e = 0; e < 2; e++) {
    int c = lane + e * 64;
    int col = h * HDIM + c;
    float v = e ? v1 : v0;
    float hn = (v - mu) * rs * gw[col] + gb[col];
    size_t gidx = (size_t)m * DIM2X + col;
    pre[gidx] = f2b((hn + skip[col] * b2f(qk[gidx])) * b2f(bg[gidx]));
  }
}

extern "C" void kernel_launch(void* const* d_in, const int* in_sizes, int n_in,
                              void* d_out, int out_size, void* d_ws, size_t ws_size,
                              hipStream_t stream) {
  const float* x     = (const float*)d_in[0];
  const float* ln_w  = (const float*)d_in[1];
  const float* ln_b  = (const float*)d_in[2];
  const float* mlp1w = (const float*)d_in[3];
  const float* mlp1b = (const float*)d_in[4];
  const float* mlp2w = (const float*)d_in[5];
  const float* mlp2b = (const float*)d_in[6];
  const float* convw = (const float*)d_in[7];
  const float* convb = (const float*)d_in[8];
  const float* bqw   = (const float*)d_in[9];
  const float* bkw   = (const float*)d_in[10];
  const float* bvw   = (const float*)d_in[11];
  const float* wqw   = (const float*)d_in[12];
  const float* wqb   = (const float*)d_in[13];
  const float* wkw   = (const float*)d_in[14];
  const float* wkb   = (const float*)d_in[15];
  const float* wvw   = (const float*)d_in[16];
  const float* wvb   = (const float*)d_in[17];
  const float* wiw   = (const float*)d_in[18];
  const float* wib   = (const float*)d_in[19];
  const float* wfw   = (const float*)d_in[20];
  const float* wfb   = (const float*)d_in[21];
  const float* gnw   = (const float*)d_in[22];
  const float* gnb   = (const float*)d_in[23];
  const float* skip  = (const float*)d_in[24];
  const float* finw  = (const float*)d_in[25];
  const float* finb  = (const float*)d_in[26];
  float* out = (float*)d_out;

  float* GA  = (float*)d_ws;
  float* ITb = GA;
  float* FTb = GA + 32768;
  float* CSb = GA + 65536;
  float* MDb = GA + 98304;
  const size_t SLOT = 4u * 1024u * 1024u;
  bf16* S0 = (bf16*)((char*)d_ws + (1 << 20));
  bf16* S1 = S0 + SLOT;
  bf16* S2 = S1 + SLOT;
  bf16* S3 = S2 + SLOT;
  bf16* S4 = S3 + SLOT;
  bf16* S5 = S4 + SLOT;
  bf16* S6 = S5 + SLOT;
  bf16 *LN = S0, *BG = S2, *QKb = S3, *Qb = S4, *Kb = S5, *Vb = S6;
  bf16 *QH = S0, *KH = S1, *VT = S4, *Hb = S5, *PRE = S6;
  bf16* WTb   = S6 + SLOT;
  bf16* mlp1T = WTb;
  bf16* mlp2T = WTb + 524288;
  bf16* convT = WTb + 1048576;                 // [1024][4096] flat-K layout
  bf16* bqT   = WTb + 5242880;
  bf16* bkT   = bqT + 262144;
  bf16* bvT   = bkT + 262144;
  bf16* wqT   = bvT + 262144;
  bf16* wkT   = wqT + 1048576;
  bf16* wvT   = wkT + 1048576;
  bf16* finT  = wvT + 1048576;
  bf16* APD   = finT + 524288;                 // padded A: [2][2051][1024]

  // fused weight prep
  k_castT3<<<dim3(32, 16, 2), 256, 0, stream>>>(mlp1w, mlp2w, mlp2w, mlp1T, DIMX, DIM2X, 1, 0, 524288);
  k_castT3<<<dim3(32, 32, 3), 256, 0, stream>>>(wqw, wkw, wvw, wqT, DIM2X, DIM2X, 1, 0, 1048576);
  k_castT3<<<dim3(8, 8, 12), 256, 0, stream>>>(bqw, bkw, bvw, bqT, 256, 256, 4, 65536, 65536);
  k_castT3<<<dim3(16, 32, 1), 256, 0, stream>>>(finw, finw, finw, finT, DIM2X, DIMX, 1, 0, 524288);
  k_convwT<<<16384, 256, 0, stream>>>(convw, convT);
  k_zeropad<<<24, 256, 0, stream>>>(APD);

  k_layernorm<<<1024, 256, 0, stream>>>(x, ln_w, ln_b, LN);
  // batched mlp: sel0 = mlp1 -> APD (store3), sel1 = mlp2 -> BG (store0, silu)
  k_mgemmB<<<dim3(16, 32, 2), 256, 0, stream>>>(LN, LN, LN, mlp1T, mlp2T, mlp2T,
                                                mlp1b, mlp2b, mlp2b, APD, BG, BG,
                                                DIMX, DIM2X, DIMX, 1, 0, 0, 0,
                                                /*actm*/ 0b10, /*storem*/ 3 | (0 << 4), /*apadm*/ 0);
  // causal conv1d == single GEMM: K=4096 contiguous window over padded rows t..t+3
  k_mgemm<1, 0, 0><<<dim3(16, 16, 2), 256, 0, stream>>>(APD, DIM2X, convT, convb, QKb, nullptr,
                                                        DIM2X, 4096, PADROWS * DIM2X, 0, SEQ * DIM2X);
  // batched block-diag q/k/v: 12 z-slices (3 weights x 4 groups)
  k_mgemmB<<<dim3(4, 32, 12), 256, 0, stream>>>(QKb, QKb, APD, bqT, bkT, bvT,
                                                nullptr, nullptr, nullptr, Qb, Kb, Vb,
                                                DIM2X, DIM2X, 256, 4, 256, 65536, 256,
                                                /*actm*/ 0, /*storem*/ 0, /*apadm*/ 0b100);
  k_gates<<<2048, 256, 0, stream>>>(Qb, Kb, wiw, wib, wfw, wfb, ITb, FTb);
  k_scan<<<16, 256, 0, stream>>>(ITb, FTb, CSb, MDb);
  // batched wq/wk/wv: sel2 writes V^T (store1)
  k_mgemmB<<<dim3(16, 32, 3), 256, 0, stream>>>(Qb, Kb, Vb, wqT, wkT, wvT,
                                                wqb, wkb, wvb, QH, KH, VT,
                                                DIM2X, DIM2X, DIM2X, 1, 0, 0, 0,
                                                /*actm*/ 0, /*storem*/ 0 | (0 << 4) | (1 << 8), /*apadm*/ 0);
  k_attn_mfma<<<dim3(32, 16), 256, 0, stream>>>(QH, KH, VT, CSb, MDb, ITb, Hb);
  k_gnorm<<<8192, 256, 0, stream>>>(Hb, QKb, BG, gnw, gnb, skip, PRE);
  k_mgemm<0, 2, 0><<<dim3(8, 32), 256, 0, stream>>>(PRE, DIM2X, finT, finb, out, x, DIMX, DIM2X, 0, 0, 0);
}

// Round 8
// 471.673 us; speedup vs baseline: 1.3843x; 1.0088x over previous
//
#include <hip/hip_runtime.h>
#include <hip/hip_bf16.h>
#include <cmath>

typedef __hip_bfloat16 bf16;
typedef __attribute__((ext_vector_type(8))) short short8;   // 8 bf16 (4 VGPRs)
typedef __attribute__((ext_vector_type(4))) float f32x4;

#define SEQ   2048
#define DIMX  512
#define DIM2X 1024
#define NHEADS 8
#define HDIM  128
#define EPSF  1e-5f
#define PADROWS 2051   // 3 zero rows + 2048 per batch

__device__ __forceinline__ float b2f(bf16 v) { return __bfloat162float(v); }
__device__ __forceinline__ bf16 f2b(float f) { return __float2bfloat16(f); }
__device__ __forceinline__ unsigned short f2bu(float f) { bf16 t = __float2bfloat16(f); return *(unsigned short*)&t; }

// async global->LDS, 16B per lane. LDS dest must be linear in lane order (wave base + lane*16).
__device__ __forceinline__ void gl16(const bf16* g, bf16* l) {
  __builtin_amdgcn_global_load_lds((const __attribute__((address_space(1))) void*)g,
                                   (__attribute__((address_space(3))) void*)l, 16, 0, 0);
}

// ---------------- LayerNorm: one wave per row of 512 (fp32 in, bf16 out) ----------------
__global__ void __launch_bounds__(256) k_layernorm(const float* __restrict__ x,
                                                   const float* __restrict__ w,
                                                   const float* __restrict__ b,
                                                   bf16* __restrict__ out) {
  int row  = blockIdx.x * 4 + (threadIdx.x >> 6);
  int lane = threadIdx.x & 63;
  const float* xr = x + (size_t)row * DIMX;
  float v[8]; float s = 0.f, sq = 0.f;
#pragma unroll
  for (int i = 0; i < 8; i++) {
    float f = xr[lane + i * 64];
    v[i] = f; s += f; sq += f * f;
  }
#pragma unroll
  for (int off = 32; off; off >>= 1) { s += __shfl_xor(s, off); sq += __shfl_xor(sq, off); }
  float mu  = s * (1.f / DIMX);
  float var = sq * (1.f / DIMX) - mu * mu;
  float rs  = rsqrtf(var + EPSF);
  bf16* o = out + (size_t)row * DIMX;
#pragma unroll
  for (int i = 0; i < 8; i++) {
    int c = lane + i * 64;
    o[c] = f2b((v[i] - mu) * rs * w[c] + b[c]);
  }
}

// ---------------- fused weight cast+transpose: dst = sel-th of {W0,W1,W2} ----------------
__global__ void __launch_bounds__(256) k_castT3(const float* __restrict__ W0,
                                                const float* __restrict__ W1,
                                                const float* __restrict__ W2,
                                                bf16* __restrict__ WT,
                                                int K, int N, int innerZ, int gW, int gT) {
  __shared__ float t[32][33];
  const int z = blockIdx.z;
  const int sel = z / innerZ, zz = z % innerZ;
  const float* W = (sel == 0 ? W0 : sel == 1 ? W1 : W2) + (size_t)zz * gW;
  bf16* T = WT + (size_t)(sel * innerZ + zz) * gT;
  const int k0 = blockIdx.y * 32, n0 = blockIdx.x * 32;
  const int r = threadIdx.x >> 5, c = threadIdx.x & 31;
#pragma unroll
  for (int i = 0; i < 4; i++)
    t[r + i * 8][c] = W[(size_t)(k0 + r + i * 8) * N + n0 + c];
  __syncthreads();
#pragma unroll
  for (int i = 0; i < 4; i++)
    T[(size_t)(n0 + r + i * 8) * K + k0 + c] = f2b(t[c][r + i * 8]);
}

// ---------------- conv weight reshape: WT2[o][kk*1024+i] = bf16(conv_w[o][i][kk]) ----------------
__global__ void __launch_bounds__(256) k_convwT(const float* __restrict__ cw, bf16* __restrict__ wc) {
  int idx = blockIdx.x * 256 + threadIdx.x;     // out-ordered: (o, kk, i)
  int o = idx >> 12, z = idx & 4095, kk = z >> 10, i = z & 1023;
  wc[idx] = f2b(cw[(size_t)o * 4096 + i * 4 + kk]);
}

// ---------------- zero the 3 pad rows before each batch of padded A ----------------
__global__ void __launch_bounds__(256) k_zeropad(bf16* __restrict__ p) {
  int idx = blockIdx.x * 256 + threadIdx.x;     // 6144 total
  int b = idx / 3072, off = idx % 3072;
  p[(size_t)b * PADROWS * DIM2X + off] = f2b(0.f);
}

// ---------------- GEMM body: 128x64 block, 4 waves, T4 counted-vmcnt pipeline ----------------
// 4 LDS buffers, prefetch depth 2, ONE raw s_barrier per k-step (no vmcnt(0) drain).
// Buffer distance: skew <= 1 trip (per-step barrier); writer at step s touches buf (s+2)&3,
// oldest live reader uses buf (s-1)&3 -> distinct. Waits: vmcnt(6/3/0) for 3 loads/stage.
__device__ __forceinline__ void mgemm_body(const bf16* A, int lda, const bf16* WT,
                                           const float* bias, void* Cv, const float* xres,
                                           int ldc, int K, int ACT, int STORE, int APAD,
                                           size_t coff) {
  __shared__ __align__(16) bf16 smA[4][128 * 32];
  __shared__ __align__(16) bf16 smB[4][64 * 32];
  const int tid  = threadIdx.x;
  const int lane = tid & 63;
  const int w = tid >> 6, wy = w >> 1, wx = w & 1;
  const int col = lane & 15, quad = lane >> 4;
  const int bm = blockIdx.y * 128, bn = blockIdx.x * 64;

  const int r4 = tid >> 2, c8 = (tid & 3) * 8;
  int ra0 = bm + r4, ra1 = bm + 64 + r4;
  if (APAD) { ra0 += (ra0 >> 11) * 3 + 3; ra1 += (ra1 >> 11) * 3 + 3; }
  const bf16* gA0 = A + (size_t)ra0 * lda + c8;
  const bf16* gA1 = A + (size_t)ra1 * lda + c8;
  const bf16* gB0 = WT + (size_t)(bn + r4) * K + c8;

  f32x4 acc[4][2];
#pragma unroll
  for (int a = 0; a < 4; a++)
#pragma unroll
    for (int b = 0; b < 2; b++) acc[a][b] = (f32x4){0.f, 0.f, 0.f, 0.f};

  const int laoff = (wy * 64) * 32, lboff = (wx * 32) * 32;
  const int lsa = r4 * 32 + c8;
  const int nsteps = K >> 5;

#define GSTAGE(buf, k0s)                                                       \
  do {                                                                         \
    gl16(gA0 + (k0s), &smA[buf][lsa]);                                         \
    gl16(gA1 + (k0s), &smA[buf][64 * 32 + lsa]);                               \
    gl16(gB0 + (k0s), &smB[buf][lsa]);                                         \
  } while (0)

  GSTAGE(0, 0);
  if (nsteps > 1) GSTAGE(1, 32);
  for (int s = 0; s < nsteps; ++s) {
    if (s + 2 < nsteps) GSTAGE((s + 2) & 3, (s + 2) * 32);
    if (s + 2 < nsteps)      asm volatile("s_waitcnt vmcnt(6)" ::: "memory");
    else if (s + 1 < nsteps) asm volatile("s_waitcnt vmcnt(3)" ::: "memory");
    else                     asm volatile("s_waitcnt vmcnt(0)" ::: "memory");
    __builtin_amdgcn_s_barrier();
    asm volatile("" ::: "memory");
    const bf16* bA = smA[s & 3];
    const bf16* bB = smB[s & 3];
    short8 af[4], bfr[2];
#pragma unroll
    for (int mt = 0; mt < 4; mt++)
      af[mt] = *(const short8*)&bA[laoff + (mt * 16 + col) * 32 + quad * 8];
#pragma unroll
    for (int nt = 0; nt < 2; nt++)
      bfr[nt] = *(const short8*)&bB[lboff + (nt * 16 + col) * 32 + quad * 8];
#pragma unroll
    for (int mt = 0; mt < 4; mt++)
#pragma unroll
      for (int nt = 0; nt < 2; nt++)
        acc[mt][nt] = __builtin_amdgcn_mfma_f32_16x16x32_bf16(af[mt], bfr[nt], acc[mt][nt], 0, 0, 0);
    // no trailing barrier: 4 buffers tolerate the 1-trip skew
  }
#undef GSTAGE

#pragma unroll
  for (int mt = 0; mt < 4; mt++) {
#pragma unroll
    for (int nt = 0; nt < 2; nt++) {
      const int n = bn + wx * 32 + nt * 16 + col;
      const int mrow0 = bm + wy * 64 + mt * 16 + quad * 4;
      float bs = bias ? bias[n] : 0.f;
      if (STORE == 1) {
        bf16* C = (bf16*)Cv + coff;
        ushort4 pk;
        pk.x = f2bu(acc[mt][nt][0] + bs); pk.y = f2bu(acc[mt][nt][1] + bs);
        pk.z = f2bu(acc[mt][nt][2] + bs); pk.w = f2bu(acc[mt][nt][3] + bs);
        *(ushort4*)(C + (size_t)n * 4096 + mrow0) = pk;
      } else if (STORE == 2) {
        float* O = (float*)Cv + coff;
#pragma unroll
        for (int r = 0; r < 4; r++) {
          size_t gi = (size_t)(mrow0 + r) * ldc + n;
          O[gi] = acc[mt][nt][r] + bs + xres[gi];
        }
      } else if (STORE == 3) {
        bf16* C = (bf16*)Cv;
        const int pr = (mrow0 >> 11) * 3 + 3;   // all 4 rows in same batch (128-blocks)
#pragma unroll
        for (int r = 0; r < 4; r++)
          C[(size_t)(mrow0 + pr + r) * ldc + n] = f2b(acc[mt][nt][r] + bs);
      } else {
        bf16* C = (bf16*)Cv + coff;
#pragma unroll
        for (int r = 0; r < 4; r++) {
          float v = acc[mt][nt][r] + bs;
          if (ACT == 1) v = v / (1.f + expf(-v));  // silu
          C[(size_t)(mrow0 + r) * ldc + n] = f2b(v);
        }
      }
    }
  }
}

// template variant (conv, fin)
template <int ACT, int STORE, int APAD>
__global__ void __launch_bounds__(256) k_mgemm(const bf16* __restrict__ A, int lda,
                                               const bf16* __restrict__ WT,
                                               const float* __restrict__ bias,
                                               void* __restrict__ Cv,
                                               const float* __restrict__ xres,
                                               int ldc, int K,
                                               int gA, int gW, int gC) {
  const int g = blockIdx.z;
  mgemm_body(A + (size_t)g * gA, lda, WT + (size_t)g * gW, bias, Cv, xres,
             ldc, K, ACT, STORE, APAD, (size_t)g * gC);
}

// batched variant: z-slice selects one of 3 jobs (uniform scalar branches)
__global__ void __launch_bounds__(256) k_mgemmB(const bf16* A0, const bf16* A1, const bf16* A2,
                                                const bf16* W0, const bf16* W1, const bf16* W2,
                                                const float* b0, const float* b1, const float* b2,
                                                void* C0, void* C1, void* C2,
                                                int lda, int ldc, int K, int zPer,
                                                int gA, int gW, int gC,
                                                int actm, int storem, int apadm) {
  const int z = blockIdx.z;
  const int sel = z / zPer, zz = z % zPer;
  const bf16* A = (sel == 0 ? A0 : sel == 1 ? A1 : A2) + (size_t)zz * gA;
  const bf16* W = (sel == 0 ? W0 : sel == 1 ? W1 : W2) + (size_t)zz * gW;
  const float* bias = sel == 0 ? b0 : sel == 1 ? b1 : b2;
  void* Cv = sel == 0 ? C0 : sel == 1 ? C1 : C2;
  mgemm_body(A, lda, W, bias, Cv, nullptr, ldc, K,
             (actm >> sel) & 1, (storem >> (4 * sel)) & 15, (apadm >> sel) & 1,
             (size_t)zz * gC);
}

// ---------------- gate GEMV ----------------
__global__ void __launch_bounds__(256) k_gates(const bf16* __restrict__ q, const bf16* __restrict__ kk,
                                               const float* __restrict__ wi, const float* __restrict__ wib,
                                               const float* __restrict__ wf, const float* __restrict__ wfb,
                                               float* __restrict__ it, float* __restrict__ ft) {
  int gid  = blockIdx.x * 4 + (threadIdx.x >> 6);
  int lane = threadIdx.x & 63;
  int which = gid >> 12;
  int m = gid & 4095;
  const bf16* row = (which ? kk : q) + (size_t)m * DIM2X;
  const float* w = which ? wf : wi;
  float s[8] = {0, 0, 0, 0, 0, 0, 0, 0};
  for (int d = lane; d < DIM2X; d += 64) {
    float xv = b2f(row[d]);
    const float4* wp = (const float4*)(w + d * 8);
    float4 w0 = wp[0], w1 = wp[1];
    s[0] += xv * w0.x; s[1] += xv * w0.y; s[2] += xv * w0.z; s[3] += xv * w0.w;
    s[4] += xv * w1.x; s[5] += xv * w1.y; s[6] += xv * w1.z; s[7] += xv * w1.w;
  }
#pragma unroll
  for (int off = 32; off; off >>= 1) {
#pragma unroll
    for (int h = 0; h < 8; h++) s[h] += __shfl_xor(s[h], off);
  }
  if (lane == 0) {
    int b_ = m >> 11, tt = m & 2047;
    const float* wb = which ? wfb : wib;
    float* dst = which ? ft : it;
#pragma unroll
    for (int h = 0; h < 8; h++)
      dst[((size_t)(b_ * NHEADS + h)) * SEQ + tt] = s[h] + wb[h];
  }
}

// ---------------- per-(b,h) scan ----------------
__global__ void __launch_bounds__(256) k_scan(const float* __restrict__ it, const float* __restrict__ ft,
                                              float* __restrict__ cs, float* __restrict__ md) {
  const int bh = blockIdx.x;
  const int t  = threadIdx.x;
  const float* fr = ft + (size_t)bh * SEQ;
  const float* ir = it + (size_t)bh * SEQ;
  float* csr = cs + (size_t)bh * SEQ;
  float* mdr = md + (size_t)bh * SEQ;
  __shared__ float tmp[256];
  float loc[8]; float run = 0.f;
#pragma unroll
  for (int j = 0; j < 8; j++) {
    float xv = fr[t * 8 + j];
    float ls = fminf(xv, 0.f) - log1pf(expf(-fabsf(xv)));
    run += ls; loc[j] = run;
  }
  tmp[t] = run;
  __syncthreads();
  for (int off = 1; off < 256; off <<= 1) {
    float add = (t >= off) ? tmp[t - off] : 0.f;
    __syncthreads();
    tmp[t] += add;
    __syncthreads();
  }
  float exc = (t == 0) ? 0.f : tmp[t - 1];
  float csv[8];
#pragma unroll
  for (int j = 0; j < 8; j++) { csv[j] = loc[j] + exc; csr[t * 8 + j] = csv[j]; }
  __syncthreads();
  float rmax = -INFINITY; float gm[8];
#pragma unroll
  for (int j = 0; j < 8; j++) {
    float gv = ir[t * 8 + j] - csv[j];
    rmax = fmaxf(rmax, gv); gm[j] = rmax;
  }
  tmp[t] = rmax;
  __syncthreads();
  for (int off = 1; off < 256; off <<= 1) {
    float other = (t >= off) ? tmp[t - off] : -INFINITY;
    __syncthreads();
    tmp[t] = fmaxf(tmp[t], other);
    __syncthreads();
  }
  float emax = (t == 0) ? -INFINITY : tmp[t - 1];
#pragma unroll
  for (int j = 0; j < 8; j++) mdr[t * 8 + j] = csv[j] + fmaxf(gm[j], emax);
}

// ---------------- MFMA causal attention: T4 pipeline + balanced tile pairing ----------------
// tile = ((by>>3)&1) ? bx : 31-bx  ==> the two blocks a CU receives (linear ids c, c+256)
// have tile lengths summing to 31 (was: same tile twice -> 2x critical path).
// 4 LDS buffers, prefetch depth 2, one raw s_barrier per trip, counted vmcnt(8/4/0).
__global__ void __launch_bounds__(256) k_attn_mfma(const bf16* __restrict__ qh,
                                                   const bf16* __restrict__ kh,
                                                   const bf16* __restrict__ vt,
                                                   const float* __restrict__ cs,
                                                   const float* __restrict__ md,
                                                   const float* __restrict__ itl,
                                                   bf16* __restrict__ Hout) {
  const int bh = blockIdx.y, b_ = bh >> 3, h = bh & 7;
  const int bx = blockIdx.x;
  const int tile = ((blockIdx.y >> 3) & 1) ? bx : 31 - bx;   // balanced pairing
  const int i0 = tile * 64;
  const int tid = threadIdx.x;
  const int w = tid >> 6;                     // wave 0..3 -> i-rows i0+16w..
  const int lane = tid & 63;
  const int col = lane & 15, quad = lane >> 4;
  const int i0w = i0 + w * 16;
  const int iwmax = i0w + 15;
  const float L2E = 1.44269504f;

  __shared__ __align__(16) bf16 smK[4 * 4096]; // [buf][j 32][d 128], chunk^(j&7) swizzle
  __shared__ __align__(16) bf16 smV[4 * 4096]; // [buf][n 128][j 32], chunk^((n>>1)&3) swizzle
  __shared__ __align__(16) bf16 Sc[4][16][40];

  const size_t baseQK = ((size_t)b_ * SEQ) * DIM2X + (size_t)h * HDIM;
  const size_t vtb = (size_t)(h * HDIM) * 4096 + (size_t)b_ * SEQ;
  const float* csp = cs + (size_t)bh * SEQ;
  const float* mdp = md + (size_t)bh * SEQ;
  const float* itp = itl + (size_t)bh * SEQ;

  short8 qf[4];
#pragma unroll
  for (int kc = 0; kc < 4; kc++)
    qf[kc] = *(const short8*)(qh + baseQK + (size_t)(i0w + col) * DIM2X + kc * 32 + quad * 8);

  float cs_i[4], md_i[4];                     // log2 domain
#pragma unroll
  for (int r = 0; r < 4; r++) {
    int i = i0w + quad * 4 + r;
    cs_i[r] = csp[i] * L2E; md_i[r] = mdp[i] * L2E;
  }

  f32x4 accpv[8];
#pragma unroll
  for (int nb = 0; nb < 8; nb++) accpv[nb] = (f32x4){0.f, 0.f, 0.f, 0.f};
  float rs[4] = {0.f, 0.f, 0.f, 0.f};

  // staging sources (thread t covers LDS chunk t of each 8KB buffer; source pre-swizzled)
  const int kj = tid >> 4, kq = tid & 15;     // K: row kj (+16), chunk kq
  const bf16* gKs = kh + baseQK + (size_t)kj * DIM2X + ((kq ^ (kj & 7)) * 8);
  const int vn = tid >> 2, vq = tid & 3;      // V: row vn (+64), chunk vq
  const bf16* gVs = vt + vtb + (size_t)vn * 4096 + ((vq ^ ((vn >> 1) & 3)) * 8);

  const int trips = 2 * tile + 2;

#define STAGE(buf, j0s)                                                        \
  do {                                                                         \
    bf16* dK = &smK[(buf) * 4096 + tid * 8];                                   \
    gl16(gKs + (size_t)(j0s) * DIM2X, dK);                                     \
    gl16(gKs + (size_t)((j0s) + 16) * DIM2X, dK + 2048);                       \
    bf16* dV = &smV[(buf) * 4096 + tid * 8];                                   \
    gl16(gVs + (j0s), dV);                                                     \
    gl16(gVs + (j0s) + (size_t)64 * 4096, dV + 2048);                          \
  } while (0)

  STAGE(0, 0);
  STAGE(1, 32);                               // trips >= 2 always
  for (int t = 0; t < trips; ++t) {
    const int cur = t & 3;
    const int j0p = t * 32;
    if (t + 2 < trips) STAGE((t + 2) & 3, j0p + 64);
    if (t + 2 < trips)      asm volatile("s_waitcnt vmcnt(8)" ::: "memory");
    else if (t + 1 < trips) asm volatile("s_waitcnt vmcnt(4)" ::: "memory");
    else                    asm volatile("s_waitcnt vmcnt(0)" ::: "memory");
    __builtin_amdgcn_s_barrier();
    asm volatile("" ::: "memory");
    if (j0p <= iwmax) {
      // hoisted gate loads, log2 domain
      float g0 = (itp[j0p + col] - csp[j0p + col]) * L2E;
      float g1 = (itp[j0p + 16 + col] - csp[j0p + 16 + col]) * L2E;
      const bool jt1 = (j0p + 16 <= iwmax);
#pragma unroll
      for (int jt = 0; jt < 2; jt++) {
        const int j0 = j0p + jt * 16;
        float sv[4] = {0.f, 0.f, 0.f, 0.f};
        if (jt == 0 || jt1) {
          const int jj = jt * 16 + col;
          f32x4 aq = (f32x4){0.f, 0.f, 0.f, 0.f};
#pragma unroll
          for (int kc = 0; kc < 4; kc++) {
            short8 bk = *(const short8*)&smK[cur * 4096 + jj * 128 + ((((kc << 2) | quad) ^ (jj & 7)) << 3)];
            aq = __builtin_amdgcn_mfma_f32_16x16x32_bf16(qf[kc], bk, aq, 0, 0, 0);
          }
          const int j = j0 + col;
          const float gj = jt ? g1 : g0;
#pragma unroll
          for (int r = 0; r < 4; r++) {
            const int i = i0w + quad * 4 + r;
            // arg <= -5 by construction (md = exact row max); 2^-5 = 1/tau
            float s = (j <= i) ? exp2f(cs_i[r] + gj - md_i[r] - 5.f) * aq[r] : 0.f;
            sv[r] = s; rs[r] += s;
          }
        }
#pragma unroll
        for (int r = 0; r < 4; r++) Sc[w][quad * 4 + r][jt * 16 + col] = f2b(sv[r]);
      }
      // own-wave cross-lane LDS round-trip: force write completion before read (rule #18)
      asm volatile("s_waitcnt lgkmcnt(0)" ::: "memory");
      __builtin_amdgcn_sched_barrier(0);
      short8 af = *(const short8*)(&Sc[w][col][quad * 8]);
#pragma unroll
      for (int nb = 0; nb < 8; nb++) {
        const int rn = nb * 16 + col;
        short8 bv = *(const short8*)&smV[cur * 4096 + rn * 32 + ((quad ^ ((rn >> 1) & 3)) << 3)];
        accpv[nb] = __builtin_amdgcn_mfma_f32_16x16x32_bf16(af, bv, accpv[nb], 0, 0, 0);
      }
    }
    // no trailing barrier: 4 buffers tolerate the 1-trip skew
  }
#undef STAGE

  // wave-local epilogue (each wave owns full rows)
#pragma unroll
  for (int r = 0; r < 4; r++) {
    float v = rs[r];
    v += __shfl_xor(v, 1); v += __shfl_xor(v, 2);
    v += __shfl_xor(v, 4); v += __shfl_xor(v, 8);
    rs[r] = v;
  }
  float inv[4];
#pragma unroll
  for (int r = 0; r < 4; r++) {
    float maxit = fmaxf(fabsf(rs[r]), exp2f(fminf(-md_i[r], 43.f)));
    inv[r] = 1.f / (maxit + 1e-8f);
  }
#pragma unroll
  for (int nb = 0; nb < 8; nb++)
#pragma unroll
    for (int r = 0; r < 4; r++)
      Hout[baseQK + (size_t)(i0w + quad * 4 + r) * DIM2X + nb * 16 + col] = f2b(accpv[nb][r] * inv[r]);
}

// ---------------- GroupNorm(per-head over 128) + skip*qk then *bgate ----------------
__global__ void __launch_bounds__(256) k_gnorm(const bf16* __restrict__ H, const bf16* __restrict__ qk,
                                               const bf16* __restrict__ bg,
                                               const float* __restrict__ gw, const float* __restrict__ gb,
                                               const float* __restrict__ skip, bf16* __restrict__ pre) {
  int gid  = blockIdx.x * 4 + (threadIdx.x >> 6);
  int lane = threadIdx.x & 63;
  int m = gid >> 3, h = gid & 7;
  const bf16* Hr = H + (size_t)m * DIM2X + (size_t)h * HDIM;
  float v0 = b2f(Hr[lane]), v1 = b2f(Hr[lane + 64]);
  float s = v0 + v1, sq = v0 * v0 + v1 * v1;
#pragma unroll
  for (int off = 32; off; off >>= 1) { s += __shfl_xor(s, off); sq += __shfl_xor(sq, off); }
  float mu  = s * (1.f / 128.f);
  float var = sq * (1.f / 128.f) - mu * mu;
  float rs  = rsqrtf(var + EPSF);
#pragma unroll
  for (int e = 0; e < 2; e++) {
    int c = lane + e * 64;
    int col = h * HDIM + c;
    float v = e ? v1 : v0;
    float hn = (v - mu) * rs * gw[col] + gb[col];
    size_t gidx = (size_t)m * DIM2X + col;
    pre[gidx] = f2b((hn + skip[col] * b2f(qk[gidx])) * b2f(bg[gidx]));
  }
}

extern "C" void kernel_launch(void* const* d_in, const int* in_sizes, int n_in,
                              void* d_out, int out_size, void* d_ws, size_t ws_size,
                              hipStream_t stream) {
  const float* x     = (const float*)d_in[0];
  const float* ln_w  = (const float*)d_in[1];
  const float* ln_b  = (const float*)d_in[2];
  const float* mlp1w = (const float*)d_in[3];
  const float* mlp1b = (const float*)d_in[4];
  const float* mlp2w = (const float*)d_in[5];
  const float* mlp2b = (const float*)d_in[6];
  const float* convw = (const float*)d_in[7];
  const float* convb = (const float*)d_in[8];
  const float* bqw   = (const float*)d_in[9];
  const float* bkw   = (const float*)d_in[10];
  const float* bvw   = (const float*)d_in[11];
  const float* wqw   = (const float*)d_in[12];
  const float* wqb   = (const float*)d_in[13];
  const float* wkw   = (const float*)d_in[14];
  const float* wkb   = (const float*)d_in[15];
  const float* wvw   = (const float*)d_in[16];
  const float* wvb   = (const float*)d_in[17];
  const float* wiw   = (const float*)d_in[18];
  const float* wib   = (const float*)d_in[19];
  const float* wfw   = (const float*)d_in[20];
  const float* wfb   = (const float*)d_in[21];
  const float* gnw   = (const float*)d_in[22];
  const float* gnb   = (const float*)d_in[23];
  const float* skip  = (const float*)d_in[24];
  const float* finw  = (const float*)d_in[25];
  const float* finb  = (const float*)d_in[26];
  float* out = (float*)d_out;

  float* GA  = (float*)d_ws;
  float* ITb = GA;
  float* FTb = GA + 32768;
  float* CSb = GA + 65536;
  float* MDb = GA + 98304;
  const size_t SLOT = 4u * 1024u * 1024u;
  bf16* S0 = (bf16*)((char*)d_ws + (1 << 20));
  bf16* S1 = S0 + SLOT;
  bf16* S2 = S1 + SLOT;
  bf16* S3 = S2 + SLOT;
  bf16* S4 = S3 + SLOT;
  bf16* S5 = S4 + SLOT;
  bf16* S6 = S5 + SLOT;
  bf16 *LN = S0, *BG = S2, *QKb = S3, *Qb = S4, *Kb = S5, *Vb = S6;
  bf16 *QH = S0, *KH = S1, *VT = S4, *Hb = S5, *PRE = S6;
  bf16* WTb   = S6 + SLOT;
  bf16* mlp1T = WTb;
  bf16* mlp2T = WTb + 524288;
  bf16* convT = WTb + 1048576;                 // [1024][4096] flat-K layout
  bf16* bqT   = WTb + 5242880;
  bf16* bkT   = bqT + 262144;
  bf16* bvT   = bkT + 262144;
  bf16* wqT   = bvT + 262144;
  bf16* wkT   = wqT + 1048576;
  bf16* wvT   = wkT + 1048576;
  bf16* finT  = wvT + 1048576;
  bf16* APD   = finT + 524288;                 // padded A: [2][2051][1024]

  // fused weight prep
  k_castT3<<<dim3(32, 16, 2), 256, 0, stream>>>(mlp1w, mlp2w, mlp2w, mlp1T, DIMX, DIM2X, 1, 0, 524288);
  k_castT3<<<dim3(32, 32, 3), 256, 0, stream>>>(wqw, wkw, wvw, wqT, DIM2X, DIM2X, 1, 0, 1048576);
  k_castT3<<<dim3(8, 8, 12), 256, 0, stream>>>(bqw, bkw, bvw, bqT, 256, 256, 4, 65536, 65536);
  k_castT3<<<dim3(16, 32, 1), 256, 0, stream>>>(finw, finw, finw, finT, DIM2X, DIMX, 1, 0, 524288);
  k_convwT<<<16384, 256, 0, stream>>>(convw, convT);
  k_zeropad<<<24, 256, 0, stream>>>(APD);

  k_layernorm<<<1024, 256, 0, stream>>>(x, ln_w, ln_b, LN);
  // batched mlp: sel0 = mlp1 -> APD (store3), sel1 = mlp2 -> BG (store0, silu)
  k_mgemmB<<<dim3(16, 32, 2), 256, 0, stream>>>(LN, LN, LN, mlp1T, mlp2T, mlp2T,
                                                mlp1b, mlp2b, mlp2b, APD, BG, BG,
                                                DIMX, DIM2X, DIMX, 1, 0, 0, 0,
                                                /*actm*/ 0b10, /*storem*/ 3 | (0 << 4), /*apadm*/ 0);
  // causal conv1d == single GEMM: K=4096 contiguous window over padded rows t..t+3
  k_mgemm<1, 0, 0><<<dim3(16, 16, 2), 256, 0, stream>>>(APD, DIM2X, convT, convb, QKb, nullptr,
                                                        DIM2X, 4096, PADROWS * DIM2X, 0, SEQ * DIM2X);
  // batched block-diag q/k/v: 12 z-slices (3 weights x 4 groups)
  k_mgemmB<<<dim3(4, 32, 12), 256, 0, stream>>>(QKb, QKb, APD, bqT, bkT, bvT,
                                                nullptr, nullptr, nullptr, Qb, Kb, Vb,
                                                DIM2X, DIM2X, 256, 4, 256, 65536, 256,
                                                /*actm*/ 0, /*storem*/ 0, /*apadm*/ 0b100);
  k_gates<<<2048, 256, 0, stream>>>(Qb, Kb, wiw, wib, wfw, wfb, ITb, FTb);
  k_scan<<<16, 256, 0, stream>>>(ITb, FTb, CSb, MDb);
  // batched wq/wk/wv: sel2 writes V^T (store1)
  k_mgemmB<<<dim3(16, 32, 3), 256, 0, stream>>>(Qb, Kb, Vb, wqT, wkT, wvT,
                                                wqb, wkb, wvb, QH, KH, VT,
                                                DIM2X, DIM2X, DIM2X, 1, 0, 0, 0,
                                                /*actm*/ 0, /*storem*/ 0 | (0 << 4) | (1 << 8), /*apadm*/ 0);
  k_attn_mfma<<<dim3(32, 16), 256, 0, stream>>>(QH, KH, VT, CSb, MDb, ITb, Hb);
  k_gnorm<<<8192, 256, 0, stream>>>(Hb, QKb, BG, gnw, gnb, skip, PRE);
  k_mgemm<0, 2, 0><<<dim3(8, 32), 256, 0, stream>>>(PRE, DIM2X, finT, finb, out, x, DIMX, DIM2X, 0, 0, 0);
}

// Round 9
// 460.501 us; speedup vs baseline: 1.4179x; 1.0243x over previous
//
#include <hip/hip_runtime.h>
#include <hip/hip_bf16.h>
#include <cmath>

typedef __hip_bfloat16 bf16;
typedef __attribute__((ext_vector_type(8))) short short8;   // 8 bf16 (4 VGPRs)
typedef __attribute__((ext_vector_type(4))) float f32x4;

#define SEQ   2048
#define DIMX  512
#define DIM2X 1024
#define NHEADS 8
#define HDIM  128
#define EPSF  1e-5f
#define PADROWS 2051   // 3 zero rows + 2048 per batch

__device__ __forceinline__ float b2f(bf16 v) { return __bfloat162float(v); }
__device__ __forceinline__ bf16 f2b(float f) { return __float2bfloat16(f); }
__device__ __forceinline__ unsigned short f2bu(float f) { bf16 t = __float2bfloat16(f); return *(unsigned short*)&t; }

// async global->LDS, 16B per lane. LDS dest must be linear in lane order (wave base + lane*16).
__device__ __forceinline__ void gl16(const bf16* g, bf16* l) {
  __builtin_amdgcn_global_load_lds((const __attribute__((address_space(1))) void*)g,
                                   (__attribute__((address_space(3))) void*)l, 16, 0, 0);
}

// ---------------- LayerNorm: one wave per row of 512 (fp32 in, bf16 out) ----------------
__global__ void __launch_bounds__(256) k_layernorm(const float* __restrict__ x,
                                                   const float* __restrict__ w,
                                                   const float* __restrict__ b,
                                                   bf16* __restrict__ out) {
  int row  = blockIdx.x * 4 + (threadIdx.x >> 6);
  int lane = threadIdx.x & 63;
  const float* xr = x + (size_t)row * DIMX;
  float v[8]; float s = 0.f, sq = 0.f;
#pragma unroll
  for (int i = 0; i < 8; i++) {
    float f = xr[lane + i * 64];
    v[i] = f; s += f; sq += f * f;
  }
#pragma unroll
  for (int off = 32; off; off >>= 1) { s += __shfl_xor(s, off); sq += __shfl_xor(sq, off); }
  float mu  = s * (1.f / DIMX);
  float var = sq * (1.f / DIMX) - mu * mu;
  float rs  = rsqrtf(var + EPSF);
  bf16* o = out + (size_t)row * DIMX;
#pragma unroll
  for (int i = 0; i < 8; i++) {
    int c = lane + i * 64;
    o[c] = f2b((v[i] - mu) * rs * w[c] + b[c]);
  }
}

// ---------------- fused weight cast+transpose: dst = sel-th of {W0,W1,W2} ----------------
__global__ void __launch_bounds__(256) k_castT3(const float* __restrict__ W0,
                                                const float* __restrict__ W1,
                                                const float* __restrict__ W2,
                                                bf16* __restrict__ WT,
                                                int K, int N, int innerZ, int gW, int gT) {
  __shared__ float t[32][33];
  const int z = blockIdx.z;
  const int sel = z / innerZ, zz = z % innerZ;
  const float* W = (sel == 0 ? W0 : sel == 1 ? W1 : W2) + (size_t)zz * gW;
  bf16* T = WT + (size_t)(sel * innerZ + zz) * gT;
  const int k0 = blockIdx.y * 32, n0 = blockIdx.x * 32;
  const int r = threadIdx.x >> 5, c = threadIdx.x & 31;
#pragma unroll
  for (int i = 0; i < 4; i++)
    t[r + i * 8][c] = W[(size_t)(k0 + r + i * 8) * N + n0 + c];
  __syncthreads();
#pragma unroll
  for (int i = 0; i < 4; i++)
    T[(size_t)(n0 + r + i * 8) * K + k0 + c] = f2b(t[c][r + i * 8]);
}

// ---------------- conv weight reshape: WT2[o][kk*1024+i] = bf16(conv_w[o][i][kk]) ----------------
__global__ void __launch_bounds__(256) k_convwT(const float* __restrict__ cw, bf16* __restrict__ wc) {
  int idx = blockIdx.x * 256 + threadIdx.x;     // out-ordered: (o, kk, i)
  int o = idx >> 12, z = idx & 4095, kk = z >> 10, i = z & 1023;
  wc[idx] = f2b(cw[(size_t)o * 4096 + i * 4 + kk]);
}

// ---------------- zero the 3 pad rows before each batch of padded A ----------------
__global__ void __launch_bounds__(256) k_zeropad(bf16* __restrict__ p) {
  int idx = blockIdx.x * 256 + threadIdx.x;     // 6144 total
  int b = idx / 3072, off = idx % 3072;
  p[(size_t)b * PADROWS * DIM2X + off] = f2b(0.f);
}

// ---------------- GEMM body: 128x64 block, 4 waves, counted-vmcnt pipeline ----------------
// 4 LDS buffers, prefetch depth 2, ONE raw s_barrier per k-step.
__device__ __forceinline__ void mgemm_body(const bf16* A, int lda, const bf16* WT,
                                           const float* bias, void* Cv, const float* xres,
                                           int ldc, int K, int ACT, int STORE, int APAD,
                                           size_t coff, int bm, int bn) {
  __shared__ __align__(16) bf16 smA[4][128 * 32];
  __shared__ __align__(16) bf16 smB[4][64 * 32];
  const int tid  = threadIdx.x;
  const int lane = tid & 63;
  const int w = tid >> 6, wy = w >> 1, wx = w & 1;
  const int col = lane & 15, quad = lane >> 4;

  const int r4 = tid >> 2, c8 = (tid & 3) * 8;
  int ra0 = bm + r4, ra1 = bm + 64 + r4;
  if (APAD) { ra0 += (ra0 >> 11) * 3 + 3; ra1 += (ra1 >> 11) * 3 + 3; }
  const bf16* gA0 = A + (size_t)ra0 * lda + c8;
  const bf16* gA1 = A + (size_t)ra1 * lda + c8;
  const bf16* gB0 = WT + (size_t)(bn + r4) * K + c8;

  f32x4 acc[4][2];
#pragma unroll
  for (int a = 0; a < 4; a++)
#pragma unroll
    for (int b = 0; b < 2; b++) acc[a][b] = (f32x4){0.f, 0.f, 0.f, 0.f};

  const int laoff = (wy * 64) * 32, lboff = (wx * 32) * 32;
  const int lsa = r4 * 32 + c8;
  const int nsteps = K >> 5;

#define GSTAGE(buf, k0s)                                                       \
  do {                                                                         \
    gl16(gA0 + (k0s), &smA[buf][lsa]);                                         \
    gl16(gA1 + (k0s), &smA[buf][64 * 32 + lsa]);                               \
    gl16(gB0 + (k0s), &smB[buf][lsa]);                                         \
  } while (0)

  GSTAGE(0, 0);
  if (nsteps > 1) GSTAGE(1, 32);
  for (int s = 0; s < nsteps; ++s) {
    if (s + 2 < nsteps) GSTAGE((s + 2) & 3, (s + 2) * 32);
    if (s + 2 < nsteps)      asm volatile("s_waitcnt vmcnt(6)" ::: "memory");
    else if (s + 1 < nsteps) asm volatile("s_waitcnt vmcnt(3)" ::: "memory");
    else                     asm volatile("s_waitcnt vmcnt(0)" ::: "memory");
    __builtin_amdgcn_s_barrier();
    asm volatile("" ::: "memory");
    const bf16* bA = smA[s & 3];
    const bf16* bB = smB[s & 3];
    short8 af[4], bfr[2];
#pragma unroll
    for (int mt = 0; mt < 4; mt++)
      af[mt] = *(const short8*)&bA[laoff + (mt * 16 + col) * 32 + quad * 8];
#pragma unroll
    for (int nt = 0; nt < 2; nt++)
      bfr[nt] = *(const short8*)&bB[lboff + (nt * 16 + col) * 32 + quad * 8];
#pragma unroll
    for (int mt = 0; mt < 4; mt++)
#pragma unroll
      for (int nt = 0; nt < 2; nt++)
        acc[mt][nt] = __builtin_amdgcn_mfma_f32_16x16x32_bf16(af[mt], bfr[nt], acc[mt][nt], 0, 0, 0);
    // no trailing barrier: 4 buffers tolerate the 1-trip skew
  }
#undef GSTAGE

#pragma unroll
  for (int mt = 0; mt < 4; mt++) {
#pragma unroll
    for (int nt = 0; nt < 2; nt++) {
      const int n = bn + wx * 32 + nt * 16 + col;
      const int mrow0 = bm + wy * 64 + mt * 16 + quad * 4;
      float bs = bias ? bias[n] : 0.f;
      if (STORE == 1) {
        bf16* C = (bf16*)Cv + coff;
        ushort4 pk;
        pk.x = f2bu(acc[mt][nt][0] + bs); pk.y = f2bu(acc[mt][nt][1] + bs);
        pk.z = f2bu(acc[mt][nt][2] + bs); pk.w = f2bu(acc[mt][nt][3] + bs);
        *(ushort4*)(C + (size_t)n * 4096 + mrow0) = pk;
      } else if (STORE == 2) {
        float* O = (float*)Cv + coff;
#pragma unroll
        for (int r = 0; r < 4; r++) {
          size_t gi = (size_t)(mrow0 + r) * ldc + n;
          O[gi] = acc[mt][nt][r] + bs + xres[gi];
        }
      } else if (STORE == 3) {
        bf16* C = (bf16*)Cv;
        const int pr = (mrow0 >> 11) * 3 + 3;   // all 4 rows in same batch (128-blocks)
#pragma unroll
        for (int r = 0; r < 4; r++)
          C[(size_t)(mrow0 + pr + r) * ldc + n] = f2b(acc[mt][nt][r] + bs);
      } else {
        bf16* C = (bf16*)Cv + coff;
#pragma unroll
        for (int r = 0; r < 4; r++) {
          float v = acc[mt][nt][r] + bs;
          if (ACT == 1) v = v / (1.f + expf(-v));  // silu
          C[(size_t)(mrow0 + r) * ldc + n] = f2b(v);
        }
      }
    }
  }
}

// T1 bijective XCD swizzle (m204 form, r=0 case; requires nwg % 8 == 0 — true for all
// launches below). Dispatch ids d, d+8, ... (round-robin to one XCD) get CONSECUTIVE
// work ids -> blocks sharing an A-panel / B-panel chunk co-locate on one XCD's L2.
__device__ __forceinline__ int xcd_work_id() {
  const int nx = gridDim.x, ny = gridDim.y;
  const int d = blockIdx.x + nx * (blockIdx.y + ny * blockIdx.z);
  const int q = (nx * ny * (int)gridDim.z) >> 3;
  return (d & 7) * q + (d >> 3);
}

// template variant (conv, fin)
template <int ACT, int STORE, int APAD>
__global__ void __launch_bounds__(256) k_mgemm(const bf16* __restrict__ A, int lda,
                                               const bf16* __restrict__ WT,
                                               const float* __restrict__ bias,
                                               void* __restrict__ Cv,
                                               const float* __restrict__ xres,
                                               int ldc, int K,
                                               int gA, int gW, int gC) {
  const int wk = xcd_work_id();
  const int nx = gridDim.x, ny = gridDim.y;
  const int wx = wk % nx, rest = wk / nx;
  const int wy = rest % ny, g = rest / ny;
  mgemm_body(A + (size_t)g * gA, lda, WT + (size_t)g * gW, bias, Cv, xres,
             ldc, K, ACT, STORE, APAD, (size_t)g * gC, wy * 128, wx * 64);
}

// batched variant: z-slice selects one of 3 jobs (uniform scalar branches)
__global__ void __launch_bounds__(256) k_mgemmB(const bf16* A0, const bf16* A1, const bf16* A2,
                                                const bf16* W0, const bf16* W1, const bf16* W2,
                                                const float* b0, const float* b1, const float* b2,
                                                void* C0, void* C1, void* C2,
                                                int lda, int ldc, int K, int zPer,
                                                int gA, int gW, int gC,
                                                int actm, int storem, int apadm) {
  const int wk = xcd_work_id();
  const int nx = gridDim.x, ny = gridDim.y;
  const int wx = wk % nx, rest = wk / nx;
  const int wy = rest % ny, z = rest / ny;
  const int sel = z / zPer, zz = z % zPer;
  const bf16* A = (sel == 0 ? A0 : sel == 1 ? A1 : A2) + (size_t)zz * gA;
  const bf16* W = (sel == 0 ? W0 : sel == 1 ? W1 : W2) + (size_t)zz * gW;
  const float* bias = sel == 0 ? b0 : sel == 1 ? b1 : b2;
  void* Cv = sel == 0 ? C0 : sel == 1 ? C1 : C2;
  mgemm_body(A, lda, W, bias, Cv, nullptr, ldc, K,
             (actm >> sel) & 1, (storem >> (4 * sel)) & 15, (apadm >> sel) & 1,
             (size_t)zz * gC, wy * 128, wx * 64);
}

// ---------------- gate GEMV ----------------
__global__ void __launch_bounds__(256) k_gates(const bf16* __restrict__ q, const bf16* __restrict__ kk,
                                               const float* __restrict__ wi, const float* __restrict__ wib,
                                               const float* __restrict__ wf, const float* __restrict__ wfb,
                                               float* __restrict__ it, float* __restrict__ ft) {
  int gid  = blockIdx.x * 4 + (threadIdx.x >> 6);
  int lane = threadIdx.x & 63;
  int which = gid >> 12;
  int m = gid & 4095;
  const bf16* row = (which ? kk : q) + (size_t)m * DIM2X;
  const float* w = which ? wf : wi;
  float s[8] = {0, 0, 0, 0, 0, 0, 0, 0};
  for (int d = lane; d < DIM2X; d += 64) {
    float xv = b2f(row[d]);
    const float4* wp = (const float4*)(w + d * 8);
    float4 w0 = wp[0], w1 = wp[1];
    s[0] += xv * w0.x; s[1] += xv * w0.y; s[2] += xv * w0.z; s[3] += xv * w0.w;
    s[4] += xv * w1.x; s[5] += xv * w1.y; s[6] += xv * w1.z; s[7] += xv * w1.w;
  }
#pragma unroll
  for (int off = 32; off; off >>= 1) {
#pragma unroll
    for (int h = 0; h < 8; h++) s[h] += __shfl_xor(s[h], off);
  }
  if (lane == 0) {
    int b_ = m >> 11, tt = m & 2047;
    const float* wb = which ? wfb : wib;
    float* dst = which ? ft : it;
#pragma unroll
    for (int h = 0; h < 8; h++)
      dst[((size_t)(b_ * NHEADS + h)) * SEQ + tt] = s[h] + wb[h];
  }
}

// ---------------- per-(b,h) scan ----------------
__global__ void __launch_bounds__(256) k_scan(const float* __restrict__ it, const float* __restrict__ ft,
                                              float* __restrict__ cs, float* __restrict__ md) {
  const int bh = blockIdx.x;
  const int t  = threadIdx.x;
  const float* fr = ft + (size_t)bh * SEQ;
  const float* ir = it + (size_t)bh * SEQ;
  float* csr = cs + (size_t)bh * SEQ;
  float* mdr = md + (size_t)bh * SEQ;
  __shared__ float tmp[256];
  float loc[8]; float run = 0.f;
#pragma unroll
  for (int j = 0; j < 8; j++) {
    float xv = fr[t * 8 + j];
    float ls = fminf(xv, 0.f) - log1pf(expf(-fabsf(xv)));
    run += ls; loc[j] = run;
  }
  tmp[t] = run;
  __syncthreads();
  for (int off = 1; off < 256; off <<= 1) {
    float add = (t >= off) ? tmp[t - off] : 0.f;
    __syncthreads();
    tmp[t] += add;
    __syncthreads();
  }
  float exc = (t == 0) ? 0.f : tmp[t - 1];
  float csv[8];
#pragma unroll
  for (int j = 0; j < 8; j++) { csv[j] = loc[j] + exc; csr[t * 8 + j] = csv[j]; }
  __syncthreads();
  float rmax = -INFINITY; float gm[8];
#pragma unroll
  for (int j = 0; j < 8; j++) {
    float gv = ir[t * 8 + j] - csv[j];
    rmax = fmaxf(rmax, gv); gm[j] = rmax;
  }
  tmp[t] = rmax;
  __syncthreads();
  for (int off = 1; off < 256; off <<= 1) {
    float other = (t >= off) ? tmp[t - off] : -INFINITY;
    __syncthreads();
    tmp[t] = fmaxf(tmp[t], other);
    __syncthreads();
  }
  float emax = (t == 0) ? -INFINITY : tmp[t - 1];
#pragma unroll
  for (int j = 0; j < 8; j++) mdr[t * 8 + j] = csv[j] + fmaxf(gm[j], emax);
}

// ---------------- MFMA causal attention: uniform two-tile blocks ----------------
// Block (pr, bh) processes tile pr THEN tile 31-pr: total trips = (2pr+2)+(2(31-pr)+2)
// = 68 for EVERY block -> perfect load balance by construction (no dispatch-order
// assumption). Grid (16,16) = 256 blocks. 4 LDS buffers, prefetch depth 2, one raw
// s_barrier per trip, counted vmcnt(8/4/0). exp2-domain softmax.
__global__ void __launch_bounds__(256) k_attn_mfma(const bf16* __restrict__ qh,
                                                   const bf16* __restrict__ kh,
                                                   const bf16* __restrict__ vt,
                                                   const float* __restrict__ cs,
                                                   const float* __restrict__ md,
                                                   const float* __restrict__ itl,
                                                   bf16* __restrict__ Hout) {
  const int bh = blockIdx.y, b_ = bh >> 3, h = bh & 7;
  const int pr = blockIdx.x;                  // pair 0..15
  const int tid = threadIdx.x;
  const int w = tid >> 6;                     // wave 0..3
  const int lane = tid & 63;
  const int col = lane & 15, quad = lane >> 4;
  const float L2E = 1.44269504f;

  __shared__ __align__(16) bf16 smK[4 * 4096]; // [buf][j 32][d 128], chunk^(j&7) swizzle
  __shared__ __align__(16) bf16 smV[4 * 4096]; // [buf][n 128][j 32], chunk^((n>>1)&3) swizzle
  __shared__ __align__(16) bf16 Sc[4][16][40];

  const size_t baseQK = ((size_t)b_ * SEQ) * DIM2X + (size_t)h * HDIM;
  const size_t vtb = (size_t)(h * HDIM) * 4096 + (size_t)b_ * SEQ;
  const float* csp = cs + (size_t)bh * SEQ;
  const float* mdp = md + (size_t)bh * SEQ;
  const float* itp = itl + (size_t)bh * SEQ;

  // staging sources (thread t covers LDS chunk t of each 8KB buffer; source pre-swizzled)
  const int kj = tid >> 4, kq = tid & 15;     // K: row kj (+16), chunk kq
  const bf16* gKs = kh + baseQK + (size_t)kj * DIM2X + ((kq ^ (kj & 7)) * 8);
  const int vn = tid >> 2, vq = tid & 3;      // V: row vn (+64), chunk vq
  const bf16* gVs = vt + vtb + (size_t)vn * 4096 + ((vq ^ ((vn >> 1) & 3)) * 8);

#define STAGE(buf, j0s)                                                        \
  do {                                                                         \
    bf16* dK = &smK[(buf) * 4096 + tid * 8];                                   \
    gl16(gKs + (size_t)(j0s) * DIM2X, dK);                                     \
    gl16(gKs + (size_t)((j0s) + 16) * DIM2X, dK + 2048);                       \
    bf16* dV = &smV[(buf) * 4096 + tid * 8];                                   \
    gl16(gVs + (j0s), dV);                                                     \
    gl16(gVs + (j0s) + (size_t)64 * 4096, dV + 2048);                          \
  } while (0)

  for (int ph = 0; ph < 2; ++ph) {
    const int tile = ph ? (31 - pr) : pr;
    const int i0 = tile * 64;
    const int i0w = i0 + w * 16;
    const int iwmax = i0w + 15;

    short8 qf[4];
#pragma unroll
    for (int kc = 0; kc < 4; kc++)
      qf[kc] = *(const short8*)(qh + baseQK + (size_t)(i0w + col) * DIM2X + kc * 32 + quad * 8);

    float cs_i[4], md_i[4];                   // log2 domain
#pragma unroll
    for (int r = 0; r < 4; r++) {
      int i = i0w + quad * 4 + r;
      cs_i[r] = csp[i] * L2E; md_i[r] = mdp[i] * L2E;
    }

    f32x4 accpv[8];
#pragma unroll
    for (int nb = 0; nb < 8; nb++) accpv[nb] = (f32x4){0.f, 0.f, 0.f, 0.f};
    float rs[4] = {0.f, 0.f, 0.f, 0.f};

    const int trips = 2 * tile + 2;
    STAGE(0, 0);
    STAGE(1, 32);                             // trips >= 2 always
    for (int t = 0; t < trips; ++t) {
      const int cur = t & 3;
      const int j0p = t * 32;
      if (t + 2 < trips) STAGE((t + 2) & 3, j0p + 64);
      if (t + 2 < trips)      asm volatile("s_waitcnt vmcnt(8)" ::: "memory");
      else if (t + 1 < trips) asm volatile("s_waitcnt vmcnt(4)" ::: "memory");
      else                    asm volatile("s_waitcnt vmcnt(0)" ::: "memory");
      __builtin_amdgcn_s_barrier();
      asm volatile("" ::: "memory");
      if (j0p <= iwmax) {
        // hoisted gate loads, log2 domain
        float g0 = (itp[j0p + col] - csp[j0p + col]) * L2E;
        float g1 = (itp[j0p + 16 + col] - csp[j0p + 16 + col]) * L2E;
        const bool jt1 = (j0p + 16 <= iwmax);
#pragma unroll
        for (int jt = 0; jt < 2; jt++) {
          const int j0 = j0p + jt * 16;
          float sv[4] = {0.f, 0.f, 0.f, 0.f};
          if (jt == 0 || jt1) {
            const int jj = jt * 16 + col;
            f32x4 aq = (f32x4){0.f, 0.f, 0.f, 0.f};
#pragma unroll
            for (int kc = 0; kc < 4; kc++) {
              short8 bk = *(const short8*)&smK[cur * 4096 + jj * 128 + ((((kc << 2) | quad) ^ (jj & 7)) << 3)];
              aq = __builtin_amdgcn_mfma_f32_16x16x32_bf16(qf[kc], bk, aq, 0, 0, 0);
            }
            const int j = j0 + col;
            const float gj = jt ? g1 : g0;
#pragma unroll
            for (int r = 0; r < 4; r++) {
              const int i = i0w + quad * 4 + r;
              // arg <= -5 by construction (md = exact row max); 2^-5 = 1/tau
              float s = (j <= i) ? exp2f(cs_i[r] + gj - md_i[r] - 5.f) * aq[r] : 0.f;
              sv[r] = s; rs[r] += s;
            }
          }
#pragma unroll
          for (int r = 0; r < 4; r++) Sc[w][quad * 4 + r][jt * 16 + col] = f2b(sv[r]);
        }
        // own-wave cross-lane LDS round-trip: force write completion before read (rule #18)
        asm volatile("s_waitcnt lgkmcnt(0)" ::: "memory");
        __builtin_amdgcn_sched_barrier(0);
        short8 af = *(const short8*)(&Sc[w][col][quad * 8]);
#pragma unroll
        for (int nb = 0; nb < 8; nb++) {
          const int rn = nb * 16 + col;
          short8 bv = *(const short8*)&smV[cur * 4096 + rn * 32 + ((quad ^ ((rn >> 1) & 3)) << 3)];
          accpv[nb] = __builtin_amdgcn_mfma_f32_16x16x32_bf16(af, bv, accpv[nb], 0, 0, 0);
        }
      }
      // no trailing barrier: 4 buffers tolerate the 1-trip skew
    }
    __syncthreads();                          // drain skew before buffer reuse (next phase)

    // wave-local epilogue (each wave owns full rows)
#pragma unroll
    for (int r = 0; r < 4; r++) {
      float v = rs[r];
      v += __shfl_xor(v, 1); v += __shfl_xor(v, 2);
      v += __shfl_xor(v, 4); v += __shfl_xor(v, 8);
      rs[r] = v;
    }
    float inv[4];
#pragma unroll
    for (int r = 0; r < 4; r++) {
      float maxit = fmaxf(fabsf(rs[r]), exp2f(fminf(-md_i[r], 43.f)));
      inv[r] = 1.f / (maxit + 1e-8f);
    }
#pragma unroll
    for (int nb = 0; nb < 8; nb++)
#pragma unroll
      for (int r = 0; r < 4; r++)
        Hout[baseQK + (size_t)(i0w + quad * 4 + r) * DIM2X + nb * 16 + col] = f2b(accpv[nb][r] * inv[r]);
  }
#undef STAGE
}

// ---------------- GroupNorm(per-head over 128) + skip*qk then *bgate ----------------
__global__ void __launch_bounds__(256) k_gnorm(const bf16* __restrict__ H, const bf16* __restrict__ qk,
                                               const bf16* __restrict__ bg,
                                               const float* __restrict__ gw, const float* __restrict__ gb,
                                               const float* __restrict__ skip, bf16* __restrict__ pre) {
  int gid  = blockIdx.x * 4 + (threadIdx.x >> 6);
  int lane = threadIdx.x & 63;
  int m = gid >> 3, h = gid & 7;
  const bf16* Hr = H + (size_t)m * DIM2X + (size_t)h * HDIM;
  float v0 = b2f(Hr[lane]), v1 = b2f(Hr[lane + 64]);
  float s = v0 + v1, sq = v0 * v0 + v1 * v1;
#pragma unroll
  for (int off = 32; off; off >>= 1) { s += __shfl_xor(s, off); sq += __shfl_xor(sq, off); }
  float mu  = s * (1.f / 128.f);
  float var = sq * (1.f / 128.f) - mu * mu;
  float rs  = rsqrtf(var + EPSF);
#pragma unroll
  for (int e = 0; e < 2; e++) {
    int c = lane + e * 64;
    int col = h * HDIM + c;
    float v = e ? v1 : v0;
    float hn = (v - mu) * rs * gw[col] + gb[col];
    size_t gidx = (size_t)m * DIM2X + col;
    pre[gidx] = f2b((hn + skip[col] * b2f(qk[gidx])) * b2f(bg[gidx]));
  }
}

extern "C" void kernel_launch(void* const* d_in, const int* in_sizes, int n_in,
                              void* d_out, int out_size, void* d_ws, size_t ws_size,
                              hipStream_t stream) {
  const float* x     = (const float*)d_in[0];
  const float* ln_w  = (const float*)d_in[1];
  const float* ln_b  = (const float*)d_in[2];
  const float* mlp1w = (const float*)d_in[3];
  const float* mlp1b = (const float*)d_in[4];
  const float* mlp2w = (const float*)d_in[5];
  const float* mlp2b = (const float*)d_in[6];
  const float* convw = (const float*)d_in[7];
  const float* convb = (const float*)d_in[8];
  const float* bqw   = (const float*)d_in[9];
  const float* bkw   = (const float*)d_in[10];
  const float* bvw   = (const float*)d_in[11];
  const float* wqw   = (const float*)d_in[12];
  const float* wqb   = (const float*)d_in[13];
  const float* wkw   = (const float*)d_in[14];
  const float* wkb   = (const float*)d_in[15];
  const float* wvw   = (const float*)d_in[16];
  const float* wvb   = (const float*)d_in[17];
  const float* wiw   = (const float*)d_in[18];
  const float* wib   = (const float*)d_in[19];
  const float* wfw   = (const float*)d_in[20];
  const float* wfb   = (const float*)d_in[21];
  const float* gnw   = (const float*)d_in[22];
  const float* gnb   = (const float*)d_in[23];
  const float* skip  = (const float*)d_in[24];
  const float* finw  = (const float*)d_in[25];
  const float* finb  = (const float*)d_in[26];
  float* out = (float*)d_out;

  float* GA  = (float*)d_ws;
  float* ITb = GA;
  float* FTb = GA + 32768;
  float* CSb = GA + 65536;
  float* MDb = GA + 98304;
  const size_t SLOT = 4u * 1024u * 1024u;
  bf16* S0 = (bf16*)((char*)d_ws + (1 << 20));
  bf16* S1 = S0 + SLOT;
  bf16* S2 = S1 + SLOT;
  bf16* S3 = S2 + SLOT;
  bf16* S4 = S3 + SLOT;
  bf16* S5 = S4 + SLOT;
  bf16* S6 = S5 + SLOT;
  bf16 *LN = S0, *BG = S2, *QKb = S3, *Qb = S4, *Kb = S5, *Vb = S6;
  bf16 *QH = S0, *KH = S1, *VT = S4, *Hb = S5, *PRE = S6;
  bf16* WTb   = S6 + SLOT;
  bf16* mlp1T = WTb;
  bf16* mlp2T = WTb + 524288;
  bf16* convT = WTb + 1048576;                 // [1024][4096] flat-K layout
  bf16* bqT   = WTb + 5242880;
  bf16* bkT   = bqT + 262144;
  bf16* bvT   = bkT + 262144;
  bf16* wqT   = bvT + 262144;
  bf16* wkT   = wqT + 1048576;
  bf16* wvT   = wkT + 1048576;
  bf16* finT  = wvT + 1048576;
  bf16* APD   = finT + 524288;                 // padded A: [2][2051][1024]

  // fused weight prep
  k_castT3<<<dim3(32, 16, 2), 256, 0, stream>>>(mlp1w, mlp2w, mlp2w, mlp1T, DIMX, DIM2X, 1, 0, 524288);
  k_castT3<<<dim3(32, 32, 3), 256, 0, stream>>>(wqw, wkw, wvw, wqT, DIM2X, DIM2X, 1, 0, 1048576);
  k_castT3<<<dim3(8, 8, 12), 256, 0, stream>>>(bqw, bkw, bvw, bqT, 256, 256, 4, 65536, 65536);
  k_castT3<<<dim3(16, 32, 1), 256, 0, stream>>>(finw, finw, finw, finT, DIM2X, DIMX, 1, 0, 524288);
  k_convwT<<<16384, 256, 0, stream>>>(convw, convT);
  k_zeropad<<<24, 256, 0, stream>>>(APD);

  k_layernorm<<<1024, 256, 0, stream>>>(x, ln_w, ln_b, LN);
  // batched mlp: sel0 = mlp1 -> APD (store3), sel1 = mlp2 -> BG (store0, silu)
  k_mgemmB<<<dim3(16, 32, 2), 256, 0, stream>>>(LN, LN, LN, mlp1T, mlp2T, mlp2T,
                                                mlp1b, mlp2b, mlp2b, APD, BG, BG,
                                                DIMX, DIM2X, DIMX, 1, 0, 0, 0,
                                                /*actm*/ 0b10, /*storem*/ 3 | (0 << 4), /*apadm*/ 0);
  // causal conv1d == single GEMM: K=4096 contiguous window over padded rows t..t+3
  k_mgemm<1, 0, 0><<<dim3(16, 16, 2), 256, 0, stream>>>(APD, DIM2X, convT, convb, QKb, nullptr,
                                                        DIM2X, 4096, PADROWS * DIM2X, 0, SEQ * DIM2X);
  // batched block-diag q/k/v: 12 z-slices (3 weights x 4 groups)
  k_mgemmB<<<dim3(4, 32, 12), 256, 0, stream>>>(QKb, QKb, APD, bqT, bkT, bvT,
                                                nullptr, nullptr, nullptr, Qb, Kb, Vb,
                                                DIM2X, DIM2X, 256, 4, 256, 65536, 256,
                                                /*actm*/ 0, /*storem*/ 0, /*apadm*/ 0b100);
  k_gates<<<2048, 256, 0, stream>>>(Qb, Kb, wiw, wib, wfw, wfb, ITb, FTb);
  k_scan<<<16, 256, 0, stream>>>(ITb, FTb, CSb, MDb);
  // batched wq/wk/wv: sel2 writes V^T (store1)
  k_mgemmB<<<dim3(16, 32, 3), 256, 0, stream>>>(Qb, Kb, Vb, wqT, wkT, wvT,
                                                wqb, wkb, wvb, QH, KH, VT,
                                                DIM2X, DIM2X, DIM2X, 1, 0, 0, 0,
                                                /*actm*/ 0, /*storem*/ 0 | (0 << 4) | (1 << 8), /*apadm*/ 0);
  k_attn_mfma<<<dim3(16, 16), 256, 0, stream>>>(QH, KH, VT, CSb, MDb, ITb, Hb);
  k_gnorm<<<8192, 256, 0, stream>>>(Hb, QKb, BG, gnw, gnb, skip, PRE);
  k_mgemm<0, 2, 0><<<dim3(8, 32), 256, 0, stream>>>(PRE, DIM2X, finT, finb, out, x, DIMX, DIM2X, 0, 0, 0);
}

// Round 11
// 444.904 us; speedup vs baseline: 1.4676x; 1.0351x over previous
//
#include <hip/hip_runtime.h>
#include <hip/hip_bf16.h>
#include <cmath>

typedef __hip_bfloat16 bf16;
typedef __attribute__((ext_vector_type(8))) short short8;   // 8 bf16 (4 VGPRs)
typedef __attribute__((ext_vector_type(4))) float f32x4;

#define SEQ   2048
#define DIMX  512
#define DIM2X 1024
#define NHEADS 8
#define HDIM  128
#define EPSF  1e-5f
#define PADROWS 2051   // 3 zero rows + 2048 per batch

__device__ __forceinline__ float b2f(bf16 v) { return __bfloat162float(v); }
__device__ __forceinline__ bf16 f2b(float f) { return __float2bfloat16(f); }
__device__ __forceinline__ unsigned short f2bu(float f) { bf16 t = __float2bfloat16(f); return *(unsigned short*)&t; }

// async global->LDS, 16B per lane. LDS dest must be linear in lane order (wave base + lane*16).
__device__ __forceinline__ void gl16(const bf16* g, bf16* l) {
  __builtin_amdgcn_global_load_lds((const __attribute__((address_space(1))) void*)g,
                                   (__attribute__((address_space(3))) void*)l, 16, 0, 0);
}

// ---------------- LayerNorm: one wave per row of 512 (fp32 in, bf16 out) ----------------
__global__ void __launch_bounds__(256) k_layernorm(const float* __restrict__ x,
                                                   const float* __restrict__ w,
                                                   const float* __restrict__ b,
                                                   bf16* __restrict__ out) {
  int row  = blockIdx.x * 4 + (threadIdx.x >> 6);
  int lane = threadIdx.x & 63;
  const float* xr = x + (size_t)row * DIMX;
  float v[8]; float s = 0.f, sq = 0.f;
#pragma unroll
  for (int i = 0; i < 8; i++) {
    float f = xr[lane + i * 64];
    v[i] = f; s += f; sq += f * f;
  }
#pragma unroll
  for (int off = 32; off; off >>= 1) { s += __shfl_xor(s, off); sq += __shfl_xor(sq, off); }
  float mu  = s * (1.f / DIMX);
  float var = sq * (1.f / DIMX) - mu * mu;
  float rs  = rsqrtf(var + EPSF);
  bf16* o = out + (size_t)row * DIMX;
#pragma unroll
  for (int i = 0; i < 8; i++) {
    int c = lane + i * 64;
    o[c] = f2b((v[i] - mu) * rs * w[c] + b[c]);
  }
}

// ---------------- fused weight cast+transpose: dst = sel-th of {W0,W1,W2} ----------------
__global__ void __launch_bounds__(256) k_castT3(const float* __restrict__ W0,
                                                const float* __restrict__ W1,
                                                const float* __restrict__ W2,
                                                bf16* __restrict__ WT,
                                                int K, int N, int innerZ, int gW, int gT) {
  __shared__ float t[32][33];
  const int z = blockIdx.z;
  const int sel = z / innerZ, zz = z % innerZ;
  const float* W = (sel == 0 ? W0 : sel == 1 ? W1 : W2) + (size_t)zz * gW;
  bf16* T = WT + (size_t)(sel * innerZ + zz) * gT;
  const int k0 = blockIdx.y * 32, n0 = blockIdx.x * 32;
  const int r = threadIdx.x >> 5, c = threadIdx.x & 31;
#pragma unroll
  for (int i = 0; i < 4; i++)
    t[r + i * 8][c] = W[(size_t)(k0 + r + i * 8) * N + n0 + c];
  __syncthreads();
#pragma unroll
  for (int i = 0; i < 4; i++)
    T[(size_t)(n0 + r + i * 8) * K + k0 + c] = f2b(t[c][r + i * 8]);
}

// ---------------- conv weight reshape: WT2[o][kk*1024+i] = bf16(conv_w[o][i][kk]) ----------------
__global__ void __launch_bounds__(256) k_convwT(const float* __restrict__ cw, bf16* __restrict__ wc) {
  int idx = blockIdx.x * 256 + threadIdx.x;     // out-ordered: (o, kk, i)
  int o = idx >> 12, z = idx & 4095, kk = z >> 10, i = z & 1023;
  wc[idx] = f2b(cw[(size_t)o * 4096 + i * 4 + kk]);
}

// ---------------- zero the 3 pad rows before each batch of padded A ----------------
__global__ void __launch_bounds__(256) k_zeropad(bf16* __restrict__ p) {
  int idx = blockIdx.x * 256 + threadIdx.x;     // 6144 total
  int b = idx / 3072, off = idx % 3072;
  p[(size_t)b * PADROWS * DIM2X + off] = f2b(0.f);
}

// ---------------- GEMM body: 128x64 block, 4 waves, counted-vmcnt pipeline ----------------
// 4 LDS buffers, prefetch depth 2, ONE raw s_barrier per k-step. Counted window holds
// ONLY staging loads (no stores precede a counted wait).
__device__ __forceinline__ void mgemm_body(const bf16* A, int lda, const bf16* WT,
                                           const float* bias, void* Cv, const float* xres,
                                           int ldc, int K, int ACT, int STORE, int APAD,
                                           size_t coff, int bm, int bn) {
  __shared__ __align__(16) bf16 smA[4][128 * 32];
  __shared__ __align__(16) bf16 smB[4][64 * 32];
  const int tid  = threadIdx.x;
  const int lane = tid & 63;
  const int w = tid >> 6, wy = w >> 1, wx = w & 1;
  const int col = lane & 15, quad = lane >> 4;

  const int r4 = tid >> 2, c8 = (tid & 3) * 8;
  int ra0 = bm + r4, ra1 = bm + 64 + r4;
  if (APAD) { ra0 += (ra0 >> 11) * 3 + 3; ra1 += (ra1 >> 11) * 3 + 3; }
  const bf16* gA0 = A + (size_t)ra0 * lda + c8;
  const bf16* gA1 = A + (size_t)ra1 * lda + c8;
  const bf16* gB0 = WT + (size_t)(bn + r4) * K + c8;

  f32x4 acc[4][2];
#pragma unroll
  for (int a = 0; a < 4; a++)
#pragma unroll
    for (int b = 0; b < 2; b++) acc[a][b] = (f32x4){0.f, 0.f, 0.f, 0.f};

  const int laoff = (wy * 64) * 32, lboff = (wx * 32) * 32;
  const int lsa = r4 * 32 + c8;
  const int nsteps = K >> 5;

#define GSTAGE(buf, k0s)                                                       \
  do {                                                                         \
    gl16(gA0 + (k0s), &smA[buf][lsa]);                                         \
    gl16(gA1 + (k0s), &smA[buf][64 * 32 + lsa]);                               \
    gl16(gB0 + (k0s), &smB[buf][lsa]);                                         \
  } while (0)

  GSTAGE(0, 0);
  if (nsteps > 1) GSTAGE(1, 32);
  for (int s = 0; s < nsteps; ++s) {
    if (s + 2 < nsteps) GSTAGE((s + 2) & 3, (s + 2) * 32);
    if (s + 2 < nsteps)      asm volatile("s_waitcnt vmcnt(6)" ::: "memory");
    else if (s + 1 < nsteps) asm volatile("s_waitcnt vmcnt(3)" ::: "memory");
    else                     asm volatile("s_waitcnt vmcnt(0)" ::: "memory");
    __builtin_amdgcn_s_barrier();
    asm volatile("" ::: "memory");
    const bf16* bA = smA[s & 3];
    const bf16* bB = smB[s & 3];
    short8 af[4], bfr[2];
#pragma unroll
    for (int mt = 0; mt < 4; mt++)
      af[mt] = *(const short8*)&bA[laoff + (mt * 16 + col) * 32 + quad * 8];
#pragma unroll
    for (int nt = 0; nt < 2; nt++)
      bfr[nt] = *(const short8*)&bB[lboff + (nt * 16 + col) * 32 + quad * 8];
#pragma unroll
    for (int mt = 0; mt < 4; mt++)
#pragma unroll
      for (int nt = 0; nt < 2; nt++)
        acc[mt][nt] = __builtin_amdgcn_mfma_f32_16x16x32_bf16(af[mt], bfr[nt], acc[mt][nt], 0, 0, 0);
    // no trailing barrier: 4 buffers tolerate the 1-trip skew
  }
#undef GSTAGE

#pragma unroll
  for (int mt = 0; mt < 4; mt++) {
#pragma unroll
    for (int nt = 0; nt < 2; nt++) {
      const int n = bn + wx * 32 + nt * 16 + col;
      const int mrow0 = bm + wy * 64 + mt * 16 + quad * 4;
      float bs = bias ? bias[n] : 0.f;
      if (STORE == 1) {
        bf16* C = (bf16*)Cv + coff;
        ushort4 pk;
        pk.x = f2bu(acc[mt][nt][0] + bs); pk.y = f2bu(acc[mt][nt][1] + bs);
        pk.z = f2bu(acc[mt][nt][2] + bs); pk.w = f2bu(acc[mt][nt][3] + bs);
        *(ushort4*)(C + (size_t)n * 4096 + mrow0) = pk;
      } else if (STORE == 2) {
        float* O = (float*)Cv + coff;
#pragma unroll
        for (int r = 0; r < 4; r++) {
          size_t gi = (size_t)(mrow0 + r) * ldc + n;
          O[gi] = acc[mt][nt][r] + bs + xres[gi];
        }
      } else if (STORE == 3) {
        bf16* C = (bf16*)Cv;
        const int pr = (mrow0 >> 11) * 3 + 3;   // all 4 rows in same batch (128-blocks)
#pragma unroll
        for (int r = 0; r < 4; r++)
          C[(size_t)(mrow0 + pr + r) * ldc + n] = f2b(acc[mt][nt][r] + bs);
      } else {
        bf16* C = (bf16*)Cv + coff;
#pragma unroll
        for (int r = 0; r < 4; r++) {
          float v = acc[mt][nt][r] + bs;
          if (ACT == 1) v = v / (1.f + expf(-v));  // silu
          C[(size_t)(mrow0 + r) * ldc + n] = f2b(v);
        }
      }
    }
  }
}

// T1 bijective XCD swizzle (m204 form, r=0 case; requires nwg % 8 == 0 — true for all
// launches below). Blocks round-robining to one XCD get CONSECUTIVE work ids ->
// blocks sharing an A/B panel chunk co-locate on one XCD's L2. (round 9: fleet ~ -23us)
__device__ __forceinline__ int xcd_work_id() {
  const int nx = gridDim.x, ny = gridDim.y;
  const int d = blockIdx.x + nx * (blockIdx.y + ny * blockIdx.z);
  const int q = (nx * ny * (int)gridDim.z) >> 3;
  return (d & 7) * q + (d >> 3);
}

// template variant (conv, fin)
template <int ACT, int STORE, int APAD>
__global__ void __launch_bounds__(256) k_mgemm(const bf16* __restrict__ A, int lda,
                                               const bf16* __restrict__ WT,
                                               const float* __restrict__ bias,
                                               void* __restrict__ Cv,
                                               const float* __restrict__ xres,
                                               int ldc, int K,
                                               int gA, int gW, int gC) {
  const int wk = xcd_work_id();
  const int nx = gridDim.x, ny = gridDim.y;
  const int wx = wk % nx, rest = wk / nx;
  const int wy = rest % ny, g = rest / ny;
  mgemm_body(A + (size_t)g * gA, lda, WT + (size_t)g * gW, bias, Cv, xres,
             ldc, K, ACT, STORE, APAD, (size_t)g * gC, wy * 128, wx * 64);
}

// batched variant: z-slice selects one of 3 jobs (uniform scalar branches)
__global__ void __launch_bounds__(256) k_mgemmB(const bf16* A0, const bf16* A1, const bf16* A2,
                                                const bf16* W0, const bf16* W1, const bf16* W2,
                                                const float* b0, const float* b1, const float* b2,
                                                void* C0, void* C1, void* C2,
                                                int lda, int ldc, int K, int zPer,
                                                int gA, int gW, int gC,
                                                int actm, int storem, int apadm) {
  const int wk = xcd_work_id();
  const int nx = gridDim.x, ny = gridDim.y;
  const int wx = wk % nx, rest = wk / nx;
  const int wy = rest % ny, z = rest / ny;
  const int sel = z / zPer, zz = z % zPer;
  const bf16* A = (sel == 0 ? A0 : sel == 1 ? A1 : A2) + (size_t)zz * gA;
  const bf16* W = (sel == 0 ? W0 : sel == 1 ? W1 : W2) + (size_t)zz * gW;
  const float* bias = sel == 0 ? b0 : sel == 1 ? b1 : b2;
  void* Cv = sel == 0 ? C0 : sel == 1 ? C1 : C2;
  mgemm_body(A, lda, W, bias, Cv, nullptr, ldc, K,
             (actm >> sel) & 1, (storem >> (4 * sel)) & 15, (apadm >> sel) & 1,
             (size_t)zz * gC, wy * 128, wx * 64);
}

// ---------------- gate GEMV ----------------
__global__ void __launch_bounds__(256) k_gates(const bf16* __restrict__ q, const bf16* __restrict__ kk,
                                               const float* __restrict__ wi, const float* __restrict__ wib,
                                               const float* __restrict__ wf, const float* __restrict__ wfb,
                                               float* __restrict__ it, float* __restrict__ ft) {
  int gid  = blockIdx.x * 4 + (threadIdx.x >> 6);
  int lane = threadIdx.x & 63;
  int which = gid >> 12;
  int m = gid & 4095;
  const bf16* row = (which ? kk : q) + (size_t)m * DIM2X;
  const float* w = which ? wf : wi;
  float s[8] = {0, 0, 0, 0, 0, 0, 0, 0};
  for (int d = lane; d < DIM2X; d += 64) {
    float xv = b2f(row[d]);
    const float4* wp = (const float4*)(w + d * 8);
    float4 w0 = wp[0], w1 = wp[1];
    s[0] += xv * w0.x; s[1] += xv * w0.y; s[2] += xv * w0.z; s[3] += xv * w0.w;
    s[4] += xv * w1.x; s[5] += xv * w1.y; s[6] += xv * w1.z; s[7] += xv * w1.w;
  }
#pragma unroll
  for (int off = 32; off; off >>= 1) {
#pragma unroll
    for (int h = 0; h < 8; h++) s[h] += __shfl_xor(s[h], off);
  }
  if (lane == 0) {
    int b_ = m >> 11, tt = m & 2047;
    const float* wb = which ? wfb : wib;
    float* dst = which ? ft : it;
#pragma unroll
    for (int h = 0; h < 8; h++)
      dst[((size_t)(b_ * NHEADS + h)) * SEQ + tt] = s[h] + wb[h];
  }
}

// ---------------- per-(b,h) scan ----------------
__global__ void __launch_bounds__(256) k_scan(const float* __restrict__ it, const float* __restrict__ ft,
                                              float* __restrict__ cs, float* __restrict__ md) {
  const int bh = blockIdx.x;
  const int t  = threadIdx.x;
  const float* fr = ft + (size_t)bh * SEQ;
  const float* ir = it + (size_t)bh * SEQ;
  float* csr = cs + (size_t)bh * SEQ;
  float* mdr = md + (size_t)bh * SEQ;
  __shared__ float tmp[256];
  float loc[8]; float run = 0.f;
#pragma unroll
  for (int j = 0; j < 8; j++) {
    float xv = fr[t * 8 + j];
    float ls = fminf(xv, 0.f) - log1pf(expf(-fabsf(xv)));
    run += ls; loc[j] = run;
  }
  tmp[t] = run;
  __syncthreads();
  for (int off = 1; off < 256; off <<= 1) {
    float add = (t >= off) ? tmp[t - off] : 0.f;
    __syncthreads();
    tmp[t] += add;
    __syncthreads();
  }
  float exc = (t == 0) ? 0.f : tmp[t - 1];
  float csv[8];
#pragma unroll
  for (int j = 0; j < 8; j++) { csv[j] = loc[j] + exc; csr[t * 8 + j] = csv[j]; }
  __syncthreads();
  float rmax = -INFINITY; float gm[8];
#pragma unroll
  for (int j = 0; j < 8; j++) {
    float gv = ir[t * 8 + j] - csv[j];
    rmax = fmaxf(rmax, gv); gm[j] = rmax;
  }
  tmp[t] = rmax;
  __syncthreads();
  for (int off = 1; off < 256; off <<= 1) {
    float other = (t >= off) ? tmp[t - off] : -INFINITY;
    __syncthreads();
    tmp[t] = fmaxf(tmp[t], other);
    __syncthreads();
  }
  float emax = (t == 0) ? -INFINITY : tmp[t - 1];
#pragma unroll
  for (int j = 0; j < 8; j++) mdr[t * 8 + j] = csv[j] + fmaxf(gm[j], emax);
}

// ---------------- MFMA causal attention (round-8 structure) + FUSED GroupNorm epilogue ----------------
// Single tile per block, grid (32,16). 4 LDS buffers, prefetch depth 2, one raw s_barrier
// per trip, counted vmcnt(8/4/0) — window holds ONLY staging loads.
// Epilogue: each wave holds all 128 head-dims of its 16 rows -> GroupNorm via 4 shfl_xor
// steps within the 16-lane quad group; writes PRE = (gn(H)*gw+gb + skip*qk)*bg directly.
// ROUND-11 FIX: rbase must include baseQK (batch offset b_*SEQ*DIM2X + h*HDIM) — round 10
// dropped it, writing batch 1 onto batch 0 (absmax 0.51).
__global__ void __launch_bounds__(256) k_attn_mfma(const bf16* __restrict__ qh,
                                                   const bf16* __restrict__ kh,
                                                   const bf16* __restrict__ vt,
                                                   const float* __restrict__ cs,
                                                   const float* __restrict__ md,
                                                   const float* __restrict__ itl,
                                                   const bf16* __restrict__ qk,
                                                   const bf16* __restrict__ bg,
                                                   const float* __restrict__ gw,
                                                   const float* __restrict__ gb,
                                                   const float* __restrict__ skip,
                                                   bf16* __restrict__ pre) {
  const int bh = blockIdx.y, b_ = bh >> 3, h = bh & 7;
  const int bx = blockIdx.x;
  const int tile = ((blockIdx.y >> 3) & 1) ? bx : 31 - bx;   // balanced pairing heuristic
  const int i0 = tile * 64;
  const int tid = threadIdx.x;
  const int w = tid >> 6;                     // wave 0..3 -> i-rows i0+16w..
  const int lane = tid & 63;
  const int col = lane & 15, quad = lane >> 4;
  const int i0w = i0 + w * 16;
  const int iwmax = i0w + 15;
  const float L2E = 1.44269504f;

  __shared__ __align__(16) bf16 smK[4 * 4096]; // [buf][j 32][d 128], chunk^(j&7) swizzle
  __shared__ __align__(16) bf16 smV[4 * 4096]; // [buf][n 128][j 32], chunk^((n>>1)&3) swizzle
  __shared__ __align__(16) bf16 Sc[4][16][40];

  const size_t baseQK = ((size_t)b_ * SEQ) * DIM2X + (size_t)h * HDIM;
  const size_t vtb = (size_t)(h * HDIM) * 4096 + (size_t)b_ * SEQ;
  const float* csp = cs + (size_t)bh * SEQ;
  const float* mdp = md + (size_t)bh * SEQ;
  const float* itp = itl + (size_t)bh * SEQ;

  short8 qf[4];
#pragma unroll
  for (int kc = 0; kc < 4; kc++)
    qf[kc] = *(const short8*)(qh + baseQK + (size_t)(i0w + col) * DIM2X + kc * 32 + quad * 8);

  float cs_i[4], md_i[4];                     // log2 domain
#pragma unroll
  for (int r = 0; r < 4; r++) {
    int i = i0w + quad * 4 + r;
    cs_i[r] = csp[i] * L2E; md_i[r] = mdp[i] * L2E;
  }

  f32x4 accpv[8];
#pragma unroll
  for (int nb = 0; nb < 8; nb++) accpv[nb] = (f32x4){0.f, 0.f, 0.f, 0.f};
  float rs[4] = {0.f, 0.f, 0.f, 0.f};

  // staging sources (thread t covers LDS chunk t of each 8KB buffer; source pre-swizzled)
  const int kj = tid >> 4, kq = tid & 15;     // K: row kj (+16), chunk kq
  const bf16* gKs = kh + baseQK + (size_t)kj * DIM2X + ((kq ^ (kj & 7)) * 8);
  const int vn = tid >> 2, vq = tid & 3;      // V: row vn (+64), chunk vq
  const bf16* gVs = vt + vtb + (size_t)vn * 4096 + ((vq ^ ((vn >> 1) & 3)) * 8);

  const int trips = 2 * tile + 2;

#define STAGE(buf, j0s)                                                        \
  do {                                                                         \
    bf16* dK = &smK[(buf) * 4096 + tid * 8];                                   \
    gl16(gKs + (size_t)(j0s) * DIM2X, dK);                                     \
    gl16(gKs + (size_t)((j0s) + 16) * DIM2X, dK + 2048);                       \
    bf16* dV = &smV[(buf) * 4096 + tid * 8];                                   \
    gl16(gVs + (j0s), dV);                                                     \
    gl16(gVs + (j0s) + (size_t)64 * 4096, dV + 2048);                          \
  } while (0)

  STAGE(0, 0);
  STAGE(1, 32);                               // trips >= 2 always
  for (int t = 0; t < trips; ++t) {
    const int cur = t & 3;
    const int j0p = t * 32;
    if (t + 2 < trips) STAGE((t + 2) & 3, j0p + 64);
    if (t + 2 < trips)      asm volatile("s_waitcnt vmcnt(8)" ::: "memory");
    else if (t + 1 < trips) asm volatile("s_waitcnt vmcnt(4)" ::: "memory");
    else                    asm volatile("s_waitcnt vmcnt(0)" ::: "memory");
    __builtin_amdgcn_s_barrier();
    asm volatile("" ::: "memory");
    if (j0p <= iwmax) {
      // hoisted gate loads, log2 domain
      float g0 = (itp[j0p + col] - csp[j0p + col]) * L2E;
      float g1 = (itp[j0p + 16 + col] - csp[j0p + 16 + col]) * L2E;
      const bool jt1 = (j0p + 16 <= iwmax);
#pragma unroll
      for (int jt = 0; jt < 2; jt++) {
        const int j0 = j0p + jt * 16;
        float sv[4] = {0.f, 0.f, 0.f, 0.f};
        if (jt == 0 || jt1) {
          const int jj = jt * 16 + col;
          f32x4 aq = (f32x4){0.f, 0.f, 0.f, 0.f};
#pragma unroll
          for (int kc = 0; kc < 4; kc++) {
            short8 bk = *(const short8*)&smK[cur * 4096 + jj * 128 + ((((kc << 2) | quad) ^ (jj & 7)) << 3)];
            aq = __builtin_amdgcn_mfma_f32_16x16x32_bf16(qf[kc], bk, aq, 0, 0, 0);
          }
          const int j = j0 + col;
          const float gj = jt ? g1 : g0;
#pragma unroll
          for (int r = 0; r < 4; r++) {
            const int i = i0w + quad * 4 + r;
            // arg <= -5 by construction (md = exact row max); 2^-5 = 1/tau
            float s = (j <= i) ? exp2f(cs_i[r] + gj - md_i[r] - 5.f) * aq[r] : 0.f;
            sv[r] = s; rs[r] += s;
          }
        }
#pragma unroll
        for (int r = 0; r < 4; r++) Sc[w][quad * 4 + r][jt * 16 + col] = f2b(sv[r]);
      }
      // own-wave cross-lane LDS round-trip: force write completion before read (rule #18)
      asm volatile("s_waitcnt lgkmcnt(0)" ::: "memory");
      __builtin_amdgcn_sched_barrier(0);
      short8 af = *(const short8*)(&Sc[w][col][quad * 8]);
#pragma unroll
      for (int nb = 0; nb < 8; nb++) {
        const int rn = nb * 16 + col;
        short8 bv = *(const short8*)&smV[cur * 4096 + rn * 32 + ((quad ^ ((rn >> 1) & 3)) << 3)];
        accpv[nb] = __builtin_amdgcn_mfma_f32_16x16x32_bf16(af, bv, accpv[nb], 0, 0, 0);
      }
    }
    // no trailing barrier: 4 buffers tolerate the 1-trip skew
  }
#undef STAGE

  // ---- fused epilogue: H normalize + GroupNorm + skip/bgate, write PRE ----
#pragma unroll
  for (int r = 0; r < 4; r++) {
    float v = rs[r];
    v += __shfl_xor(v, 1); v += __shfl_xor(v, 2);
    v += __shfl_xor(v, 4); v += __shfl_xor(v, 8);
    rs[r] = v;
  }
  float inv[4];
#pragma unroll
  for (int r = 0; r < 4; r++) {
    float maxit = fmaxf(fabsf(rs[r]), exp2f(fminf(-md_i[r], 43.f)));
    inv[r] = 1.f / (maxit + 1e-8f);
  }
  // per-col params (col = h*128 + nb*16 + colIdx; independent of r)
  float gwv[8], gbv[8], skv[8];
#pragma unroll
  for (int nb = 0; nb < 8; nb++) {
    int c = h * HDIM + nb * 16 + col;
    gwv[nb] = gw[c]; gbv[nb] = gb[c]; skv[nb] = skip[c];
  }
#pragma unroll
  for (int r = 0; r < 4; r++) {
    const int row = i0w + quad * 4 + r;       // row within batch
    float s1 = 0.f, s2 = 0.f;
#pragma unroll
    for (int nb = 0; nb < 8; nb++) {
      float v = accpv[nb][r] * inv[r];
      s1 += v; s2 += v * v;
    }
    // reduce over the 16 lanes of this quad-group (all 128 head-dims of this row)
    s1 += __shfl_xor(s1, 1); s2 += __shfl_xor(s2, 1);
    s1 += __shfl_xor(s1, 2); s2 += __shfl_xor(s2, 2);
    s1 += __shfl_xor(s1, 4); s2 += __shfl_xor(s2, 4);
    s1 += __shfl_xor(s1, 8); s2 += __shfl_xor(s2, 8);
    float mu  = s1 * (1.f / 128.f);
    float var = s2 * (1.f / 128.f) - mu * mu;
    float rsg = rsqrtf(var + EPSF);
    const size_t rbase = baseQK + (size_t)row * DIM2X;   // FIX: include batch+head offset
#pragma unroll
    for (int nb = 0; nb < 8; nb++) {
      float hv = accpv[nb][r] * inv[r];
      float hn = (hv - mu) * rsg * gwv[nb] + gbv[nb];
      size_t gi = rbase + nb * 16 + col;
      pre[gi] = f2b((hn + skv[nb] * b2f(qk[gi])) * b2f(bg[gi]));
    }
  }
}

extern "C" void kernel_launch(void* const* d_in, const int* in_sizes, int n_in,
                              void* d_out, int out_size, void* d_ws, size_t ws_size,
                              hipStream_t stream) {
  const float* x     = (const float*)d_in[0];
  const float* ln_w  = (const float*)d_in[1];
  const float* ln_b  = (const float*)d_in[2];
  const float* mlp1w = (const float*)d_in[3];
  const float* mlp1b = (const float*)d_in[4];
  const float* mlp2w = (const float*)d_in[5];
  const float* mlp2b = (const float*)d_in[6];
  const float* convw = (const float*)d_in[7];
  const float* convb = (const float*)d_in[8];
  const float* bqw   = (const float*)d_in[9];
  const float* bkw   = (const float*)d_in[10];
  const float* bvw   = (const float*)d_in[11];
  const float* wqw   = (const float*)d_in[12];
  const float* wqb   = (const float*)d_in[13];
  const float* wkw   = (const float*)d_in[14];
  const float* wkb   = (const float*)d_in[15];
  const float* wvw   = (const float*)d_in[16];
  const float* wvb   = (const float*)d_in[17];
  const float* wiw   = (const float*)d_in[18];
  const float* wib   = (const float*)d_in[19];
  const float* wfw   = (const float*)d_in[20];
  const float* wfb   = (const float*)d_in[21];
  const float* gnw   = (const float*)d_in[22];
  const float* gnb   = (const float*)d_in[23];
  const float* skip  = (const float*)d_in[24];
  const float* finw  = (const float*)d_in[25];
  const float* finb  = (const float*)d_in[26];
  float* out = (float*)d_out;

  float* GA  = (float*)d_ws;
  float* ITb = GA;
  float* FTb = GA + 32768;
  float* CSb = GA + 65536;
  float* MDb = GA + 98304;
  const size_t SLOT = 4u * 1024u * 1024u;
  bf16* S0 = (bf16*)((char*)d_ws + (1 << 20));
  bf16* S1 = S0 + SLOT;
  bf16* S2 = S1 + SLOT;
  bf16* S3 = S2 + SLOT;
  bf16* S4 = S3 + SLOT;
  bf16* S5 = S4 + SLOT;
  bf16* S6 = S5 + SLOT;
  bf16 *LN = S0, *BG = S2, *QKb = S3, *Qb = S4, *Kb = S5, *Vb = S6;
  bf16 *QH = S0, *KH = S1, *VT = S4, *PRE = S6;
  bf16* WTb   = S6 + SLOT;
  bf16* mlp1T = WTb;
  bf16* mlp2T = WTb + 524288;
  bf16* convT = WTb + 1048576;                 // [1024][4096] flat-K layout
  bf16* bqT   = WTb + 5242880;
  bf16* bkT   = bqT + 262144;
  bf16* bvT   = bkT + 262144;
  bf16* wqT   = bvT + 262144;
  bf16* wkT   = wqT + 1048576;
  bf16* wvT   = wkT + 1048576;
  bf16* finT  = wvT + 1048576;
  bf16* APD   = finT + 524288;                 // padded A: [2][2051][1024]

  // fused weight prep
  k_castT3<<<dim3(32, 16, 2), 256, 0, stream>>>(mlp1w, mlp2w, mlp2w, mlp1T, DIMX, DIM2X, 1, 0, 524288);
  k_castT3<<<dim3(32, 32, 3), 256, 0, stream>>>(wqw, wkw, wvw, wqT, DIM2X, DIM2X, 1, 0, 1048576);
  k_castT3<<<dim3(8, 8, 12), 256, 0, stream>>>(bqw, bkw, bvw, bqT, 256, 256, 4, 65536, 65536);
  k_castT3<<<dim3(16, 32, 1), 256, 0, stream>>>(finw, finw, finw, finT, DIM2X, DIMX, 1, 0, 524288);
  k_convwT<<<16384, 256, 0, stream>>>(convw, convT);
  k_zeropad<<<24, 256, 0, stream>>>(APD);

  k_layernorm<<<1024, 256, 0, stream>>>(x, ln_w, ln_b, LN);
  // batched mlp: sel0 = mlp1 -> APD (store3), sel1 = mlp2 -> BG (store0, silu)
  k_mgemmB<<<dim3(16, 32, 2), 256, 0, stream>>>(LN, LN, LN, mlp1T, mlp2T, mlp2T,
                                                mlp1b, mlp2b, mlp2b, APD, BG, BG,
                                                DIMX, DIM2X, DIMX, 1, 0, 0, 0,
                                                /*actm*/ 0b10, /*storem*/ 3 | (0 << 4), /*apadm*/ 0);
  // causal conv1d == single GEMM: K=4096 contiguous window over padded rows t..t+3
  k_mgemm<1, 0, 0><<<dim3(16, 16, 2), 256, 0, stream>>>(APD, DIM2X, convT, convb, QKb, nullptr,
                                                        DIM2X, 4096, PADROWS * DIM2X, 0, SEQ * DIM2X);
  // batched block-diag q/k/v: 12 z-slices (3 weights x 4 groups)
  k_mgemmB<<<dim3(4, 32, 12), 256, 0, stream>>>(QKb, QKb, APD, bqT, bkT, bvT,
                                                nullptr, nullptr, nullptr, Qb, Kb, Vb,
                                                DIM2X, DIM2X, 256, 4, 256, 65536, 256,
                                                /*actm*/ 0, /*storem*/ 0, /*apadm*/ 0b100);
  k_gates<<<2048, 256, 0, stream>>>(Qb, Kb, wiw, wib, wfw, wfb, ITb, FTb);
  k_scan<<<16, 256, 0, stream>>>(ITb, FTb, CSb, MDb);
  // batched wq/wk/wv: sel2 writes V^T (store1)
  k_mgemmB<<<dim3(16, 32, 3), 256, 0, stream>>>(Qb, Kb, Vb, wqT, wkT, wvT,
                                                wqb, wkb, wvb, QH, KH, VT,
                                                DIM2X, DIM2X, DIM2X, 1, 0, 0, 0,
                                                /*actm*/ 0, /*storem*/ 0 | (0 << 4) | (1 << 8), /*apadm*/ 0);
  // attention with fused GroupNorm + skip/bgate epilogue (writes PRE directly)
  k_attn_mfma<<<dim3(32, 16), 256, 0, stream>>>(QH, KH, VT, CSb, MDb, ITb,
                                                QKb, BG, gnw, gnb, skip, PRE);
  k_mgemm<0, 2, 0><<<dim3(8, 32), 256, 0, stream>>>(PRE, DIM2X, finT, finb, out, x, DIMX, DIM2X, 0, 0, 0);
}

// Round 12
// 442.640 us; speedup vs baseline: 1.4751x; 1.0051x over previous
//
#include <hip/hip_runtime.h>
#include <hip/hip_bf16.h>
#include <cmath>

typedef __hip_bfloat16 bf16;
typedef __attribute__((ext_vector_type(8))) short short8;   // 8 bf16 (4 VGPRs)
typedef __attribute__((ext_vector_type(4))) float f32x4;

#define SEQ   2048
#define DIMX  512
#define DIM2X 1024
#define NHEADS 8
#define HDIM  128
#define EPSF  1e-5f
#define PADROWS 2051   // 3 zero rows + 2048 per batch

__device__ __forceinline__ float b2f(bf16 v) { return __bfloat162float(v); }
__device__ __forceinline__ bf16 f2b(float f) { return __float2bfloat16(f); }
__device__ __forceinline__ unsigned short f2bu(float f) { bf16 t = __float2bfloat16(f); return *(unsigned short*)&t; }

// async global->LDS, 16B per lane. LDS dest must be linear in lane order (wave base + lane*16).
__device__ __forceinline__ void gl16(const bf16* g, bf16* l) {
  __builtin_amdgcn_global_load_lds((const __attribute__((address_space(1))) void*)g,
                                   (__attribute__((address_space(3))) void*)l, 16, 0, 0);
}

// ---------------- LayerNorm: one wave per row of 512 (fp32 in, bf16 out) ----------------
__global__ void __launch_bounds__(256) k_layernorm(const float* __restrict__ x,
                                                   const float* __restrict__ w,
                                                   const float* __restrict__ b,
                                                   bf16* __restrict__ out) {
  int row  = blockIdx.x * 4 + (threadIdx.x >> 6);
  int lane = threadIdx.x & 63;
  const float* xr = x + (size_t)row * DIMX;
  float v[8]; float s = 0.f, sq = 0.f;
#pragma unroll
  for (int i = 0; i < 8; i++) {
    float f = xr[lane + i * 64];
    v[i] = f; s += f; sq += f * f;
  }
#pragma unroll
  for (int off = 32; off; off >>= 1) { s += __shfl_xor(s, off); sq += __shfl_xor(sq, off); }
  float mu  = s * (1.f / DIMX);
  float var = sq * (1.f / DIMX) - mu * mu;
  float rs  = rsqrtf(var + EPSF);
  bf16* o = out + (size_t)row * DIMX;
#pragma unroll
  for (int i = 0; i < 8; i++) {
    int c = lane + i * 64;
    o[c] = f2b((v[i] - mu) * rs * w[c] + b[c]);
  }
}

// ---------------- fused weight cast+transpose: dst = sel-th of {W0,W1,W2} ----------------
__global__ void __launch_bounds__(256) k_castT3(const float* __restrict__ W0,
                                                const float* __restrict__ W1,
                                                const float* __restrict__ W2,
                                                bf16* __restrict__ WT,
                                                int K, int N, int innerZ, int gW, int gT) {
  __shared__ float t[32][33];
  const int z = blockIdx.z;
  const int sel = z / innerZ, zz = z % innerZ;
  const float* W = (sel == 0 ? W0 : sel == 1 ? W1 : W2) + (size_t)zz * gW;
  bf16* T = WT + (size_t)(sel * innerZ + zz) * gT;
  const int k0 = blockIdx.y * 32, n0 = blockIdx.x * 32;
  const int r = threadIdx.x >> 5, c = threadIdx.x & 31;
#pragma unroll
  for (int i = 0; i < 4; i++)
    t[r + i * 8][c] = W[(size_t)(k0 + r + i * 8) * N + n0 + c];
  __syncthreads();
#pragma unroll
  for (int i = 0; i < 4; i++)
    T[(size_t)(n0 + r + i * 8) * K + k0 + c] = f2b(t[c][r + i * 8]);
}

// ---------------- conv weight reshape (coalesced): thread = one (o,i) ----------------
// reads float4 cw[o][i][0..3] (16B contiguous), writes 4 coalesced bf16 streams
// wc[o*4096 + kk*1024 + i]. Was: stride-16B gather (4x read amplification).
__global__ void __launch_bounds__(256) k_convwT(const float* __restrict__ cw, bf16* __restrict__ wc) {
  int idx = blockIdx.x * 256 + threadIdx.x;     // (o,i)
  int o = idx >> 10, i = idx & 1023;
  float4 v = *(const float4*)(cw + (size_t)idx * 4);
  size_t base = (size_t)o * 4096 + i;
  wc[base]        = f2b(v.x);
  wc[base + 1024] = f2b(v.y);
  wc[base + 2048] = f2b(v.z);
  wc[base + 3072] = f2b(v.w);
}

// ---------------- zero the 3 pad rows before each batch of padded A ----------------
__global__ void __launch_bounds__(256) k_zeropad(bf16* __restrict__ p) {
  int idx = blockIdx.x * 256 + threadIdx.x;     // 6144 total
  int b = idx / 3072, off = idx % 3072;
  p[(size_t)b * PADROWS * DIM2X + off] = f2b(0.f);
}

// ---------------- GEMM body: 128x64 block, 4 waves, BK=64, 3-buffer counted pipeline ----------------
// Per step: stage 24KB (6 gl16/thread), 16 MFMA/wave (2 k-chunks of 32). Order per step:
// wait vmcnt(6) [stage(s) landed] -> barrier -> issue stage(s+2) [write-after-barrier: all
// waves done reading buf (s+2)%3=(s-1)%3] -> compute. Counted window holds ONLY staging loads.
// LDS chunk^(row&7) XOR on both sides (src pre-swizzle + read XOR): 2 lanes/bank = free.
__device__ __forceinline__ void mgemm_body(const bf16* A, int lda, const bf16* WT,
                                           const float* bias, void* Cv, const float* xres,
                                           int ldc, int K, int ACT, int STORE, int APAD,
                                           size_t coff, int bm, int bn) {
  __shared__ __align__(16) bf16 smA[3][128 * 64];
  __shared__ __align__(16) bf16 smB[3][64 * 64];
  const int tid  = threadIdx.x;
  const int lane = tid & 63;
  const int w = tid >> 6, wy = w >> 1, wx = w & 1;
  const int col = lane & 15, quad = lane >> 4;

  // staging: thread t covers A chunks t,t+256,t+512,t+768 ([128][64] linear) and
  // B chunks t,t+256 ([64][64] linear). chunk=(row*8+c8i); source col pre-swizzled.
  const int r8 = tid >> 3, c8i = tid & 7;
  const int swz = (c8i ^ (r8 & 7)) * 8;       // (r8+p*32)&7 == r8&7
  const bf16* gA[4];
#pragma unroll
  for (int p = 0; p < 4; p++) {
    int ra = bm + r8 + p * 32;
    if (APAD) ra += (ra >> 11) * 3 + 3;
    gA[p] = A + (size_t)ra * lda + swz;
  }
  const bf16* gB[2];
#pragma unroll
  for (int p = 0; p < 2; p++)
    gB[p] = WT + (size_t)(bn + r8 + p * 32) * K + swz;

  f32x4 acc[4][2];
#pragma unroll
  for (int a = 0; a < 4; a++)
#pragma unroll
    for (int b = 0; b < 2; b++) acc[a][b] = (f32x4){0.f, 0.f, 0.f, 0.f};

  const int nsteps = K >> 6;                  // all K here are multiples of 64, nsteps >= 4

#define GSTAGE(buf, k0s)                                                       \
  do {                                                                         \
    bf16* dA = &smA[buf][tid * 8];                                             \
    gl16(gA[0] + (k0s), dA);                                                   \
    gl16(gA[1] + (k0s), dA + 2048);                                            \
    gl16(gA[2] + (k0s), dA + 4096);                                            \
    gl16(gA[3] + (k0s), dA + 6144);                                            \
    bf16* dB = &smB[buf][tid * 8];                                             \
    gl16(gB[0] + (k0s), dB);                                                   \
    gl16(gB[1] + (k0s), dB + 2048);                                            \
  } while (0)

  GSTAGE(0, 0);
  GSTAGE(1, 64);
  int buf = 0;
  for (int s = 0; s < nsteps; ++s) {
    if (s + 1 < nsteps) asm volatile("s_waitcnt vmcnt(6)" ::: "memory");
    else                asm volatile("s_waitcnt vmcnt(0)" ::: "memory");
    __builtin_amdgcn_s_barrier();
    if (s + 2 < nsteps) {
      int nb = buf + 2; if (nb >= 3) nb -= 3;
      GSTAGE(nb, (s + 2) * 64);
    }
    asm volatile("" ::: "memory");
    const bf16* bA = smA[buf];
    const bf16* bB = smB[buf];
#pragma unroll
    for (int kc = 0; kc < 2; kc++) {
      short8 af[4], bfr[2];
#pragma unroll
      for (int mt = 0; mt < 4; mt++) {
        const int row = wy * 64 + mt * 16 + col;
        af[mt] = *(const short8*)&bA[row * 64 + (((kc * 4 + quad) ^ (row & 7)) << 3)];
      }
#pragma unroll
      for (int nt = 0; nt < 2; nt++) {
        const int row = wx * 32 + nt * 16 + col;
        bfr[nt] = *(const short8*)&bB[row * 64 + (((kc * 4 + quad) ^ (row & 7)) << 3)];
      }
#pragma unroll
      for (int mt = 0; mt < 4; mt++)
#pragma unroll
        for (int nt = 0; nt < 2; nt++)
          acc[mt][nt] = __builtin_amdgcn_mfma_f32_16x16x32_bf16(af[mt], bfr[nt], acc[mt][nt], 0, 0, 0);
    }
    if (++buf >= 3) buf = 0;
  }
#undef GSTAGE

#pragma unroll
  for (int mt = 0; mt < 4; mt++) {
#pragma unroll
    for (int nt = 0; nt < 2; nt++) {
      const int n = bn + wx * 32 + nt * 16 + col;
      const int mrow0 = bm + wy * 64 + mt * 16 + quad * 4;
      float bs = bias ? bias[n] : 0.f;
      if (STORE == 1) {
        bf16* C = (bf16*)Cv + coff;
        ushort4 pk;
        pk.x = f2bu(acc[mt][nt][0] + bs); pk.y = f2bu(acc[mt][nt][1] + bs);
        pk.z = f2bu(acc[mt][nt][2] + bs); pk.w = f2bu(acc[mt][nt][3] + bs);
        *(ushort4*)(C + (size_t)n * 4096 + mrow0) = pk;
      } else if (STORE == 2) {
        float* O = (float*)Cv + coff;
#pragma unroll
        for (int r = 0; r < 4; r++) {
          size_t gi = (size_t)(mrow0 + r) * ldc + n;
          O[gi] = acc[mt][nt][r] + bs + xres[gi];
        }
      } else if (STORE == 3) {
        bf16* C = (bf16*)Cv;
        const int pr = (mrow0 >> 11) * 3 + 3;   // all 4 rows in same batch (128-blocks)
#pragma unroll
        for (int r = 0; r < 4; r++)
          C[(size_t)(mrow0 + pr + r) * ldc + n] = f2b(acc[mt][nt][r] + bs);
      } else {
        bf16* C = (bf16*)Cv + coff;
#pragma unroll
        for (int r = 0; r < 4; r++) {
          float v = acc[mt][nt][r] + bs;
          if (ACT == 1) v = v / (1.f + expf(-v));  // silu
          C[(size_t)(mrow0 + r) * ldc + n] = f2b(v);
        }
      }
    }
  }
}

// T1 bijective XCD swizzle (m204 form, r=0 case; requires nwg % 8 == 0 — true for all
// launches below). Blocks round-robining to one XCD get CONSECUTIVE work ids ->
// blocks sharing an A/B panel chunk co-locate on one XCD's L2. (round 9: fleet ~ -23us)
__device__ __forceinline__ int xcd_work_id() {
  const int nx = gridDim.x, ny = gridDim.y;
  const int d = blockIdx.x + nx * (blockIdx.y + ny * blockIdx.z);
  const int q = (nx * ny * (int)gridDim.z) >> 3;
  return (d & 7) * q + (d >> 3);
}

// template variant (conv, fin)
template <int ACT, int STORE, int APAD>
__global__ void __launch_bounds__(256) k_mgemm(const bf16* __restrict__ A, int lda,
                                               const bf16* __restrict__ WT,
                                               const float* __restrict__ bias,
                                               void* __restrict__ Cv,
                                               const float* __restrict__ xres,
                                               int ldc, int K,
                                               int gA, int gW, int gC) {
  const int wk = xcd_work_id();
  const int nx = gridDim.x, ny = gridDim.y;
  const int wx = wk % nx, rest = wk / nx;
  const int wy = rest % ny, g = rest / ny;
  mgemm_body(A + (size_t)g * gA, lda, WT + (size_t)g * gW, bias, Cv, xres,
             ldc, K, ACT, STORE, APAD, (size_t)g * gC, wy * 128, wx * 64);
}

// batched variant: z-slice selects one of 3 jobs (uniform scalar branches)
__global__ void __launch_bounds__(256) k_mgemmB(const bf16* A0, const bf16* A1, const bf16* A2,
                                                const bf16* W0, const bf16* W1, const bf16* W2,
                                                const float* b0, const float* b1, const float* b2,
                                                void* C0, void* C1, void* C2,
                                                int lda, int ldc, int K, int zPer,
                                                int gA, int gW, int gC,
                                                int actm, int storem, int apadm) {
  const int wk = xcd_work_id();
  const int nx = gridDim.x, ny = gridDim.y;
  const int wx = wk % nx, rest = wk / nx;
  const int wy = rest % ny, z = rest / ny;
  const int sel = z / zPer, zz = z % zPer;
  const bf16* A = (sel == 0 ? A0 : sel == 1 ? A1 : A2) + (size_t)zz * gA;
  const bf16* W = (sel == 0 ? W0 : sel == 1 ? W1 : W2) + (size_t)zz * gW;
  const float* bias = sel == 0 ? b0 : sel == 1 ? b1 : b2;
  void* Cv = sel == 0 ? C0 : sel == 1 ? C1 : C2;
  mgemm_body(A, lda, W, bias, Cv, nullptr, ldc, K,
             (actm >> sel) & 1, (storem >> (4 * sel)) & 15, (apadm >> sel) & 1,
             (size_t)zz * gC, wy * 128, wx * 64);
}

// ---------------- gate GEMV ----------------
__global__ void __launch_bounds__(256) k_gates(const bf16* __restrict__ q, const bf16* __restrict__ kk,
                                               const float* __restrict__ wi, const float* __restrict__ wib,
                                               const float* __restrict__ wf, const float* __restrict__ wfb,
                                               float* __restrict__ it, float* __restrict__ ft) {
  int gid  = blockIdx.x * 4 + (threadIdx.x >> 6);
  int lane = threadIdx.x & 63;
  int which = gid >> 12;
  int m = gid & 4095;
  const bf16* row = (which ? kk : q) + (size_t)m * DIM2X;
  const float* w = which ? wf : wi;
  float s[8] = {0, 0, 0, 0, 0, 0, 0, 0};
  for (int d = lane; d < DIM2X; d += 64) {
    float xv = b2f(row[d]);
    const float4* wp = (const float4*)(w + d * 8);
    float4 w0 = wp[0], w1 = wp[1];
    s[0] += xv * w0.x; s[1] += xv * w0.y; s[2] += xv * w0.z; s[3] += xv * w0.w;
    s[4] += xv * w1.x; s[5] += xv * w1.y; s[6] += xv * w1.z; s[7] += xv * w1.w;
  }
#pragma unroll
  for (int off = 32; off; off >>= 1) {
#pragma unroll
    for (int h = 0; h < 8; h++) s[h] += __shfl_xor(s[h], off);
  }
  if (lane == 0) {
    int b_ = m >> 11, tt = m & 2047;
    const float* wb = which ? wfb : wib;
    float* dst = which ? ft : it;
#pragma unroll
    for (int h = 0; h < 8; h++)
      dst[((size_t)(b_ * NHEADS + h)) * SEQ + tt] = s[h] + wb[h];
  }
}

// ---------------- per-(b,h) scan ----------------
__global__ void __launch_bounds__(256) k_scan(const float* __restrict__ it, const float* __restrict__ ft,
                                              float* __restrict__ cs, float* __restrict__ md) {
  const int bh = blockIdx.x;
  const int t  = threadIdx.x;
  const float* fr = ft + (size_t)bh * SEQ;
  const float* ir = it + (size_t)bh * SEQ;
  float* csr = cs + (size_t)bh * SEQ;
  float* mdr = md + (size_t)bh * SEQ;
  __shared__ float tmp[256];
  float loc[8]; float run = 0.f;
#pragma unroll
  for (int j = 0; j < 8; j++) {
    float xv = fr[t * 8 + j];
    float ls = fminf(xv, 0.f) - log1pf(expf(-fabsf(xv)));
    run += ls; loc[j] = run;
  }
  tmp[t] = run;
  __syncthreads();
  for (int off = 1; off < 256; off <<= 1) {
    float add = (t >= off) ? tmp[t - off] : 0.f;
    __syncthreads();
    tmp[t] += add;
    __syncthreads();
  }
  float exc = (t == 0) ? 0.f : tmp[t - 1];
  float csv[8];
#pragma unroll
  for (int j = 0; j < 8; j++) { csv[j] = loc[j] + exc; csr[t * 8 + j] = csv[j]; }
  __syncthreads();
  float rmax = -INFINITY; float gm[8];
#pragma unroll
  for (int j = 0; j < 8; j++) {
    float gv = ir[t * 8 + j] - csv[j];
    rmax = fmaxf(rmax, gv); gm[j] = rmax;
  }
  tmp[t] = rmax;
  __syncthreads();
  for (int off = 1; off < 256; off <<= 1) {
    float other = (t >= off) ? tmp[t - off] : -INFINITY;
    __syncthreads();
    tmp[t] = fmaxf(tmp[t], other);
    __syncthreads();
  }
  float emax = (t == 0) ? -INFINITY : tmp[t - 1];
#pragma unroll
  for (int j = 0; j < 8; j++) mdr[t * 8 + j] = csv[j] + fmaxf(gm[j], emax);
}

// ---------------- MFMA causal attention (round-8 structure) + FUSED GroupNorm epilogue ----------------
// Single tile per block, grid (32,16). 4 LDS buffers, prefetch depth 2, one raw s_barrier
// per trip, counted vmcnt(8/4/0) — window holds ONLY staging loads.
// Epilogue: GroupNorm via shfl_xor within the 16-lane quad group; writes PRE directly.
__global__ void __launch_bounds__(256) k_attn_mfma(const bf16* __restrict__ qh,
                                                   const bf16* __restrict__ kh,
                                                   const bf16* __restrict__ vt,
                                                   const float* __restrict__ cs,
                                                   const float* __restrict__ md,
                                                   const float* __restrict__ itl,
                                                   const bf16* __restrict__ qk,
                                                   const bf16* __restrict__ bg,
                                                   const float* __restrict__ gw,
                                                   const float* __restrict__ gb,
                                                   const float* __restrict__ skip,
                                                   bf16* __restrict__ pre) {
  const int bh = blockIdx.y, b_ = bh >> 3, h = bh & 7;
  const int bx = blockIdx.x;
  const int tile = ((blockIdx.y >> 3) & 1) ? bx : 31 - bx;   // balanced pairing heuristic
  const int i0 = tile * 64;
  const int tid = threadIdx.x;
  const int w = tid >> 6;                     // wave 0..3 -> i-rows i0+16w..
  const int lane = tid & 63;
  const int col = lane & 15, quad = lane >> 4;
  const int i0w = i0 + w * 16;
  const int iwmax = i0w + 15;
  const float L2E = 1.44269504f;

  __shared__ __align__(16) bf16 smK[4 * 4096]; // [buf][j 32][d 128], chunk^(j&7) swizzle
  __shared__ __align__(16) bf16 smV[4 * 4096]; // [buf][n 128][j 32], chunk^((n>>1)&3) swizzle
  __shared__ __align__(16) bf16 Sc[4][16][40];

  const size_t baseQK = ((size_t)b_ * SEQ) * DIM2X + (size_t)h * HDIM;
  const size_t vtb = (size_t)(h * HDIM) * 4096 + (size_t)b_ * SEQ;
  const float* csp = cs + (size_t)bh * SEQ;
  const float* mdp = md + (size_t)bh * SEQ;
  const float* itp = itl + (size_t)bh * SEQ;

  short8 qf[4];
#pragma unroll
  for (int kc = 0; kc < 4; kc++)
    qf[kc] = *(const short8*)(qh + baseQK + (size_t)(i0w + col) * DIM2X + kc * 32 + quad * 8);

  float cs_i[4], md_i[4];                     // log2 domain
#pragma unroll
  for (int r = 0; r < 4; r++) {
    int i = i0w + quad * 4 + r;
    cs_i[r] = csp[i] * L2E; md_i[r] = mdp[i] * L2E;
  }

  f32x4 accpv[8];
#pragma unroll
  for (int nb = 0; nb < 8; nb++) accpv[nb] = (f32x4){0.f, 0.f, 0.f, 0.f};
  float rs[4] = {0.f, 0.f, 0.f, 0.f};

  // staging sources (thread t covers LDS chunk t of each 8KB buffer; source pre-swizzled)
  const int kj = tid >> 4, kq = tid & 15;     // K: row kj (+16), chunk kq
  const bf16* gKs = kh + baseQK + (size_t)kj * DIM2X + ((kq ^ (kj & 7)) * 8);
  const int vn = tid >> 2, vq = tid & 3;      // V: row vn (+64), chunk vq
  const bf16* gVs = vt + vtb + (size_t)vn * 4096 + ((vq ^ ((vn >> 1) & 3)) * 8);

  const int trips = 2 * tile + 2;

#define STAGE(buf, j0s)                                                        \
  do {                                                                         \
    bf16* dK = &smK[(buf) * 4096 + tid * 8];                                   \
    gl16(gKs + (size_t)(j0s) * DIM2X, dK);                                     \
    gl16(gKs + (size_t)((j0s) + 16) * DIM2X, dK + 2048);                       \
    bf16* dV = &smV[(buf) * 4096 + tid * 8];                                   \
    gl16(gVs + (j0s), dV);                                                     \
    gl16(gVs + (j0s) + (size_t)64 * 4096, dV + 2048);                          \
  } while (0)

  STAGE(0, 0);
  STAGE(1, 32);                               // trips >= 2 always
  for (int t = 0; t < trips; ++t) {
    const int cur = t & 3;
    const int j0p = t * 32;
    if (t + 2 < trips) STAGE((t + 2) & 3, j0p + 64);
    if (t + 2 < trips)      asm volatile("s_waitcnt vmcnt(8)" ::: "memory");
    else if (t + 1 < trips) asm volatile("s_waitcnt vmcnt(4)" ::: "memory");
    else                    asm volatile("s_waitcnt vmcnt(0)" ::: "memory");
    __builtin_amdgcn_s_barrier();
    asm volatile("" ::: "memory");
    if (j0p <= iwmax) {
      // hoisted gate loads, log2 domain
      float g0 = (itp[j0p + col] - csp[j0p + col]) * L2E;
      float g1 = (itp[j0p + 16 + col] - csp[j0p + 16 + col]) * L2E;
      const bool jt1 = (j0p + 16 <= iwmax);
#pragma unroll
      for (int jt = 0; jt < 2; jt++) {
        const int j0 = j0p + jt * 16;
        float sv[4] = {0.f, 0.f, 0.f, 0.f};
        if (jt == 0 || jt1) {
          const int jj = jt * 16 + col;
          f32x4 aq = (f32x4){0.f, 0.f, 0.f, 0.f};
#pragma unroll
          for (int kc = 0; kc < 4; kc++) {
            short8 bk = *(const short8*)&smK[cur * 4096 + jj * 128 + ((((kc << 2) | quad) ^ (jj & 7)) << 3)];
            aq = __builtin_amdgcn_mfma_f32_16x16x32_bf16(qf[kc], bk, aq, 0, 0, 0);
          }
          const int j = j0 + col;
          const float gj = jt ? g1 : g0;
#pragma unroll
          for (int r = 0; r < 4; r++) {
            const int i = i0w + quad * 4 + r;
            // arg <= -5 by construction (md = exact row max); 2^-5 = 1/tau
            float s = (j <= i) ? exp2f(cs_i[r] + gj - md_i[r] - 5.f) * aq[r] : 0.f;
            sv[r] = s; rs[r] += s;
          }
        }
#pragma unroll
        for (int r = 0; r < 4; r++) Sc[w][quad * 4 + r][jt * 16 + col] = f2b(sv[r]);
      }
      // own-wave cross-lane LDS round-trip: force write completion before read (rule #18)
      asm volatile("s_waitcnt lgkmcnt(0)" ::: "memory");
      __builtin_amdgcn_sched_barrier(0);
      short8 af = *(const short8*)(&Sc[w][col][quad * 8]);
#pragma unroll
      for (int nb = 0; nb < 8; nb++) {
        const int rn = nb * 16 + col;
        short8 bv = *(const short8*)&smV[cur * 4096 + rn * 32 + ((quad ^ ((rn >> 1) & 3)) << 3)];
        accpv[nb] = __builtin_amdgcn_mfma_f32_16x16x32_bf16(af, bv, accpv[nb], 0, 0, 0);
      }
    }
    // no trailing barrier: 4 buffers tolerate the 1-trip skew
  }
#undef STAGE

  // ---- fused epilogue: H normalize + GroupNorm + skip/bgate, write PRE ----
#pragma unroll
  for (int r = 0; r < 4; r++) {
    float v = rs[r];
    v += __shfl_xor(v, 1); v += __shfl_xor(v, 2);
    v += __shfl_xor(v, 4); v += __shfl_xor(v, 8);
    rs[r] = v;
  }
  float inv[4];
#pragma unroll
  for (int r = 0; r < 4; r++) {
    float maxit = fmaxf(fabsf(rs[r]), exp2f(fminf(-md_i[r], 43.f)));
    inv[r] = 1.f / (maxit + 1e-8f);
  }
  // per-col params (col = h*128 + nb*16 + colIdx; independent of r)
  float gwv[8], gbv[8], skv[8];
#pragma unroll
  for (int nb = 0; nb < 8; nb++) {
    int c = h * HDIM + nb * 16 + col;
    gwv[nb] = gw[c]; gbv[nb] = gb[c]; skv[nb] = skip[c];
  }
#pragma unroll
  for (int r = 0; r < 4; r++) {
    const int row = i0w + quad * 4 + r;       // row within batch
    float s1 = 0.f, s2 = 0.f;
#pragma unroll
    for (int nb = 0; nb < 8; nb++) {
      float v = accpv[nb][r] * inv[r];
      s1 += v; s2 += v * v;
    }
    // reduce over the 16 lanes of this quad-group (all 128 head-dims of this row)
    s1 += __shfl_xor(s1, 1); s2 += __shfl_xor(s2, 1);
    s1 += __shfl_xor(s1, 2); s2 += __shfl_xor(s2, 2);
    s1 += __shfl_xor(s1, 4); s2 += __shfl_xor(s2, 4);
    s1 += __shfl_xor(s1, 8); s2 += __shfl_xor(s2, 8);
    float mu  = s1 * (1.f / 128.f);
    float var = s2 * (1.f / 128.f) - mu * mu;
    float rsg = rsqrtf(var + EPSF);
    const size_t rbase = baseQK + (size_t)row * DIM2X;   // includes batch+head offset
#pragma unroll
    for (int nb = 0; nb < 8; nb++) {
      float hv = accpv[nb][r] * inv[r];
      float hn = (hv - mu) * rsg * gwv[nb] + gbv[nb];
      size_t gi = rbase + nb * 16 + col;
      pre[gi] = f2b((hn + skv[nb] * b2f(qk[gi])) * b2f(bg[gi]));
    }
  }
}

extern "C" void kernel_launch(void* const* d_in, const int* in_sizes, int n_in,
                              void* d_out, int out_size, void* d_ws, size_t ws_size,
                              hipStream_t stream) {
  const float* x     = (const float*)d_in[0];
  const float* ln_w  = (const float*)d_in[1];
  const float* ln_b  = (const float*)d_in[2];
  const float* mlp1w = (const float*)d_in[3];
  const float* mlp1b = (const float*)d_in[4];
  const float* mlp2w = (const float*)d_in[5];
  const float* mlp2b = (const float*)d_in[6];
  const float* convw = (const float*)d_in[7];
  const float* convb = (const float*)d_in[8];
  const float* bqw   = (const float*)d_in[9];
  const float* bkw   = (const float*)d_in[10];
  const float* bvw   = (const float*)d_in[11];
  const float* wqw   = (const float*)d_in[12];
  const float* wqb   = (const float*)d_in[13];
  const float* wkw   = (const float*)d_in[14];
  const float* wkb   = (const float*)d_in[15];
  const float* wvw   = (const float*)d_in[16];
  const float* wvb   = (const float*)d_in[17];
  const float* wiw   = (const float*)d_in[18];
  const float* wib   = (const float*)d_in[19];
  const float* wfw   = (const float*)d_in[20];
  const float* wfb   = (const float*)d_in[21];
  const float* gnw   = (const float*)d_in[22];
  const float* gnb   = (const float*)d_in[23];
  const float* skip  = (const float*)d_in[24];
  const float* finw  = (const float*)d_in[25];
  const float* finb  = (const float*)d_in[26];
  float* out = (float*)d_out;

  float* GA  = (float*)d_ws;
  float* ITb = GA;
  float* FTb = GA + 32768;
  float* CSb = GA + 65536;
  float* MDb = GA + 98304;
  const size_t SLOT = 4u * 1024u * 1024u;
  bf16* S0 = (bf16*)((char*)d_ws + (1 << 20));
  bf16* S1 = S0 + SLOT;
  bf16* S2 = S1 + SLOT;
  bf16* S3 = S2 + SLOT;
  bf16* S4 = S3 + SLOT;
  bf16* S5 = S4 + SLOT;
  bf16* S6 = S5 + SLOT;
  bf16 *LN = S0, *BG = S2, *QKb = S3, *Qb = S4, *Kb = S5, *Vb = S6;
  bf16 *QH = S0, *KH = S1, *VT = S4, *PRE = S6;
  bf16* WTb   = S6 + SLOT;
  bf16* mlp1T = WTb;
  bf16* mlp2T = WTb + 524288;
  bf16* convT = WTb + 1048576;                 // [1024][4096] flat-K layout
  bf16* bqT   = WTb + 5242880;
  bf16* bkT   = bqT + 262144;
  bf16* bvT   = bkT + 262144;
  bf16* wqT   = bvT + 262144;
  bf16* wkT   = wqT + 1048576;
  bf16* wvT   = wkT + 1048576;
  bf16* finT  = wvT + 1048576;
  bf16* APD   = finT + 524288;                 // padded A: [2][2051][1024]

  // fused weight prep
  k_castT3<<<dim3(32, 16, 2), 256, 0, stream>>>(mlp1w, mlp2w, mlp2w, mlp1T, DIMX, DIM2X, 1, 0, 524288);
  k_castT3<<<dim3(32, 32, 3), 256, 0, stream>>>(wqw, wkw, wvw, wqT, DIM2X, DIM2X, 1, 0, 1048576);
  k_castT3<<<dim3(8, 8, 12), 256, 0, stream>>>(bqw, bkw, bvw, bqT, 256, 256, 4, 65536, 65536);
  k_castT3<<<dim3(16, 32, 1), 256, 0, stream>>>(finw, finw, finw, finT, DIM2X, DIMX, 1, 0, 524288);
  k_convwT<<<4096, 256, 0, stream>>>(convw, convT);
  k_zeropad<<<24, 256, 0, stream>>>(APD);

  k_layernorm<<<1024, 256, 0, stream>>>(x, ln_w, ln_b, LN);
  // batched mlp: sel0 = mlp1 -> APD (store3), sel1 = mlp2 -> BG (store0, silu)
  k_mgemmB<<<dim3(16, 32, 2), 256, 0, stream>>>(LN, LN, LN, mlp1T, mlp2T, mlp2T,
                                                mlp1b, mlp2b, mlp2b, APD, BG, BG,
                                                DIMX, DIM2X, DIMX, 1, 0, 0, 0,
                                                /*actm*/ 0b10, /*storem*/ 3 | (0 << 4), /*apadm*/ 0);
  // causal conv1d == single GEMM: K=4096 contiguous window over padded rows t..t+3
  k_mgemm<1, 0, 0><<<dim3(16, 16, 2), 256, 0, stream>>>(APD, DIM2X, convT, convb, QKb, nullptr,
                                                        DIM2X, 4096, PADROWS * DIM2X, 0, SEQ * DIM2X);
  // batched block-diag q/k/v: 12 z-slices (3 weights x 4 groups)
  k_mgemmB<<<dim3(4, 32, 12), 256, 0, stream>>>(QKb, QKb, APD, bqT, bkT, bvT,
                                                nullptr, nullptr, nullptr, Qb, Kb, Vb,
                                                DIM2X, DIM2X, 256, 4, 256, 65536, 256,
                                                /*actm*/ 0, /*storem*/ 0, /*apadm*/ 0b100);
  k_gates<<<2048, 256, 0, stream>>>(Qb, Kb, wiw, wib, wfw, wfb, ITb, FTb);
  k_scan<<<16, 256, 0, stream>>>(ITb, FTb, CSb, MDb);
  // batched wq/wk/wv: sel2 writes V^T (store1)
  k_mgemmB<<<dim3(16, 32, 3), 256, 0, stream>>>(Qb, Kb, Vb, wqT, wkT, wvT,
                                                wqb, wkb, wvb, QH, KH, VT,
                                                DIM2X, DIM2X, DIM2X, 1, 0, 0, 0,
                                                /*actm*/ 0, /*storem*/ 0 | (0 << 4) | (1 << 8), /*apadm*/ 0);
  // attention with fused GroupNorm + skip/bgate epilogue (writes PRE directly)
  k_attn_mfma<<<dim3(32, 16), 256, 0, stream>>>(QH, KH, VT, CSb, MDb, ITb,
                                                QKb, BG, gnw, gnb, skip, PRE);
  k_mgemm<0, 2, 0><<<dim3(8, 32), 256, 0, stream>>>(PRE, DIM2X, finT, finb, out, x, DIMX, DIM2X, 0, 0, 0);
}

// Round 13
// 442.328 us; speedup vs baseline: 1.4761x; 1.0007x over previous
//
#include <hip/hip_runtime.h>
#include <hip/hip_bf16.h>
#include <cmath>

typedef __hip_bfloat16 bf16;
typedef __attribute__((ext_vector_type(8))) short short8;   // 8 bf16 (4 VGPRs)
typedef __attribute__((ext_vector_type(4))) float f32x4;

#define SEQ   2048
#define DIMX  512
#define DIM2X 1024
#define NHEADS 8
#define HDIM  128
#define EPSF  1e-5f
#define PADROWS 2051   // 3 zero rows + 2048 per batch

__device__ __forceinline__ float b2f(bf16 v) { return __bfloat162float(v); }
__device__ __forceinline__ bf16 f2b(float f) { return __float2bfloat16(f); }
__device__ __forceinline__ unsigned short f2bu(float f) { bf16 t = __float2bfloat16(f); return *(unsigned short*)&t; }

// async global->LDS, 16B per lane. LDS dest must be linear in lane order (wave base + lane*16).
__device__ __forceinline__ void gl16(const bf16* g, bf16* l) {
  __builtin_amdgcn_global_load_lds((const __attribute__((address_space(1))) void*)g,
                                   (__attribute__((address_space(3))) void*)l, 16, 0, 0);
}

// ---------------- LayerNorm: one wave per row of 512 (fp32 in, bf16 out) ----------------
__global__ void __launch_bounds__(256) k_layernorm(const float* __restrict__ x,
                                                   const float* __restrict__ w,
                                                   const float* __restrict__ b,
                                                   bf16* __restrict__ out) {
  int row  = blockIdx.x * 4 + (threadIdx.x >> 6);
  int lane = threadIdx.x & 63;
  const float* xr = x + (size_t)row * DIMX;
  float v[8]; float s = 0.f, sq = 0.f;
#pragma unroll
  for (int i = 0; i < 8; i++) {
    float f = xr[lane + i * 64];
    v[i] = f; s += f; sq += f * f;
  }
#pragma unroll
  for (int off = 32; off; off >>= 1) { s += __shfl_xor(s, off); sq += __shfl_xor(sq, off); }
  float mu  = s * (1.f / DIMX);
  float var = sq * (1.f / DIMX) - mu * mu;
  float rs  = rsqrtf(var + EPSF);
  bf16* o = out + (size_t)row * DIMX;
#pragma unroll
  for (int i = 0; i < 8; i++) {
    int c = lane + i * 64;
    o[c] = f2b((v[i] - mu) * rs * w[c] + b[c]);
  }
}

// ---------------- fused weight cast+transpose: dst = sel-th of {W0,W1,W2} ----------------
__global__ void __launch_bounds__(256) k_castT3(const float* __restrict__ W0,
                                                const float* __restrict__ W1,
                                                const float* __restrict__ W2,
                                                bf16* __restrict__ WT,
                                                int K, int N, int innerZ, int gW, int gT) {
  __shared__ float t[32][33];
  const int z = blockIdx.z;
  const int sel = z / innerZ, zz = z % innerZ;
  const float* W = (sel == 0 ? W0 : sel == 1 ? W1 : W2) + (size_t)zz * gW;
  bf16* T = WT + (size_t)(sel * innerZ + zz) * gT;
  const int k0 = blockIdx.y * 32, n0 = blockIdx.x * 32;
  const int r = threadIdx.x >> 5, c = threadIdx.x & 31;
#pragma unroll
  for (int i = 0; i < 4; i++)
    t[r + i * 8][c] = W[(size_t)(k0 + r + i * 8) * N + n0 + c];
  __syncthreads();
#pragma unroll
  for (int i = 0; i < 4; i++)
    T[(size_t)(n0 + r + i * 8) * K + k0 + c] = f2b(t[c][r + i * 8]);
}

// ---------------- conv weight reshape (coalesced): thread = one (o,i) ----------------
__global__ void __launch_bounds__(256) k_convwT(const float* __restrict__ cw, bf16* __restrict__ wc) {
  int idx = blockIdx.x * 256 + threadIdx.x;     // (o,i)
  int o = idx >> 10, i = idx & 1023;
  float4 v = *(const float4*)(cw + (size_t)idx * 4);
  size_t base = (size_t)o * 4096 + i;
  wc[base]        = f2b(v.x);
  wc[base + 1024] = f2b(v.y);
  wc[base + 2048] = f2b(v.z);
  wc[base + 3072] = f2b(v.w);
}

// ---------------- zero the 3 pad rows before each batch of padded A ----------------
__global__ void __launch_bounds__(256) k_zeropad(bf16* __restrict__ p) {
  int idx = blockIdx.x * 256 + threadIdx.x;     // 6144 total
  int b = idx / 3072, off = idx % 3072;
  p[(size_t)b * PADROWS * DIM2X + off] = f2b(0.f);
}

// ---------------- GEMM body: 128x64 block, 4 waves, BK=64, 3-buffer counted pipeline ----------------
__device__ __forceinline__ void mgemm_body(const bf16* A, int lda, const bf16* WT,
                                           const float* bias, void* Cv, const float* xres,
                                           int ldc, int K, int ACT, int STORE, int APAD,
                                           size_t coff, int bm, int bn) {
  __shared__ __align__(16) bf16 smA[3][128 * 64];
  __shared__ __align__(16) bf16 smB[3][64 * 64];
  const int tid  = threadIdx.x;
  const int lane = tid & 63;
  const int w = tid >> 6, wy = w >> 1, wx = w & 1;
  const int col = lane & 15, quad = lane >> 4;

  const int r8 = tid >> 3, c8i = tid & 7;
  const int swz = (c8i ^ (r8 & 7)) * 8;       // (r8+p*32)&7 == r8&7
  const bf16* gA[4];
#pragma unroll
  for (int p = 0; p < 4; p++) {
    int ra = bm + r8 + p * 32;
    if (APAD) ra += (ra >> 11) * 3 + 3;
    gA[p] = A + (size_t)ra * lda + swz;
  }
  const bf16* gB[2];
#pragma unroll
  for (int p = 0; p < 2; p++)
    gB[p] = WT + (size_t)(bn + r8 + p * 32) * K + swz;

  f32x4 acc[4][2];
#pragma unroll
  for (int a = 0; a < 4; a++)
#pragma unroll
    for (int b = 0; b < 2; b++) acc[a][b] = (f32x4){0.f, 0.f, 0.f, 0.f};

  const int nsteps = K >> 6;                  // all K here are multiples of 64, nsteps >= 4

#define GSTAGE(buf, k0s)                                                       \
  do {                                                                         \
    bf16* dA = &smA[buf][tid * 8];                                             \
    gl16(gA[0] + (k0s), dA);                                                   \
    gl16(gA[1] + (k0s), dA + 2048);                                            \
    gl16(gA[2] + (k0s), dA + 4096);                                            \
    gl16(gA[3] + (k0s), dA + 6144);                                            \
    bf16* dB = &smB[buf][tid * 8];                                             \
    gl16(gB[0] + (k0s), dB);                                                   \
    gl16(gB[1] + (k0s), dB + 2048);                                            \
  } while (0)

  GSTAGE(0, 0);
  GSTAGE(1, 64);
  int buf = 0;
  for (int s = 0; s < nsteps; ++s) {
    if (s + 1 < nsteps) asm volatile("s_waitcnt vmcnt(6)" ::: "memory");
    else                asm volatile("s_waitcnt vmcnt(0)" ::: "memory");
    __builtin_amdgcn_s_barrier();
    if (s + 2 < nsteps) {
      int nb = buf + 2; if (nb >= 3) nb -= 3;
      GSTAGE(nb, (s + 2) * 64);
    }
    asm volatile("" ::: "memory");
    const bf16* bA = smA[buf];
    const bf16* bB = smB[buf];
#pragma unroll
    for (int kc = 0; kc < 2; kc++) {
      short8 af[4], bfr[2];
#pragma unroll
      for (int mt = 0; mt < 4; mt++) {
        const int row = wy * 64 + mt * 16 + col;
        af[mt] = *(const short8*)&bA[row * 64 + (((kc * 4 + quad) ^ (row & 7)) << 3)];
      }
#pragma unroll
      for (int nt = 0; nt < 2; nt++) {
        const int row = wx * 32 + nt * 16 + col;
        bfr[nt] = *(const short8*)&bB[row * 64 + (((kc * 4 + quad) ^ (row & 7)) << 3)];
      }
#pragma unroll
      for (int mt = 0; mt < 4; mt++)
#pragma unroll
        for (int nt = 0; nt < 2; nt++)
          acc[mt][nt] = __builtin_amdgcn_mfma_f32_16x16x32_bf16(af[mt], bfr[nt], acc[mt][nt], 0, 0, 0);
    }
    if (++buf >= 3) buf = 0;
  }
#undef GSTAGE

#pragma unroll
  for (int mt = 0; mt < 4; mt++) {
#pragma unroll
    for (int nt = 0; nt < 2; nt++) {
      const int n = bn + wx * 32 + nt * 16 + col;
      const int mrow0 = bm + wy * 64 + mt * 16 + quad * 4;
      float bs = bias ? bias[n] : 0.f;
      if (STORE == 1) {
        bf16* C = (bf16*)Cv + coff;
        ushort4 pk;
        pk.x = f2bu(acc[mt][nt][0] + bs); pk.y = f2bu(acc[mt][nt][1] + bs);
        pk.z = f2bu(acc[mt][nt][2] + bs); pk.w = f2bu(acc[mt][nt][3] + bs);
        *(ushort4*)(C + (size_t)n * 4096 + mrow0) = pk;
      } else if (STORE == 2) {
        float* O = (float*)Cv + coff;
#pragma unroll
        for (int r = 0; r < 4; r++) {
          size_t gi = (size_t)(mrow0 + r) * ldc + n;
          O[gi] = acc[mt][nt][r] + bs + xres[gi];
        }
      } else if (STORE == 3) {
        bf16* C = (bf16*)Cv;
        const int pr = (mrow0 >> 11) * 3 + 3;   // all 4 rows in same batch (128-blocks)
#pragma unroll
        for (int r = 0; r < 4; r++)
          C[(size_t)(mrow0 + pr + r) * ldc + n] = f2b(acc[mt][nt][r] + bs);
      } else {
        bf16* C = (bf16*)Cv + coff;
#pragma unroll
        for (int r = 0; r < 4; r++) {
          float v = acc[mt][nt][r] + bs;
          if (ACT == 1) v = v / (1.f + expf(-v));  // silu
          C[(size_t)(mrow0 + r) * ldc + n] = f2b(v);
        }
      }
    }
  }
}

// T1 bijective XCD swizzle (m204 form, r=0 case; requires nwg % 8 == 0).
__device__ __forceinline__ int xcd_work_id() {
  const int nx = gridDim.x, ny = gridDim.y;
  const int d = blockIdx.x + nx * (blockIdx.y + ny * blockIdx.z);
  const int q = (nx * ny * (int)gridDim.z) >> 3;
  return (d & 7) * q + (d >> 3);
}

// template variant (conv, fin)
template <int ACT, int STORE, int APAD>
__global__ void __launch_bounds__(256) k_mgemm(const bf16* __restrict__ A, int lda,
                                               const bf16* __restrict__ WT,
                                               const float* __restrict__ bias,
                                               void* __restrict__ Cv,
                                               const float* __restrict__ xres,
                                               int ldc, int K,
                                               int gA, int gW, int gC) {
  const int wk = xcd_work_id();
  const int nx = gridDim.x, ny = gridDim.y;
  const int wx = wk % nx, rest = wk / nx;
  const int wy = rest % ny, g = rest / ny;
  mgemm_body(A + (size_t)g * gA, lda, WT + (size_t)g * gW, bias, Cv, xres,
             ldc, K, ACT, STORE, APAD, (size_t)g * gC, wy * 128, wx * 64);
}

// batched variant: z-slice selects one of 3 jobs (uniform scalar branches)
__global__ void __launch_bounds__(256) k_mgemmB(const bf16* A0, const bf16* A1, const bf16* A2,
                                                const bf16* W0, const bf16* W1, const bf16* W2,
                                                const float* b0, const float* b1, const float* b2,
                                                void* C0, void* C1, void* C2,
                                                int lda, int ldc, int K, int zPer,
                                                int gA, int gW, int gC,
                                                int actm, int storem, int apadm) {
  const int wk = xcd_work_id();
  const int nx = gridDim.x, ny = gridDim.y;
  const int wx = wk % nx, rest = wk / nx;
  const int wy = rest % ny, z = rest / ny;
  const int sel = z / zPer, zz = z % zPer;
  const bf16* A = (sel == 0 ? A0 : sel == 1 ? A1 : A2) + (size_t)zz * gA;
  const bf16* W = (sel == 0 ? W0 : sel == 1 ? W1 : W2) + (size_t)zz * gW;
  const float* bias = sel == 0 ? b0 : sel == 1 ? b1 : b2;
  void* Cv = sel == 0 ? C0 : sel == 1 ? C1 : C2;
  mgemm_body(A, lda, W, bias, Cv, nullptr, ldc, K,
             (actm >> sel) & 1, (storem >> (4 * sel)) & 15, (apadm >> sel) & 1,
             (size_t)zz * gC, wy * 128, wx * 64);
}

// ---------------- gate GEMV ----------------
__global__ void __launch_bounds__(256) k_gates(const bf16* __restrict__ q, const bf16* __restrict__ kk,
                                               const float* __restrict__ wi, const float* __restrict__ wib,
                                               const float* __restrict__ wf, const float* __restrict__ wfb,
                                               float* __restrict__ it, float* __restrict__ ft) {
  int gid  = blockIdx.x * 4 + (threadIdx.x >> 6);
  int lane = threadIdx.x & 63;
  int which = gid >> 12;
  int m = gid & 4095;
  const bf16* row = (which ? kk : q) + (size_t)m * DIM2X;
  const float* w = which ? wf : wi;
  float s[8] = {0, 0, 0, 0, 0, 0, 0, 0};
  for (int d = lane; d < DIM2X; d += 64) {
    float xv = b2f(row[d]);
    const float4* wp = (const float4*)(w + d * 8);
    float4 w0 = wp[0], w1 = wp[1];
    s[0] += xv * w0.x; s[1] += xv * w0.y; s[2] += xv * w0.z; s[3] += xv * w0.w;
    s[4] += xv * w1.x; s[5] += xv * w1.y; s[6] += xv * w1.z; s[7] += xv * w1.w;
  }
#pragma unroll
  for (int off = 32; off; off >>= 1) {
#pragma unroll
    for (int h = 0; h < 8; h++) s[h] += __shfl_xor(s[h], off);
  }
  if (lane == 0) {
    int b_ = m >> 11, tt = m & 2047;
    const float* wb = which ? wfb : wib;
    float* dst = which ? ft : it;
#pragma unroll
    for (int h = 0; h < 8; h++)
      dst[((size_t)(b_ * NHEADS + h)) * SEQ + tt] = s[h] + wb[h];
  }
}

// ---------------- per-(b,h) scan ----------------
__global__ void __launch_bounds__(256) k_scan(const float* __restrict__ it, const float* __restrict__ ft,
                                              float* __restrict__ cs, float* __restrict__ md) {
  const int bh = blockIdx.x;
  const int t  = threadIdx.x;
  const float* fr = ft + (size_t)bh * SEQ;
  const float* ir = it + (size_t)bh * SEQ;
  float* csr = cs + (size_t)bh * SEQ;
  float* mdr = md + (size_t)bh * SEQ;
  __shared__ float tmp[256];
  float loc[8]; float run = 0.f;
#pragma unroll
  for (int j = 0; j < 8; j++) {
    float xv = fr[t * 8 + j];
    float ls = fminf(xv, 0.f) - log1pf(expf(-fabsf(xv)));
    run += ls; loc[j] = run;
  }
  tmp[t] = run;
  __syncthreads();
  for (int off = 1; off < 256; off <<= 1) {
    float add = (t >= off) ? tmp[t - off] : 0.f;
    __syncthreads();
    tmp[t] += add;
    __syncthreads();
  }
  float exc = (t == 0) ? 0.f : tmp[t - 1];
  float csv[8];
#pragma unroll
  for (int j = 0; j < 8; j++) { csv[j] = loc[j] + exc; csr[t * 8 + j] = csv[j]; }
  __syncthreads();
  float rmax = -INFINITY; float gm[8];
#pragma unroll
  for (int j = 0; j < 8; j++) {
    float gv = ir[t * 8 + j] - csv[j];
    rmax = fmaxf(rmax, gv); gm[j] = rmax;
  }
  tmp[t] = rmax;
  __syncthreads();
  for (int off = 1; off < 256; off <<= 1) {
    float other = (t >= off) ? tmp[t - off] : -INFINITY;
    __syncthreads();
    tmp[t] = fmaxf(tmp[t], other);
    __syncthreads();
  }
  float emax = (t == 0) ? -INFINITY : tmp[t - 1];
#pragma unroll
  for (int j = 0; j < 8; j++) mdr[t * 8 + j] = csv[j] + fmaxf(gm[j], emax);
}

// ---------------- MFMA causal attention: 3-buffer pipeline (53KB LDS -> 3 blocks/CU) ----------------
// Single tile per block, grid (32,16). Stage-after-barrier ordering (same scheme as the GEMM
// body): writer at step t targets buf (t+2)%3 == (t-1)%3, which all waves finished reading
// before the barrier just crossed. Counted wait vmcnt(4) keeps stage(t+1) in flight.
// LDS 3x(8KB K+V)+5KB Sc = 53KB -> 3 blocks/CU (was 4-buffer 69KB -> 2 blocks/CU).
// FUSED GroupNorm + skip/bgate epilogue writes PRE directly.
__global__ void __launch_bounds__(256) k_attn_mfma(const bf16* __restrict__ qh,
                                                   const bf16* __restrict__ kh,
                                                   const bf16* __restrict__ vt,
                                                   const float* __restrict__ cs,
                                                   const float* __restrict__ md,
                                                   const float* __restrict__ itl,
                                                   const bf16* __restrict__ qk,
                                                   const bf16* __restrict__ bg,
                                                   const float* __restrict__ gw,
                                                   const float* __restrict__ gb,
                                                   const float* __restrict__ skip,
                                                   bf16* __restrict__ pre) {
  const int bh = blockIdx.y, b_ = bh >> 3, h = bh & 7;
  const int bx = blockIdx.x;
  const int tile = ((blockIdx.y >> 3) & 1) ? bx : 31 - bx;   // balanced pairing heuristic
  const int i0 = tile * 64;
  const int tid = threadIdx.x;
  const int w = tid >> 6;                     // wave 0..3 -> i-rows i0+16w..
  const int lane = tid & 63;
  const int col = lane & 15, quad = lane >> 4;
  const int i0w = i0 + w * 16;
  const int iwmax = i0w + 15;
  const float L2E = 1.44269504f;

  __shared__ __align__(16) bf16 smK[3 * 4096]; // [buf][j 32][d 128], chunk^(j&7) swizzle
  __shared__ __align__(16) bf16 smV[3 * 4096]; // [buf][n 128][j 32], chunk^((n>>1)&3) swizzle
  __shared__ __align__(16) bf16 Sc[4][16][40];

  const size_t baseQK = ((size_t)b_ * SEQ) * DIM2X + (size_t)h * HDIM;
  const size_t vtb = (size_t)(h * HDIM) * 4096 + (size_t)b_ * SEQ;
  const float* csp = cs + (size_t)bh * SEQ;
  const float* mdp = md + (size_t)bh * SEQ;
  const float* itp = itl + (size_t)bh * SEQ;

  short8 qf[4];
#pragma unroll
  for (int kc = 0; kc < 4; kc++)
    qf[kc] = *(const short8*)(qh + baseQK + (size_t)(i0w + col) * DIM2X + kc * 32 + quad * 8);

  float cs_i[4], md_i[4];                     // log2 domain
#pragma unroll
  for (int r = 0; r < 4; r++) {
    int i = i0w + quad * 4 + r;
    cs_i[r] = csp[i] * L2E; md_i[r] = mdp[i] * L2E;
  }

  f32x4 accpv[8];
#pragma unroll
  for (int nb = 0; nb < 8; nb++) accpv[nb] = (f32x4){0.f, 0.f, 0.f, 0.f};
  float rs[4] = {0.f, 0.f, 0.f, 0.f};

  // staging sources (thread t covers LDS chunk t of each 8KB buffer; source pre-swizzled)
  const int kj = tid >> 4, kq = tid & 15;     // K: row kj (+16), chunk kq
  const bf16* gKs = kh + baseQK + (size_t)kj * DIM2X + ((kq ^ (kj & 7)) * 8);
  const int vn = tid >> 2, vq = tid & 3;      // V: row vn (+64), chunk vq
  const bf16* gVs = vt + vtb + (size_t)vn * 4096 + ((vq ^ ((vn >> 1) & 3)) * 8);

  const int trips = 2 * tile + 2;

#define STAGE(buf, j0s)                                                        \
  do {                                                                         \
    bf16* dK = &smK[(buf) * 4096 + tid * 8];                                   \
    gl16(gKs + (size_t)(j0s) * DIM2X, dK);                                     \
    gl16(gKs + (size_t)((j0s) + 16) * DIM2X, dK + 2048);                       \
    bf16* dV = &smV[(buf) * 4096 + tid * 8];                                   \
    gl16(gVs + (j0s), dV);                                                     \
    gl16(gVs + (j0s) + (size_t)64 * 4096, dV + 2048);                          \
  } while (0)

  STAGE(0, 0);
  STAGE(1, 32);                               // trips >= 2 always
  int cur = 0;
  for (int t = 0; t < trips; ++t) {
    const int j0p = t * 32;
    if (t + 1 < trips) asm volatile("s_waitcnt vmcnt(4)" ::: "memory");
    else               asm volatile("s_waitcnt vmcnt(0)" ::: "memory");
    __builtin_amdgcn_s_barrier();
    if (t + 2 < trips) {
      int nb = cur + 2; if (nb >= 3) nb -= 3;
      STAGE(nb, j0p + 64);
    }
    asm volatile("" ::: "memory");
    if (j0p <= iwmax) {
      // hoisted gate loads, log2 domain
      float g0 = (itp[j0p + col] - csp[j0p + col]) * L2E;
      float g1 = (itp[j0p + 16 + col] - csp[j0p + 16 + col]) * L2E;
      const bool jt1 = (j0p + 16 <= iwmax);
#pragma unroll
      for (int jt = 0; jt < 2; jt++) {
        const int j0 = j0p + jt * 16;
        float sv[4] = {0.f, 0.f, 0.f, 0.f};
        if (jt == 0 || jt1) {
          const int jj = jt * 16 + col;
          f32x4 aq = (f32x4){0.f, 0.f, 0.f, 0.f};
#pragma unroll
          for (int kc = 0; kc < 4; kc++) {
            short8 bk = *(const short8*)&smK[cur * 4096 + jj * 128 + ((((kc << 2) | quad) ^ (jj & 7)) << 3)];
            aq = __builtin_amdgcn_mfma_f32_16x16x32_bf16(qf[kc], bk, aq, 0, 0, 0);
          }
          const int j = j0 + col;
          const float gj = jt ? g1 : g0;
#pragma unroll
          for (int r = 0; r < 4; r++) {
            const int i = i0w + quad * 4 + r;
            // arg <= -5 by construction (md = exact row max); 2^-5 = 1/tau
            float s = (j <= i) ? exp2f(cs_i[r] + gj - md_i[r] - 5.f) * aq[r] : 0.f;
            sv[r] = s; rs[r] += s;
          }
        }
#pragma unroll
        for (int r = 0; r < 4; r++) Sc[w][quad * 4 + r][jt * 16 + col] = f2b(sv[r]);
      }
      // own-wave cross-lane LDS round-trip: force write completion before read (rule #18)
      asm volatile("s_waitcnt lgkmcnt(0)" ::: "memory");
      __builtin_amdgcn_sched_barrier(0);
      short8 af = *(const short8*)(&Sc[w][col][quad * 8]);
#pragma unroll
      for (int nb = 0; nb < 8; nb++) {
        const int rn = nb * 16 + col;
        short8 bv = *(const short8*)&smV[cur * 4096 + rn * 32 + ((quad ^ ((rn >> 1) & 3)) << 3)];
        accpv[nb] = __builtin_amdgcn_mfma_f32_16x16x32_bf16(af, bv, accpv[nb], 0, 0, 0);
      }
    }
    cur = (cur + 1 == 3) ? 0 : cur + 1;
  }
#undef STAGE

  // ---- fused epilogue: H normalize + GroupNorm + skip/bgate, write PRE ----
#pragma unroll
  for (int r = 0; r < 4; r++) {
    float v = rs[r];
    v += __shfl_xor(v, 1); v += __shfl_xor(v, 2);
    v += __shfl_xor(v, 4); v += __shfl_xor(v, 8);
    rs[r] = v;
  }
  float inv[4];
#pragma unroll
  for (int r = 0; r < 4; r++) {
    float maxit = fmaxf(fabsf(rs[r]), exp2f(fminf(-md_i[r], 43.f)));
    inv[r] = 1.f / (maxit + 1e-8f);
  }
  // per-col params (col = h*128 + nb*16 + colIdx; independent of r)
  float gwv[8], gbv[8], skv[8];
#pragma unroll
  for (int nb = 0; nb < 8; nb++) {
    int c = h * HDIM + nb * 16 + col;
    gwv[nb] = gw[c]; gbv[nb] = gb[c]; skv[nb] = skip[c];
  }
#pragma unroll
  for (int r = 0; r < 4; r++) {
    const int row = i0w + quad * 4 + r;       // row within batch
    float s1 = 0.f, s2 = 0.f;
#pragma unroll
    for (int nb = 0; nb < 8; nb++) {
      float v = accpv[nb][r] * inv[r];
      s1 += v; s2 += v * v;
    }
    // reduce over the 16 lanes of this quad-group (all 128 head-dims of this row)
    s1 += __shfl_xor(s1, 1); s2 += __shfl_xor(s2, 1);
    s1 += __shfl_xor(s1, 2); s2 += __shfl_xor(s2, 2);
    s1 += __shfl_xor(s1, 4); s2 += __shfl_xor(s2, 4);
    s1 += __shfl_xor(s1, 8); s2 += __shfl_xor(s2, 8);
    float mu  = s1 * (1.f / 128.f);
    float var = s2 * (1.f / 128.f) - mu * mu;
    float rsg = rsqrtf(var + EPSF);
    const size_t rbase = baseQK + (size_t)row * DIM2X;   // includes batch+head offset
#pragma unroll
    for (int nb = 0; nb < 8; nb++) {
      float hv = accpv[nb][r] * inv[r];
      float hn = (hv - mu) * rsg * gwv[nb] + gbv[nb];
      size_t gi = rbase + nb * 16 + col;
      pre[gi] = f2b((hn + skv[nb] * b2f(qk[gi])) * b2f(bg[gi]));
    }
  }
}

extern "C" void kernel_launch(void* const* d_in, const int* in_sizes, int n_in,
                              void* d_out, int out_size, void* d_ws, size_t ws_size,
                              hipStream_t stream) {
  const float* x     = (const float*)d_in[0];
  const float* ln_w  = (const float*)d_in[1];
  const float* ln_b  = (const float*)d_in[2];
  const float* mlp1w = (const float*)d_in[3];
  const float* mlp1b = (const float*)d_in[4];
  const float* mlp2w = (const float*)d_in[5];
  const float* mlp2b = (const float*)d_in[6];
  const float* convw = (const float*)d_in[7];
  const float* convb = (const float*)d_in[8];
  const float* bqw   = (const float*)d_in[9];
  const float* bkw   = (const float*)d_in[10];
  const float* bvw   = (const float*)d_in[11];
  const float* wqw   = (const float*)d_in[12];
  const float* wqb   = (const float*)d_in[13];
  const float* wkw   = (const float*)d_in[14];
  const float* wkb   = (const float*)d_in[15];
  const float* wvw   = (const float*)d_in[16];
  const float* wvb   = (const float*)d_in[17];
  const float* wiw   = (const float*)d_in[18];
  const float* wib   = (const float*)d_in[19];
  const float* wfw   = (const float*)d_in[20];
  const float* wfb   = (const float*)d_in[21];
  const float* gnw   = (const float*)d_in[22];
  const float* gnb   = (const float*)d_in[23];
  const float* skip  = (const float*)d_in[24];
  const float* finw  = (const float*)d_in[25];
  const float* finb  = (const float*)d_in[26];
  float* out = (float*)d_out;

  float* GA  = (float*)d_ws;
  float* ITb = GA;
  float* FTb = GA + 32768;
  float* CSb = GA + 65536;
  float* MDb = GA + 98304;
  const size_t SLOT = 4u * 1024u * 1024u;
  bf16* S0 = (bf16*)((char*)d_ws + (1 << 20));
  bf16* S1 = S0 + SLOT;
  bf16* S2 = S1 + SLOT;
  bf16* S3 = S2 + SLOT;
  bf16* S4 = S3 + SLOT;
  bf16* S5 = S4 + SLOT;
  bf16* S6 = S5 + SLOT;
  bf16 *LN = S0, *BG = S2, *QKb = S3, *Qb = S4, *Kb = S5, *Vb = S6;
  bf16 *QH = S0, *KH = S1, *VT = S4, *PRE = S6;
  bf16* WTb   = S6 + SLOT;
  bf16* mlp1T = WTb;
  bf16* mlp2T = WTb + 524288;
  bf16* convT = WTb + 1048576;                 // [1024][4096] flat-K layout
  bf16* bqT   = WTb + 5242880;
  bf16* bkT   = bqT + 262144;
  bf16* bvT   = bkT + 262144;
  bf16* wqT   = bvT + 262144;
  bf16* wkT   = wqT + 1048576;
  bf16* wvT   = wkT + 1048576;
  bf16* finT  = wvT + 1048576;
  bf16* APD   = finT + 524288;                 // padded A: [2][2051][1024]

  // fused weight prep
  k_castT3<<<dim3(32, 16, 2), 256, 0, stream>>>(mlp1w, mlp2w, mlp2w, mlp1T, DIMX, DIM2X, 1, 0, 524288);
  k_castT3<<<dim3(32, 32, 3), 256, 0, stream>>>(wqw, wkw, wvw, wqT, DIM2X, DIM2X, 1, 0, 1048576);
  k_castT3<<<dim3(8, 8, 12), 256, 0, stream>>>(bqw, bkw, bvw, bqT, 256, 256, 4, 65536, 65536);
  k_castT3<<<dim3(16, 32, 1), 256, 0, stream>>>(finw, finw, finw, finT, DIM2X, DIMX, 1, 0, 524288);
  k_convwT<<<4096, 256, 0, stream>>>(convw, convT);
  k_zeropad<<<24, 256, 0, stream>>>(APD);

  k_layernorm<<<1024, 256, 0, stream>>>(x, ln_w, ln_b, LN);
  // batched mlp: sel0 = mlp1 -> APD (store3), sel1 = mlp2 -> BG (store0, silu)
  k_mgemmB<<<dim3(16, 32, 2), 256, 0, stream>>>(LN, LN, LN, mlp1T, mlp2T, mlp2T,
                                                mlp1b, mlp2b, mlp2b, APD, BG, BG,
                                                DIMX, DIM2X, DIMX, 1, 0, 0, 0,
                                                /*actm*/ 0b10, /*storem*/ 3 | (0 << 4), /*apadm*/ 0);
  // causal conv1d == single GEMM: K=4096 contiguous window over padded rows t..t+3
  k_mgemm<1, 0, 0><<<dim3(16, 16, 2), 256, 0, stream>>>(APD, DIM2X, convT, convb, QKb, nullptr,
                                                        DIM2X, 4096, PADROWS * DIM2X, 0, SEQ * DIM2X);
  // batched block-diag q/k/v: 12 z-slices (3 weights x 4 groups)
  k_mgemmB<<<dim3(4, 32, 12), 256, 0, stream>>>(QKb, QKb, APD, bqT, bkT, bvT,
                                                nullptr, nullptr, nullptr, Qb, Kb, Vb,
                                                DIM2X, DIM2X, 256, 4, 256, 65536, 256,
                                                /*actm*/ 0, /*storem*/ 0, /*apadm*/ 0b100);
  k_gates<<<2048, 256, 0, stream>>>(Qb, Kb, wiw, wib, wfw, wfb, ITb, FTb);
  k_scan<<<16, 256, 0, stream>>>(ITb, FTb, CSb, MDb);
  // batched wq/wk/wv: sel2 writes V^T (store1)
  k_mgemmB<<<dim3(16, 32, 3), 256, 0, stream>>>(Qb, Kb, Vb, wqT, wkT, wvT,
                                                wqb, wkb, wvb, QH, KH, VT,
                                                DIM2X, DIM2X, DIM2X, 1, 0, 0, 0,
                                                /*actm*/ 0, /*storem*/ 0 | (0 << 4) | (1 << 8), /*apadm*/ 0);
  // attention with fused GroupNorm + skip/bgate epilogue (writes PRE directly)
  k_attn_mfma<<<dim3(32, 16), 256, 0, stream>>>(QH, KH, VT, CSb, MDb, ITb,
                                                QKb, BG, gnw, gnb, skip, PRE);
  k_mgemm<0, 2, 0><<<dim3(8, 32), 256, 0, stream>>>(PRE, DIM2X, finT, finb, out, x, DIMX, DIM2X, 0, 0, 0);
}